// Round 6
// baseline (461.900 us; speedup 1.0000x reference)
//
#include <hip/hip_runtime.h>
#include <math.h>

#define E_EDGES 4096
#define N_NODES 1024
#define D_NODE 128
#define D_EDGE 256
#define HEADS 4
#define HD 64
#define N_CLASSES 16
#define CAP 256   // max adjacent edges per edge (avg ~16)

// direct-to-LDS 16B DMA (gfx950); HW writes wave-uniform base + lane*16,
// which matches lane-linear per-thread offsets (t*16 within a wave).
__device__ __forceinline__ void gload_lds16(const float* g, float* l)
{
    auto g1 = (const __attribute__((address_space(1))) void*)g;
    auto l3 = (__attribute__((address_space(3))) void*)l;
    __builtin_amdgcn_global_load_lds(g1, l3, 16, 0, 0);
}

// XCD-aware remap: all blocks sharing an M-panel land on one XCD so the
// A/x panel is fetched into that XCD's L2 once (R5: FETCH 17.2->5.2MB).
__device__ __forceinline__ void xcd_remap(int& bx, int& by)
{
    const int nx = gridDim.x;
    const int lid = blockIdx.x + nx * blockIdx.y;
    const int g = lid & 7, s = lid >> 3;
    const int ppx = gridDim.y >> 3;
    by = g * ppx + s / nx;
    bx = s % nx;
}

// A-tile LDS xor-swizzle: col ^ ((k&7)<<2). 4-aligned so float4 stays legal;
// write banks 2-way (free), read banks conflict-free; saves the +4 pad so
// As[2][64][64]+Bs[2][64][64] = exactly 64KB.
#define SWZ(kidx, col) ((col) ^ (((kidx) & 7) << 2))

// ---------------------------------------------------------------------------
// Big GEMM core: C[64x64] = act(A@B + bias + residual), K%64==0, N%64==0.
// BK=64, 256 thr, 4x4 micro-tile. Double-buffered LDS, ONE barrier per
// K-tile: issue next tile's B-DMA + A-reg-loads BEFORE compute, STOREA after.
// If nf != null: A row m = concat(nf[src[m]], nf[dst[m]]).
// ---------------------------------------------------------------------------
__device__ __forceinline__ void gemm_core_big(
    const float* __restrict__ A, const float* __restrict__ B,
    const float* __restrict__ bias, const float* __restrict__ residual,
    float* __restrict__ C, int N, int K, int m0, int n0,
    const float* __restrict__ nf, const int* __restrict__ src,
    const int* __restrict__ dst, int act)
{
    __shared__ float As[2][64][64];   // [buf][k][m], xor-swizzled cols
    __shared__ float Bs[2][64][64];   // [buf][k][n], DMA lane-linear
    const int t = threadIdx.x;
    const int tx = t & 15, ty = t >> 4;
    const int row = t >> 2;              // A-tile m-row 0..63
    const int kbase = (t & 3) * 4;       // A k-offset, +p*16

    int nS = 0, nD = 0;
    if (nf) { nS = src[m0 + row]; nD = dst[m0 + row]; }

    float acc[4][4] = {};
    float4 aS[4];

#define LOADA64(k0)                                                            \
    do { _Pragma("unroll") for (int p = 0; p < 4; ++p) {                       \
        const int kq = (k0) + kbase + p * 16;                                  \
        if (nf) {                                                              \
            const float* pp = (kq < D_NODE)                                    \
                ? &nf[(size_t)nS * D_NODE + kq]                                \
                : &nf[(size_t)nD * D_NODE + kq - D_NODE];                      \
            aS[p] = *(const float4*)pp;                                        \
        } else {                                                               \
            aS[p] = *(const float4*)&A[(size_t)(m0 + row) * K + kq];           \
        }                                                                      \
    } } while (0)
#define STOREA64(buf)                                                          \
    do { _Pragma("unroll") for (int p = 0; p < 4; ++p) {                       \
        const int kc = kbase + p * 16;                                         \
        As[buf][kc + 0][SWZ(kc + 0, row)] = aS[p].x;                           \
        As[buf][kc + 1][SWZ(kc + 1, row)] = aS[p].y;                           \
        As[buf][kc + 2][SWZ(kc + 2, row)] = aS[p].z;                           \
        As[buf][kc + 3][SWZ(kc + 3, row)] = aS[p].w;                           \
    } } while (0)
#define DMAB64(buf, k0)                                                        \
    do { _Pragma("unroll") for (int p = 0; p < 4; ++p) {                       \
        const int idx = t + 256 * p;                                           \
        gload_lds16(&B[(size_t)((k0) + (idx >> 4)) * N + n0 + (idx & 15) * 4], \
                    &Bs[buf][0][0] + (size_t)idx * 4);                         \
    } } while (0)
#define COMPUTE64(buf)                                                         \
    do { _Pragma("unroll") for (int kk = 0; kk < 64; ++kk) {                   \
        const float4 av = *(const float4*)&As[buf][kk][SWZ(kk, ty * 4)];       \
        const float4 bv = *(const float4*)&Bs[buf][kk][tx * 4];                \
        const float a_[4] = {av.x, av.y, av.z, av.w};                          \
        const float b_[4] = {bv.x, bv.y, bv.z, bv.w};                          \
        _Pragma("unroll")                                                      \
        for (int i = 0; i < 4; ++i)                                            \
            _Pragma("unroll")                                                  \
            for (int j = 0; j < 4; ++j) acc[i][j] += a_[i] * b_[j];            \
    } } while (0)

    const int KT = K / 64;
    LOADA64(0);
    DMAB64(0, 0);
    STOREA64(0);
    __syncthreads();                       // drains DMA vmcnt too
    for (int kt = 0; kt < KT; ++kt) {
        const int cur = kt & 1;
        if (kt + 1 < KT) {
            DMAB64(cur ^ 1, (kt + 1) * 64);
            LOADA64((kt + 1) * 64);
        }
        COMPUTE64(cur);
        if (kt + 1 < KT) STOREA64(cur ^ 1);
        __syncthreads();
    }

#pragma unroll
    for (int i = 0; i < 4; ++i) {
        const int orow = m0 + ty * 4 + i;
        const int ocol = n0 + tx * 4;
        float4 r = make_float4(acc[i][0], acc[i][1], acc[i][2], acc[i][3]);
        if (bias) {
            const float4 bb = *(const float4*)&bias[ocol];
            r.x += bb.x; r.y += bb.y; r.z += bb.z; r.w += bb.w;
        }
        if (residual) {
            const float4 rr = *(const float4*)&residual[(size_t)orow * N + ocol];
            r.x += rr.x; r.y += rr.y; r.z += rr.z; r.w += rr.w;
        }
        if (act == 1) {
            r.x = 0.5f * r.x * (1.f + erff(r.x * 0.70710678118654752f));
            r.y = 0.5f * r.y * (1.f + erff(r.y * 0.70710678118654752f));
            r.z = 0.5f * r.z * (1.f + erff(r.z * 0.70710678118654752f));
            r.w = 0.5f * r.w * (1.f + erff(r.w * 0.70710678118654752f));
        }
        *(float4*)&C[(size_t)orow * N + ocol] = r;
    }
#undef LOADA64
#undef STOREA64
#undef DMAB64
#undef COMPUTE64
}

__global__ __launch_bounds__(256) void gemm_big(
    const float* __restrict__ A, const float* __restrict__ B,
    const float* __restrict__ bias, const float* __restrict__ residual,
    float* __restrict__ C, int N, int K,
    const float* __restrict__ nf, const int* __restrict__ src,
    const int* __restrict__ dst, int act)
{
    int bx = blockIdx.x, by = blockIdx.y;
    xcd_remap(bx, by);
    gemm_core_big(A, B, bias, residual, C, N, K, by * 64, bx * 64,
                  nf, src, dst, act);
}

// ---------------------------------------------------------------------------
// Small guarded GEMM (classifier head, N=16). BK=32, single-buffer, 2-barrier.
// ---------------------------------------------------------------------------
__global__ __launch_bounds__(256) void gemm_small(
    const float* __restrict__ A, const float* __restrict__ B,
    const float* __restrict__ bias, float* __restrict__ C, int N, int K)
{
    __shared__ float As[32][68];
    __shared__ float Bs[32][68];
    const int t = threadIdx.x;
    const int tx = t & 15, ty = t >> 4;
    const int m0 = blockIdx.y * 64, n0 = 0;
    const int ar0 = t >> 3, ak0 = (t & 7) * 4;
    const int br0 = t >> 4, nc = (t & 15) * 4;
    float acc[4][4] = {};

    for (int k0 = 0; k0 < K; k0 += 32) {
        float4 a0 = *(const float4*)&A[(size_t)(m0 + ar0) * K + k0 + ak0];
        float4 a1 = *(const float4*)&A[(size_t)(m0 + ar0 + 32) * K + k0 + ak0];
        float4 b0 = make_float4(0.f, 0.f, 0.f, 0.f), b1 = b0;
        if (n0 + nc < N) {
            b0 = *(const float4*)&B[(size_t)(k0 + br0) * N + n0 + nc];
            b1 = *(const float4*)&B[(size_t)(k0 + br0 + 16) * N + n0 + nc];
        }
        As[ak0 + 0][ar0] = a0.x; As[ak0 + 1][ar0] = a0.y;
        As[ak0 + 2][ar0] = a0.z; As[ak0 + 3][ar0] = a0.w;
        As[ak0 + 0][ar0 + 32] = a1.x; As[ak0 + 1][ar0 + 32] = a1.y;
        As[ak0 + 2][ar0 + 32] = a1.z; As[ak0 + 3][ar0 + 32] = a1.w;
        *(float4*)&Bs[br0][nc] = b0; *(float4*)&Bs[br0 + 16][nc] = b1;
        __syncthreads();
#pragma unroll
        for (int kk = 0; kk < 32; ++kk) {
            const float4 av = *(const float4*)&As[kk][ty * 4];
            const float4 bv = *(const float4*)&Bs[kk][tx * 4];
            const float a_[4] = {av.x, av.y, av.z, av.w};
            const float b_[4] = {bv.x, bv.y, bv.z, bv.w};
#pragma unroll
            for (int i = 0; i < 4; ++i)
#pragma unroll
                for (int j = 0; j < 4; ++j) acc[i][j] += a_[i] * b_[j];
        }
        __syncthreads();
    }

#pragma unroll
    for (int i = 0; i < 4; ++i) {
        const int row = m0 + ty * 4 + i;
        const int col = n0 + tx * 4;
        if (col < N) {
            float4 r = make_float4(acc[i][0], acc[i][1], acc[i][2], acc[i][3]);
            const float4 bb = *(const float4*)&bias[col];
            r.x += bb.x; r.y += bb.y; r.z += bb.z; r.w += bb.w;
            *(float4*)&C[(size_t)row * N + col] = r;
        }
    }
}

// ---------------------------------------------------------------------------
// One-time adjacency build: wave per query edge, ballot-compaction ascending.
// ---------------------------------------------------------------------------
__global__ __launch_bounds__(256) void build_adj(
    const int* __restrict__ src, const int* __restrict__ dst,
    int* __restrict__ cand, int* __restrict__ ccount)
{
    const int w = threadIdx.x >> 6, lane = threadIdx.x & 63;
    const int e = blockIdx.x * 4 + w;
    const int a = src[e], b = dst[e];
    int* my = cand + (size_t)e * CAP;
    int base = 0;
    for (int c0 = 0; c0 < E_EDGES; c0 += 64) {
        const int f = c0 + lane;
        const int sf = src[f], df = dst[f];
        const bool adj = (sf == a) | (sf == b) | (df == a) | (df == b);
        const unsigned long long mk = __ballot(adj);
        if (adj) {
            const int pos = base + __popcll(mk & ((1ull << lane) - 1ull));
            if (pos < CAP) my[pos] = f;
        }
        base += __popcll(mk);
    }
    if (lane == 0) ccount[e] = (base < CAP) ? base : CAP;
}

// ---------------------------------------------------------------------------
// Sparse attention from prebuilt lists. Block = edge, wave = head, lane = dim.
// One-pass online softmax (expf(-1e9-max)==0 => sparse == dense-masked).
// ---------------------------------------------------------------------------
__global__ __launch_bounds__(256) void attn_sparse2(
    const float* __restrict__ q, const float* __restrict__ k,
    const float* __restrict__ v, const int* __restrict__ cand,
    const int* __restrict__ ccount, float* __restrict__ out)
{
    __shared__ int lc[CAP];
    const int e = blockIdx.x;
    const int t = threadIdx.x, h = t >> 6, lane = t & 63;
    const int m = ccount[e];
    if (t < m) lc[t] = cand[(size_t)e * CAP + t];
    __syncthreads();

    const float qd = q[e * D_EDGE + h * HD + lane];
    float M = -1e30f, L = 0.f, O = 0.f;
    int i = 0;
    for (; i + 2 <= m; i += 2) {
        const int f0 = lc[i], f1 = lc[i + 1];
        const float kd0 = k[f0 * D_EDGE + h * HD + lane];
        const float vd0 = v[f0 * D_EDGE + h * HD + lane];
        const float kd1 = k[f1 * D_EDGE + h * HD + lane];
        const float vd1 = v[f1 * D_EDGE + h * HD + lane];
        float s0 = qd * kd0, s1 = qd * kd1;
#pragma unroll
        for (int off = 32; off; off >>= 1) {
            s0 += __shfl_xor(s0, off);
            s1 += __shfl_xor(s1, off);
        }
        s0 *= 0.125f; s1 *= 0.125f;
        const float Mn = fmaxf(M, fmaxf(s0, s1));
        const float alpha = __expf(M - Mn);
        const float p0 = __expf(s0 - Mn), p1 = __expf(s1 - Mn);
        O = O * alpha + p0 * vd0 + p1 * vd1;
        L = L * alpha + p0 + p1;
        M = Mn;
    }
    if (i < m) {
        const int f = lc[i];
        const float kd = k[f * D_EDGE + h * HD + lane];
        const float vd = v[f * D_EDGE + h * HD + lane];
        float s = qd * kd;
#pragma unroll
        for (int off = 32; off; off >>= 1) s += __shfl_xor(s, off);
        s *= 0.125f;
        const float Mn = fmaxf(M, s);
        const float alpha = __expf(M - Mn);
        const float p = __expf(s - Mn);
        O = O * alpha + p * vd;
        L = L * alpha + p;
        M = Mn;
    }
    out[e * D_EDGE + h * HD + lane] = O / L;
}

// ---------------------------------------------------------------------------
extern "C" void kernel_launch(void* const* d_in, const int* in_sizes, int n_in,
                              void* d_out, int out_size, void* d_ws, size_t ws_size,
                              hipStream_t stream)
{
    const float* nf = (const float*)d_in[0];
    const float* ef = (const float*)d_in[1];
    const int* ei = (const int*)d_in[2];
    const int* src = ei;
    const int* dst = ei + E_EDGES;

    const float* a_Wn[2] = {(const float*)d_in[3],  (const float*)d_in[13]};
    const float* a_bn[2] = {(const float*)d_in[4],  (const float*)d_in[14]};
    const float* a_Wq[2] = {(const float*)d_in[5],  (const float*)d_in[15]};
    const float* a_bq[2] = {(const float*)d_in[6],  (const float*)d_in[16]};
    const float* a_Wk[2] = {(const float*)d_in[7],  (const float*)d_in[17]};
    const float* a_bk[2] = {(const float*)d_in[8],  (const float*)d_in[18]};
    const float* a_Wv[2] = {(const float*)d_in[9],  (const float*)d_in[19]};
    const float* a_bv[2] = {(const float*)d_in[10], (const float*)d_in[20]};
    const float* a_Wo[2] = {(const float*)d_in[11], (const float*)d_in[21]};
    const float* a_bo[2] = {(const float*)d_in[12], (const float*)d_in[22]};
    const float* cls_W1 = (const float*)d_in[23];
    const float* cls_b1 = (const float*)d_in[24];
    const float* cls_W2 = (const float*)d_in[25];
    const float* cls_b2 = (const float*)d_in[26];

    const size_t buf = (size_t)E_EDGES * D_EDGE;  // 1M floats = 4MB
    float* ws = (float*)d_ws;
    float* x  = ws + 0 * buf;
    float* qb = ws + 1 * buf;
    float* kb = ws + 2 * buf;
    float* vb = ws + 3 * buf;
    float* ao = ws + 4 * buf;
    float* y  = ws + 5 * buf;
    float* hb = ws + 6 * buf;           // classifier scratch (post-attn)
    int* cand   = (int*)(ws + 6 * buf); // alias hb: cand dead before hb write
    int* ccount = (int*)(ws + 7 * buf);

    const dim3 gFull(D_EDGE / 64, E_EDGES / 64);   // (4, 64) = 256 blocks
    const dim3 gCls(1, E_EDGES / 64);

    build_adj<<<E_EDGES / 4, 256, 0, stream>>>(src, dst, cand, ccount);

    const float* ef_in = ef;
    for (int L = 0; L < 2; ++L) {
        gemm_big<<<gFull, 256, 0, stream>>>(nullptr, a_Wn[L], a_bn[L], ef_in, x,
                                            D_EDGE, 2 * D_NODE, nf, src, dst, 0);
        // q/k/v as three fully-resident 256-block dispatches (1 block/CU each)
        gemm_big<<<gFull, 256, 0, stream>>>(x, a_Wq[L], a_bq[L], nullptr, qb,
                                            D_EDGE, D_EDGE, nullptr, nullptr, nullptr, 0);
        gemm_big<<<gFull, 256, 0, stream>>>(x, a_Wk[L], a_bk[L], nullptr, kb,
                                            D_EDGE, D_EDGE, nullptr, nullptr, nullptr, 0);
        gemm_big<<<gFull, 256, 0, stream>>>(x, a_Wv[L], a_bv[L], nullptr, vb,
                                            D_EDGE, D_EDGE, nullptr, nullptr, nullptr, 0);
        attn_sparse2<<<E_EDGES, 256, 0, stream>>>(qb, kb, vb, cand, ccount, ao);
        gemm_big<<<gFull, 256, 0, stream>>>(ao, a_Wo[L], a_bo[L], x, y,
                                            D_EDGE, D_EDGE, nullptr, nullptr, nullptr, 0);
        ef_in = y;
    }

    gemm_big<<<gFull, 256, 0, stream>>>(y, cls_W1, cls_b1, nullptr, hb,
                                        D_EDGE, D_EDGE, nullptr, nullptr, nullptr, 1);
    gemm_small<<<gCls, 256, 0, stream>>>(hb, cls_W2, cls_b2, (float*)d_out,
                                         N_CLASSES, D_EDGE);
}

// Round 7
// 212.180 us; speedup vs baseline: 2.1769x; 2.1769x over previous
//
#include <hip/hip_runtime.h>
#include <math.h>

#define E_EDGES 4096
#define N_NODES 1024
#define D_NODE 128
#define D_EDGE 256
#define HEADS 4
#define HD 64
#define N_CLASSES 16
#define CAP 256   // max adjacent edges per edge (avg ~16)

// direct-to-LDS 16B DMA (gfx950); HW writes wave-uniform base + lane*16,
// matching lane-linear per-thread offsets.
__device__ __forceinline__ void gload_lds16(const float* g, float* l)
{
    auto g1 = (const __attribute__((address_space(1))) void*)g;
    auto l3 = (__attribute__((address_space(3))) void*)l;
    __builtin_amdgcn_global_load_lds(g1, l3, 16, 0, 0);
}

// XCD-aware remap: all blocks of an M-panel get consecutive-by-8 linear ids
// so they land on one XCD -> A/x panel fetched into that L2 once
// (R5 evidence: qkv FETCH 17.2 -> 5.2MB). Requires gridDim.y % 8 == 0.
__device__ __forceinline__ void xcd_remap(int& bx, int& by)
{
    const int nx = gridDim.x;
    const int lid = blockIdx.x + nx * blockIdx.y;
    const int g = lid & 7, s = lid >> 3;
    const int ppx = gridDim.y >> 3;
    by = g * ppx + s / nx;
    bx = s % nx;
}

// ---------------------------------------------------------------------------
// GEMM core: C[32x64 tile] = act(A@B + bias + residual), K%32==0, N%64==0.
// BM=32 BN=64 BK=32, 256 thr, 2x4 micro-tile (8 acc regs -> low VGPR).
// LDS ~24.5KB -> up to 6 blocks/CU = 6 waves/SIMD (the R5/R6 kernels were
// stuck at 1 wave/SIMD; latency hiding is the point of this shape).
// Double-buffered, ONE barrier per K-tile; B via global_load_lds DMA
// (lane-linear [32][64]); A reg-staged, stored transposed [k][m] pad 34.
// If nf != null: A row m = concat(nf[src[m]], nf[dst[m]]).
// ---------------------------------------------------------------------------
__device__ __forceinline__ void gemm_core32(
    const float* __restrict__ A, const float* __restrict__ B,
    const float* __restrict__ bias, const float* __restrict__ residual,
    float* __restrict__ C, int N, int K, int m0, int n0,
    const float* __restrict__ nf, const int* __restrict__ src,
    const int* __restrict__ dst, int act)
{
    __shared__ float As[2][32][34];   // [buf][k][m], pad 34 (8B-aligned b64)
    __shared__ float Bs[2][32][64];   // [buf][k][n], DMA lane-linear
    const int t = threadIdx.x;
    const int tx = t & 15, ty = t >> 4;        // n = tx*4, m = ty*2
    const int ar = t >> 3, akc = (t & 7) * 4;  // A stage: row ar, k-col akc

    int nS = 0, nD = 0;
    if (nf) { nS = src[m0 + ar]; nD = dst[m0 + ar]; }

    float acc[2][4] = {};
    float4 aS;

#define LOADA32(k0)                                                            \
    do {                                                                       \
        const int kq = (k0) + akc;                                             \
        if (nf) {                                                              \
            const float* pp = (kq < D_NODE)                                    \
                ? &nf[(size_t)nS * D_NODE + kq]                                \
                : &nf[(size_t)nD * D_NODE + kq - D_NODE];                      \
            aS = *(const float4*)pp;                                           \
        } else {                                                               \
            aS = *(const float4*)&A[(size_t)(m0 + ar) * K + kq];               \
        }                                                                      \
    } while (0)
#define STOREA32(buf)                                                          \
    do {                                                                       \
        As[buf][akc + 0][ar] = aS.x; As[buf][akc + 1][ar] = aS.y;              \
        As[buf][akc + 2][ar] = aS.z; As[buf][akc + 3][ar] = aS.w;              \
    } while (0)
#define DMAB32(buf, k0)                                                        \
    do { _Pragma("unroll") for (int p = 0; p < 2; ++p) {                       \
        const int idx = t + 256 * p;                                           \
        gload_lds16(&B[(size_t)((k0) + (idx >> 4)) * N + n0 + (idx & 15) * 4], \
                    &Bs[buf][0][0] + (size_t)idx * 4);                         \
    } } while (0)
#define COMPUTE32(buf)                                                         \
    do { _Pragma("unroll") for (int kk = 0; kk < 32; ++kk) {                   \
        const float2 av = *(const float2*)&As[buf][kk][ty * 2];                \
        const float4 bv = *(const float4*)&Bs[buf][kk][tx * 4];                \
        const float a_[2] = {av.x, av.y};                                      \
        const float b_[4] = {bv.x, bv.y, bv.z, bv.w};                          \
        _Pragma("unroll")                                                      \
        for (int i = 0; i < 2; ++i)                                            \
            _Pragma("unroll")                                                  \
            for (int j = 0; j < 4; ++j) acc[i][j] += a_[i] * b_[j];            \
    } } while (0)

    const int KT = K / 32;
    LOADA32(0);
    DMAB32(0, 0);
    STOREA32(0);
    __syncthreads();                       // drains DMA vmcnt too
    for (int kt = 0; kt < KT; ++kt) {
        const int cur = kt & 1;
        if (kt + 1 < KT) {
            DMAB32(cur ^ 1, (kt + 1) * 32);
            LOADA32((kt + 1) * 32);
        }
        COMPUTE32(cur);
        if (kt + 1 < KT) STOREA32(cur ^ 1);
        __syncthreads();
    }

#pragma unroll
    for (int i = 0; i < 2; ++i) {
        const int orow = m0 + ty * 2 + i;
        const int ocol = n0 + tx * 4;
        float4 r = make_float4(acc[i][0], acc[i][1], acc[i][2], acc[i][3]);
        if (bias) {
            const float4 bb = *(const float4*)&bias[ocol];
            r.x += bb.x; r.y += bb.y; r.z += bb.z; r.w += bb.w;
        }
        if (residual) {
            const float4 rr = *(const float4*)&residual[(size_t)orow * N + ocol];
            r.x += rr.x; r.y += rr.y; r.z += rr.z; r.w += rr.w;
        }
        if (act == 1) {
            r.x = 0.5f * r.x * (1.f + erff(r.x * 0.70710678118654752f));
            r.y = 0.5f * r.y * (1.f + erff(r.y * 0.70710678118654752f));
            r.z = 0.5f * r.z * (1.f + erff(r.z * 0.70710678118654752f));
            r.w = 0.5f * r.w * (1.f + erff(r.w * 0.70710678118654752f));
        }
        *(float4*)&C[(size_t)orow * N + ocol] = r;
    }
#undef LOADA32
#undef STOREA32
#undef DMAB32
#undef COMPUTE32
}

__global__ __launch_bounds__(256) void gemm32(
    const float* __restrict__ A, const float* __restrict__ B,
    const float* __restrict__ bias, const float* __restrict__ residual,
    float* __restrict__ C, int N, int K,
    const float* __restrict__ nf, const int* __restrict__ src,
    const int* __restrict__ dst, int act)
{
    int bx = blockIdx.x, by = blockIdx.y;
    xcd_remap(bx, by);
    gemm_core32(A, B, bias, residual, C, N, K, by * 32, bx * 64,
                nf, src, dst, act);
}

// q/k/v fused: grid (12, 128) = 1536 blocks = one full 6-blocks/CU pass.
// After remap bx in 0..11: bx>>2 selects matrix, bx&3 the n-tile; all 12
// blocks of an M-panel share one XCD -> x panel L2-resident.
__global__ __launch_bounds__(256) void gemm_qkv32(
    const float* __restrict__ x,
    const float* __restrict__ Wq, const float* __restrict__ bq,
    const float* __restrict__ Wk, const float* __restrict__ bk,
    const float* __restrict__ Wv, const float* __restrict__ bv,
    float* __restrict__ qb, float* __restrict__ kb, float* __restrict__ vb)
{
    int bx = blockIdx.x, by = blockIdx.y;
    xcd_remap(bx, by);
    const int wsel = bx >> 2, nt = bx & 3;
    const float* B = (wsel == 0) ? Wq : (wsel == 1) ? Wk : Wv;
    const float* bias = (wsel == 0) ? bq : (wsel == 1) ? bk : bv;
    float* C = (wsel == 0) ? qb : (wsel == 1) ? kb : vb;
    gemm_core32(x, B, bias, nullptr, C, D_EDGE, D_EDGE,
                by * 32, nt * 64, nullptr, nullptr, nullptr, 0);
}

// ---------------------------------------------------------------------------
// Small guarded GEMM (classifier head, N=16). BK=32, single-buffer.
// ---------------------------------------------------------------------------
__global__ __launch_bounds__(256) void gemm_small(
    const float* __restrict__ A, const float* __restrict__ B,
    const float* __restrict__ bias, float* __restrict__ C, int N, int K)
{
    __shared__ float As[32][68];
    __shared__ float Bs[32][68];
    const int t = threadIdx.x;
    const int tx = t & 15, ty = t >> 4;
    const int m0 = blockIdx.y * 64, n0 = 0;
    const int ar0 = t >> 3, ak0 = (t & 7) * 4;
    const int br0 = t >> 4, nc = (t & 15) * 4;
    float acc[4][4] = {};

    for (int k0 = 0; k0 < K; k0 += 32) {
        float4 a0 = *(const float4*)&A[(size_t)(m0 + ar0) * K + k0 + ak0];
        float4 a1 = *(const float4*)&A[(size_t)(m0 + ar0 + 32) * K + k0 + ak0];
        float4 b0 = make_float4(0.f, 0.f, 0.f, 0.f), b1 = b0;
        if (n0 + nc < N) {
            b0 = *(const float4*)&B[(size_t)(k0 + br0) * N + n0 + nc];
            b1 = *(const float4*)&B[(size_t)(k0 + br0 + 16) * N + n0 + nc];
        }
        As[ak0 + 0][ar0] = a0.x; As[ak0 + 1][ar0] = a0.y;
        As[ak0 + 2][ar0] = a0.z; As[ak0 + 3][ar0] = a0.w;
        As[ak0 + 0][ar0 + 32] = a1.x; As[ak0 + 1][ar0 + 32] = a1.y;
        As[ak0 + 2][ar0 + 32] = a1.z; As[ak0 + 3][ar0 + 32] = a1.w;
        *(float4*)&Bs[br0][nc] = b0; *(float4*)&Bs[br0 + 16][nc] = b1;
        __syncthreads();
#pragma unroll
        for (int kk = 0; kk < 32; ++kk) {
            const float4 av = *(const float4*)&As[kk][ty * 4];
            const float4 bv = *(const float4*)&Bs[kk][tx * 4];
            const float a_[4] = {av.x, av.y, av.z, av.w};
            const float b_[4] = {bv.x, bv.y, bv.z, bv.w};
#pragma unroll
            for (int i = 0; i < 4; ++i)
#pragma unroll
                for (int j = 0; j < 4; ++j) acc[i][j] += a_[i] * b_[j];
        }
        __syncthreads();
    }

#pragma unroll
    for (int i = 0; i < 4; ++i) {
        const int row = m0 + ty * 4 + i;
        const int col = n0 + tx * 4;
        if (col < N) {
            float4 r = make_float4(acc[i][0], acc[i][1], acc[i][2], acc[i][3]);
            const float4 bb = *(const float4*)&bias[col];
            r.x += bb.x; r.y += bb.y; r.z += bb.z; r.w += bb.w;
            *(float4*)&C[(size_t)row * N + col] = r;
        }
    }
}

// ---------------------------------------------------------------------------
// One-time adjacency build: wave per query edge, ballot-compaction ascending.
// ---------------------------------------------------------------------------
__global__ __launch_bounds__(256) void build_adj(
    const int* __restrict__ src, const int* __restrict__ dst,
    int* __restrict__ cand, int* __restrict__ ccount)
{
    const int w = threadIdx.x >> 6, lane = threadIdx.x & 63;
    const int e = blockIdx.x * 4 + w;
    const int a = src[e], b = dst[e];
    int* my = cand + (size_t)e * CAP;
    int base = 0;
    for (int c0 = 0; c0 < E_EDGES; c0 += 64) {
        const int f = c0 + lane;
        const int sf = src[f], df = dst[f];
        const bool adj = (sf == a) | (sf == b) | (df == a) | (df == b);
        const unsigned long long mk = __ballot(adj);
        if (adj) {
            const int pos = base + __popcll(mk & ((1ull << lane) - 1ull));
            if (pos < CAP) my[pos] = f;
        }
        base += __popcll(mk);
    }
    if (lane == 0) ccount[e] = (base < CAP) ? base : CAP;
}

// ---------------------------------------------------------------------------
// Sparse attention from prebuilt lists. Block = edge, wave = head, lane = dim.
// One-pass online softmax (expf(-1e9-max)==0 => sparse == dense-masked).
// ---------------------------------------------------------------------------
__global__ __launch_bounds__(256) void attn_sparse2(
    const float* __restrict__ q, const float* __restrict__ k,
    const float* __restrict__ v, const int* __restrict__ cand,
    const int* __restrict__ ccount, float* __restrict__ out)
{
    __shared__ int lc[CAP];
    const int e = blockIdx.x;
    const int t = threadIdx.x, h = t >> 6, lane = t & 63;
    const int m = ccount[e];
    if (t < m) lc[t] = cand[(size_t)e * CAP + t];
    __syncthreads();

    const float qd = q[e * D_EDGE + h * HD + lane];
    float M = -1e30f, L = 0.f, O = 0.f;
    int i = 0;
    for (; i + 2 <= m; i += 2) {
        const int f0 = lc[i], f1 = lc[i + 1];
        const float kd0 = k[f0 * D_EDGE + h * HD + lane];
        const float vd0 = v[f0 * D_EDGE + h * HD + lane];
        const float kd1 = k[f1 * D_EDGE + h * HD + lane];
        const float vd1 = v[f1 * D_EDGE + h * HD + lane];
        float s0 = qd * kd0, s1 = qd * kd1;
#pragma unroll
        for (int off = 32; off; off >>= 1) {
            s0 += __shfl_xor(s0, off);
            s1 += __shfl_xor(s1, off);
        }
        s0 *= 0.125f; s1 *= 0.125f;
        const float Mn = fmaxf(M, fmaxf(s0, s1));
        const float alpha = __expf(M - Mn);
        const float p0 = __expf(s0 - Mn), p1 = __expf(s1 - Mn);
        O = O * alpha + p0 * vd0 + p1 * vd1;
        L = L * alpha + p0 + p1;
        M = Mn;
    }
    if (i < m) {
        const int f = lc[i];
        const float kd = k[f * D_EDGE + h * HD + lane];
        const float vd = v[f * D_EDGE + h * HD + lane];
        float s = qd * kd;
#pragma unroll
        for (int off = 32; off; off >>= 1) s += __shfl_xor(s, off);
        s *= 0.125f;
        const float Mn = fmaxf(M, s);
        const float alpha = __expf(M - Mn);
        const float p = __expf(s - Mn);
        O = O * alpha + p * vd;
        L = L * alpha + p;
        M = Mn;
    }
    out[e * D_EDGE + h * HD + lane] = O / L;
}

// ---------------------------------------------------------------------------
extern "C" void kernel_launch(void* const* d_in, const int* in_sizes, int n_in,
                              void* d_out, int out_size, void* d_ws, size_t ws_size,
                              hipStream_t stream)
{
    const float* nf = (const float*)d_in[0];
    const float* ef = (const float*)d_in[1];
    const int* ei = (const int*)d_in[2];
    const int* src = ei;
    const int* dst = ei + E_EDGES;

    const float* a_Wn[2] = {(const float*)d_in[3],  (const float*)d_in[13]};
    const float* a_bn[2] = {(const float*)d_in[4],  (const float*)d_in[14]};
    const float* a_Wq[2] = {(const float*)d_in[5],  (const float*)d_in[15]};
    const float* a_bq[2] = {(const float*)d_in[6],  (const float*)d_in[16]};
    const float* a_Wk[2] = {(const float*)d_in[7],  (const float*)d_in[17]};
    const float* a_bk[2] = {(const float*)d_in[8],  (const float*)d_in[18]};
    const float* a_Wv[2] = {(const float*)d_in[9],  (const float*)d_in[19]};
    const float* a_bv[2] = {(const float*)d_in[10], (const float*)d_in[20]};
    const float* a_Wo[2] = {(const float*)d_in[11], (const float*)d_in[21]};
    const float* a_bo[2] = {(const float*)d_in[12], (const float*)d_in[22]};
    const float* cls_W1 = (const float*)d_in[23];
    const float* cls_b1 = (const float*)d_in[24];
    const float* cls_W2 = (const float*)d_in[25];
    const float* cls_b2 = (const float*)d_in[26];

    const size_t buf = (size_t)E_EDGES * D_EDGE;  // 1M floats = 4MB
    float* ws = (float*)d_ws;
    float* x  = ws + 0 * buf;
    float* qb = ws + 1 * buf;
    float* kb = ws + 2 * buf;
    float* vb = ws + 3 * buf;
    float* ao = ws + 4 * buf;
    float* y  = ws + 5 * buf;
    float* hb = ws + 6 * buf;           // classifier scratch (post-attn)
    int* cand   = (int*)(ws + 6 * buf); // alias hb: cand dead before hb write
    int* ccount = (int*)(ws + 7 * buf);

    const dim3 g32(D_EDGE / 64, E_EDGES / 32);     // (4, 128) = 512 blocks
    const dim3 gQkv(12, E_EDGES / 32);             // (12, 128) = 1536 blocks
    const dim3 gCls(1, E_EDGES / 64);

    build_adj<<<E_EDGES / 4, 256, 0, stream>>>(src, dst, cand, ccount);

    const float* ef_in = ef;
    for (int L = 0; L < 2; ++L) {
        gemm32<<<g32, 256, 0, stream>>>(nullptr, a_Wn[L], a_bn[L], ef_in, x,
                                        D_EDGE, 2 * D_NODE, nf, src, dst, 0);
        gemm_qkv32<<<gQkv, 256, 0, stream>>>(x, a_Wq[L], a_bq[L], a_Wk[L], a_bk[L],
                                             a_Wv[L], a_bv[L], qb, kb, vb);
        attn_sparse2<<<E_EDGES, 256, 0, stream>>>(qb, kb, vb, cand, ccount, ao);
        gemm32<<<g32, 256, 0, stream>>>(ao, a_Wo[L], a_bo[L], x, y,
                                        D_EDGE, D_EDGE, nullptr, nullptr, nullptr, 0);
        ef_in = y;
    }

    gemm32<<<g32, 256, 0, stream>>>(y, cls_W1, cls_b1, nullptr, hb,
                                    D_EDGE, D_EDGE, nullptr, nullptr, nullptr, 1);
    gemm_small<<<gCls, 256, 0, stream>>>(hb, cls_W2, cls_b2, (float*)d_out,
                                         N_CLASSES, D_EDGE);
}

// Round 8
// 177.374 us; speedup vs baseline: 2.6041x; 1.1962x over previous
//
#include <hip/hip_runtime.h>
#include <math.h>

#define E_EDGES 4096
#define N_NODES 1024
#define D_NODE 128
#define D_EDGE 256
#define HEADS 4
#define HD 64
#define N_CLASSES 16
#define CAP 256   // max adjacent edges per edge (avg ~16)

typedef __attribute__((ext_vector_type(8))) short short8v;  // 8 bf16 = 4 VGPR
typedef __attribute__((ext_vector_type(4))) float f32x4;    // MFMA C/D frag

// f32 -> bf16 RNE (bit trick), bf16 -> f32
__device__ __forceinline__ unsigned short f2bf(float f) {
    unsigned u = __float_as_uint(f);
    return (unsigned short)((u + 0x7FFFu + ((u >> 16) & 1u)) >> 16);
}
__device__ __forceinline__ float bf2f(unsigned short b) {
    return __uint_as_float(((unsigned)b) << 16);
}

// direct-to-LDS 16B DMA (gfx950): HW writes wave-uniform base + lane*16,
// which our per-thread dest (base + t*16) matches exactly.
__device__ __forceinline__ void gload_lds16(const void* g, void* l) {
    __builtin_amdgcn_global_load_lds((const __attribute__((address_space(1))) void*)g,
                                     (__attribute__((address_space(3))) void*)l, 16, 0, 0);
}

// XCD-aware remap: all blocks of an M-panel share one XCD L2 (R5: FETCH
// 17.2 -> 5.2MB on qkv). Requires gridDim.y % 8 == 0.
__device__ __forceinline__ void xcd_remap(int& bx, int& by)
{
    const int nx = gridDim.x;
    const int lid = blockIdx.x + nx * blockIdx.y;
    const int g = lid & 7, s = lid >> 3;
    const int ppx = gridDim.y >> 3;
    by = g * ppx + s / nx;
    bx = s % nx;
}

// ---------------------------------------------------------------------------
// One-time weight prep: split f32 W[k][n] (256x256) into TRANSPOSED bf16
// hi/lo WT[n][k] so the GEMM can stage B fragments with linear LDS DMA.
// Order: a1{Wn,Wq,Wk,Wv,Wo}, a2{...}, cls_W1  -> 11 matrices.
// ---------------------------------------------------------------------------
__global__ __launch_bounds__(256) void split_w(
    const float* W0, const float* W1, const float* W2, const float* W3,
    const float* W4, const float* W5, const float* W6, const float* W7,
    const float* W8, const float* W9, const float* W10,
    short* hiT, short* loT)
{
    const float* Ws[11] = {W0, W1, W2, W3, W4, W5, W6, W7, W8, W9, W10};
    const float* W = Ws[blockIdx.x];
    short* ho = hiT + (size_t)blockIdx.x * 65536;
    short* lo = loT + (size_t)blockIdx.x * 65536;
    const int t = threadIdx.x;
    const int n = blockIdx.y * 16 + (t >> 4);
    const int k0 = (t & 15) * 16;
    short8v h0, h1, l0, l1;
#pragma unroll
    for (int j = 0; j < 8; ++j) {
        const float x = W[(size_t)(k0 + j) * 256 + n];
        const unsigned short hb = f2bf(x);
        h0[j] = (short)hb; l0[j] = (short)f2bf(x - bf2f(hb));
    }
#pragma unroll
    for (int j = 0; j < 8; ++j) {
        const float x = W[(size_t)(k0 + 8 + j) * 256 + n];
        const unsigned short hb = f2bf(x);
        h1[j] = (short)hb; l1[j] = (short)f2bf(x - bf2f(hb));
    }
    *(short8v*)&ho[(size_t)n * 256 + k0] = h0;
    *(short8v*)&ho[(size_t)n * 256 + k0 + 8] = h1;
    *(short8v*)&lo[(size_t)n * 256 + k0] = l0;
    *(short8v*)&lo[(size_t)n * 256 + k0 + 8] = l1;
}

// ---------------------------------------------------------------------------
// Split-bf16 MFMA GEMM: C[64x64] = act(A@B + bias + residual), K=N=256.
// A (f32) split to hi/lo bf16 during staging; B pre-split (WT[n][k] bf16).
// A@B = AhBh + AhBl + AlBh (lo*lo dropped, ~2^-18). 4 waves, each 32x32 out
// = 2x2 mfma_f32_16x16x32_bf16 frags. Double-buffered LDS, ONE barrier per
// K-tile; A global loads issued before MFMA, convert+ds_write after (T14);
// B staged via global_load_lds DMA (lane-linear [n][32]).
// Frag layouts (HW-verified): A row=lane&15,k=(lane>>4)*8+j; B col=lane&15;
// D col=lane&15,row=(lane>>4)*4+i.
// If nf != null: A row m = concat(nf[src[m]], nf[dst[m]]).
// ---------------------------------------------------------------------------
__device__ __forceinline__ void gemm_mfma_core(
    const float* __restrict__ A, const short* __restrict__ BhiT,
    const short* __restrict__ BloT, const float* __restrict__ bias,
    const float* __restrict__ residual, float* __restrict__ C,
    int m0, int n0,
    const float* __restrict__ nf, const int* __restrict__ src,
    const int* __restrict__ dst, int act)
{
    __shared__ short AsH[2][64 * 40];   // [buf][m][kpad40] bf16 hi
    __shared__ short AsL[2][64 * 40];
    __shared__ short BsH[2][64 * 32];   // [buf][n][k32] bf16 hi (DMA linear)
    __shared__ short BsL[2][64 * 32];
    const int t = threadIdx.x;
    const int w = t >> 6, lane = t & 63, lr = lane & 15, lg = lane >> 4;
    const int WR = (w >> 1) * 32, WC = (w & 1) * 32;  // wave's 32x32 out tile
    const int am = t >> 2, akc = (t & 3) * 8;          // A stage coords
    const int bn = t >> 2, bkc = (t & 3) * 8;          // B stage coords

    int nS = 0, nD = 0;
    if (nf) { nS = src[m0 + am]; nD = dst[m0 + am]; }

    f32x4 acc00 = {0.f, 0.f, 0.f, 0.f};
    f32x4 acc01 = acc00, acc10 = acc00, acc11 = acc00;
    float4 av0, av1;

#define LOADA_REG(k0)                                                          \
    do {                                                                       \
        const int kq0 = (k0) + akc, kq1 = kq0 + 4;                             \
        if (nf) {                                                              \
            const float* p0 = (kq0 < D_NODE)                                   \
                ? &nf[(size_t)nS * D_NODE + kq0]                               \
                : &nf[(size_t)nD * D_NODE + kq0 - D_NODE];                     \
            const float* p1 = (kq1 < D_NODE)                                   \
                ? &nf[(size_t)nS * D_NODE + kq1]                               \
                : &nf[(size_t)nD * D_NODE + kq1 - D_NODE];                     \
            av0 = *(const float4*)p0; av1 = *(const float4*)p1;                \
        } else {                                                               \
            av0 = *(const float4*)&A[(size_t)(m0 + am) * 256 + kq0];           \
            av1 = *(const float4*)&A[(size_t)(m0 + am) * 256 + kq1];           \
        }                                                                      \
    } while (0)
#define SPLIT1(f, j)                                                           \
    { const unsigned short hb = f2bf(f); ah[j] = (short)hb;                    \
      al[j] = (short)f2bf((f) - bf2f(hb)); }
#define STOREA_SPLIT(buf)                                                      \
    do {                                                                       \
        short8v ah, al;                                                        \
        SPLIT1(av0.x, 0) SPLIT1(av0.y, 1) SPLIT1(av0.z, 2) SPLIT1(av0.w, 3)    \
        SPLIT1(av1.x, 4) SPLIT1(av1.y, 5) SPLIT1(av1.z, 6) SPLIT1(av1.w, 7)    \
        *(short8v*)&AsH[buf][am * 40 + akc] = ah;                              \
        *(short8v*)&AsL[buf][am * 40 + akc] = al;                              \
    } while (0)
#define STAGE_B(buf, k0)                                                       \
    do {                                                                       \
        gload_lds16(&BhiT[(size_t)(n0 + bn) * 256 + (k0) + bkc],               \
                    (short*)&BsH[buf][0] + t * 8);                             \
        gload_lds16(&BloT[(size_t)(n0 + bn) * 256 + (k0) + bkc],               \
                    (short*)&BsL[buf][0] + t * 8);                             \
    } while (0)
#define MFMA_STEP(buf)                                                         \
    do {                                                                       \
        const int c0 = WC + lr, c1 = WC + 16 + lr;                             \
        const short8v bH0 = *(const short8v*)&BsH[buf][c0 * 32 + lg * 8];      \
        const short8v bL0 = *(const short8v*)&BsL[buf][c0 * 32 + lg * 8];      \
        const short8v bH1 = *(const short8v*)&BsH[buf][c1 * 32 + lg * 8];      \
        const short8v bL1 = *(const short8v*)&BsL[buf][c1 * 32 + lg * 8];      \
        const short8v aH0 = *(const short8v*)&AsH[buf][(WR + lr) * 40 + lg * 8];      \
        const short8v aL0 = *(const short8v*)&AsL[buf][(WR + lr) * 40 + lg * 8];      \
        const short8v aH1 = *(const short8v*)&AsH[buf][(WR + 16 + lr) * 40 + lg * 8]; \
        const short8v aL1 = *(const short8v*)&AsL[buf][(WR + 16 + lr) * 40 + lg * 8]; \
        acc00 = __builtin_amdgcn_mfma_f32_16x16x32_bf16(aH0, bH0, acc00, 0, 0, 0);    \
        acc01 = __builtin_amdgcn_mfma_f32_16x16x32_bf16(aH0, bH1, acc01, 0, 0, 0);    \
        acc10 = __builtin_amdgcn_mfma_f32_16x16x32_bf16(aH1, bH0, acc10, 0, 0, 0);    \
        acc11 = __builtin_amdgcn_mfma_f32_16x16x32_bf16(aH1, bH1, acc11, 0, 0, 0);    \
        acc00 = __builtin_amdgcn_mfma_f32_16x16x32_bf16(aH0, bL0, acc00, 0, 0, 0);    \
        acc01 = __builtin_amdgcn_mfma_f32_16x16x32_bf16(aH0, bL1, acc01, 0, 0, 0);    \
        acc10 = __builtin_amdgcn_mfma_f32_16x16x32_bf16(aH1, bL0, acc10, 0, 0, 0);    \
        acc11 = __builtin_amdgcn_mfma_f32_16x16x32_bf16(aH1, bL1, acc11, 0, 0, 0);    \
        acc00 = __builtin_amdgcn_mfma_f32_16x16x32_bf16(aL0, bH0, acc00, 0, 0, 0);    \
        acc01 = __builtin_amdgcn_mfma_f32_16x16x32_bf16(aL0, bH1, acc01, 0, 0, 0);    \
        acc10 = __builtin_amdgcn_mfma_f32_16x16x32_bf16(aL1, bH0, acc10, 0, 0, 0);    \
        acc11 = __builtin_amdgcn_mfma_f32_16x16x32_bf16(aL1, bH1, acc11, 0, 0, 0);    \
    } while (0)

    // prologue: stage tile 0
    LOADA_REG(0);
    STAGE_B(0, 0);
    STOREA_SPLIT(0);
    __syncthreads();                       // drains DMA vmcnt + lgkm

    for (int kt = 0; kt < 8; ++kt) {       // K = 256 = 8 x 32
        const int cur = kt & 1;
        if (kt < 7) {
            STAGE_B(cur ^ 1, (kt + 1) * 32);   // async DMA
            LOADA_REG((kt + 1) * 32);          // issue f32 loads early (T14)
        }
        MFMA_STEP(cur);
        if (kt < 7) STOREA_SPLIT(cur ^ 1);     // convert + ds_write late
        __syncthreads();
    }

#define EPI(accv, rt, ct)                                                      \
    do {                                                                       \
        const int col = n0 + WC + (ct) * 16 + lr;                              \
        const float bb = bias ? bias[col] : 0.f;                               \
        _Pragma("unroll") for (int i = 0; i < 4; ++i) {                        \
            const int row = m0 + WR + (rt) * 16 + lg * 4 + i;                  \
            float v = accv[i] + bb;                                            \
            if (residual) v += residual[(size_t)row * D_EDGE + col];           \
            if (act == 1) v = 0.5f * v * (1.f + erff(v * 0.70710678118654752f)); \
            C[(size_t)row * D_EDGE + col] = v;                                 \
        }                                                                      \
    } while (0)
    EPI(acc00, 0, 0); EPI(acc01, 0, 1); EPI(acc10, 1, 0); EPI(acc11, 1, 1);
#undef LOADA_REG
#undef SPLIT1
#undef STOREA_SPLIT
#undef STAGE_B
#undef MFMA_STEP
#undef EPI
}

__global__ __launch_bounds__(256) void gemm_mfma(
    const float* __restrict__ A, const short* __restrict__ BhiT,
    const short* __restrict__ BloT, const float* __restrict__ bias,
    const float* __restrict__ residual, float* __restrict__ C,
    const float* __restrict__ nf, const int* __restrict__ src,
    const int* __restrict__ dst, int act)
{
    int bx = blockIdx.x, by = blockIdx.y;
    xcd_remap(bx, by);
    gemm_mfma_core(A, BhiT, BloT, bias, residual, C, by * 64, bx * 64,
                   nf, src, dst, act);
}

// q/k/v fused: grid (12, 64); after remap bx>>2 selects matrix, bx&3 the
// n-tile. 768 blocks at 4 blocks/CU cap -> single residency pass.
__global__ __launch_bounds__(256) void gemm_mfma_qkv(
    const float* __restrict__ x, const short* __restrict__ whiT,
    const short* __restrict__ wloT,
    const float* __restrict__ bq, const float* __restrict__ bk,
    const float* __restrict__ bv,
    float* __restrict__ qb, float* __restrict__ kb, float* __restrict__ vb,
    int wbase)
{
    int bx = blockIdx.x, by = blockIdx.y;
    xcd_remap(bx, by);
    const int wsel = bx >> 2, nt = bx & 3;
    const short* BH = whiT + (size_t)(wbase + 1 + wsel) * 65536;
    const short* BL = wloT + (size_t)(wbase + 1 + wsel) * 65536;
    const float* bias = (wsel == 0) ? bq : (wsel == 1) ? bk : bv;
    float* C = (wsel == 0) ? qb : (wsel == 1) ? kb : vb;
    gemm_mfma_core(x, BH, BL, bias, nullptr, C, by * 64, nt * 64,
                   nullptr, nullptr, nullptr, 0);
}

// ---------------------------------------------------------------------------
// Small guarded f32 GEMM (classifier head, N=16).
// ---------------------------------------------------------------------------
__global__ __launch_bounds__(256) void gemm_small(
    const float* __restrict__ A, const float* __restrict__ B,
    const float* __restrict__ bias, float* __restrict__ C, int N, int K)
{
    __shared__ float As[32][68];
    __shared__ float Bs[32][68];
    const int t = threadIdx.x;
    const int tx = t & 15, ty = t >> 4;
    const int m0 = blockIdx.y * 64, n0 = 0;
    const int ar0 = t >> 3, ak0 = (t & 7) * 4;
    const int br0 = t >> 4, nc = (t & 15) * 4;
    float acc[4][4] = {};

    for (int k0 = 0; k0 < K; k0 += 32) {
        float4 a0 = *(const float4*)&A[(size_t)(m0 + ar0) * K + k0 + ak0];
        float4 a1 = *(const float4*)&A[(size_t)(m0 + ar0 + 32) * K + k0 + ak0];
        float4 b0 = make_float4(0.f, 0.f, 0.f, 0.f), b1 = b0;
        if (n0 + nc < N) {
            b0 = *(const float4*)&B[(size_t)(k0 + br0) * N + n0 + nc];
            b1 = *(const float4*)&B[(size_t)(k0 + br0 + 16) * N + n0 + nc];
        }
        As[ak0 + 0][ar0] = a0.x; As[ak0 + 1][ar0] = a0.y;
        As[ak0 + 2][ar0] = a0.z; As[ak0 + 3][ar0] = a0.w;
        As[ak0 + 0][ar0 + 32] = a1.x; As[ak0 + 1][ar0 + 32] = a1.y;
        As[ak0 + 2][ar0 + 32] = a1.z; As[ak0 + 3][ar0 + 32] = a1.w;
        *(float4*)&Bs[br0][nc] = b0; *(float4*)&Bs[br0 + 16][nc] = b1;
        __syncthreads();
#pragma unroll
        for (int kk = 0; kk < 32; ++kk) {
            const float4 av = *(const float4*)&As[kk][ty * 4];
            const float4 bv = *(const float4*)&Bs[kk][tx * 4];
            const float a_[4] = {av.x, av.y, av.z, av.w};
            const float b_[4] = {bv.x, bv.y, bv.z, bv.w};
#pragma unroll
            for (int i = 0; i < 4; ++i)
#pragma unroll
                for (int j = 0; j < 4; ++j) acc[i][j] += a_[i] * b_[j];
        }
        __syncthreads();
    }

#pragma unroll
    for (int i = 0; i < 4; ++i) {
        const int row = m0 + ty * 4 + i;
        const int col = n0 + tx * 4;
        if (col < N) {
            float4 r = make_float4(acc[i][0], acc[i][1], acc[i][2], acc[i][3]);
            const float4 bb = *(const float4*)&bias[col];
            r.x += bb.x; r.y += bb.y; r.z += bb.z; r.w += bb.w;
            *(float4*)&C[(size_t)row * N + col] = r;
        }
    }
}

// ---------------------------------------------------------------------------
// One-time adjacency build: wave per query edge, ballot-compaction ascending.
// ---------------------------------------------------------------------------
__global__ __launch_bounds__(256) void build_adj(
    const int* __restrict__ src, const int* __restrict__ dst,
    int* __restrict__ cand, int* __restrict__ ccount)
{
    const int w = threadIdx.x >> 6, lane = threadIdx.x & 63;
    const int e = blockIdx.x * 4 + w;
    const int a = src[e], b = dst[e];
    int* my = cand + (size_t)e * CAP;
    int base = 0;
    for (int c0 = 0; c0 < E_EDGES; c0 += 64) {
        const int f = c0 + lane;
        const int sf = src[f], df = dst[f];
        const bool adj = (sf == a) | (sf == b) | (df == a) | (df == b);
        const unsigned long long mk = __ballot(adj);
        if (adj) {
            const int pos = base + __popcll(mk & ((1ull << lane) - 1ull));
            if (pos < CAP) my[pos] = f;
        }
        base += __popcll(mk);
    }
    if (lane == 0) ccount[e] = (base < CAP) ? base : CAP;
}

// ---------------------------------------------------------------------------
// Sparse attention from prebuilt lists. Block = edge, wave = head, lane = dim.
// One-pass online softmax (expf(-1e9-max)==0 => sparse == dense-masked).
// ---------------------------------------------------------------------------
__global__ __launch_bounds__(256) void attn_sparse2(
    const float* __restrict__ q, const float* __restrict__ k,
    const float* __restrict__ v, const int* __restrict__ cand,
    const int* __restrict__ ccount, float* __restrict__ out)
{
    __shared__ int lc[CAP];
    const int e = blockIdx.x;
    const int t = threadIdx.x, h = t >> 6, lane = t & 63;
    const int m = ccount[e];
    if (t < m) lc[t] = cand[(size_t)e * CAP + t];
    __syncthreads();

    const float qd = q[e * D_EDGE + h * HD + lane];
    float M = -1e30f, L = 0.f, O = 0.f;
    int i = 0;
    for (; i + 2 <= m; i += 2) {
        const int f0 = lc[i], f1 = lc[i + 1];
        const float kd0 = k[f0 * D_EDGE + h * HD + lane];
        const float vd0 = v[f0 * D_EDGE + h * HD + lane];
        const float kd1 = k[f1 * D_EDGE + h * HD + lane];
        const float vd1 = v[f1 * D_EDGE + h * HD + lane];
        float s0 = qd * kd0, s1 = qd * kd1;
#pragma unroll
        for (int off = 32; off; off >>= 1) {
            s0 += __shfl_xor(s0, off);
            s1 += __shfl_xor(s1, off);
        }
        s0 *= 0.125f; s1 *= 0.125f;
        const float Mn = fmaxf(M, fmaxf(s0, s1));
        const float alpha = __expf(M - Mn);
        const float p0 = __expf(s0 - Mn), p1 = __expf(s1 - Mn);
        O = O * alpha + p0 * vd0 + p1 * vd1;
        L = L * alpha + p0 + p1;
        M = Mn;
    }
    if (i < m) {
        const int f = lc[i];
        const float kd = k[f * D_EDGE + h * HD + lane];
        const float vd = v[f * D_EDGE + h * HD + lane];
        float s = qd * kd;
#pragma unroll
        for (int off = 32; off; off >>= 1) s += __shfl_xor(s, off);
        s *= 0.125f;
        const float Mn = fmaxf(M, s);
        const float alpha = __expf(M - Mn);
        const float p = __expf(s - Mn);
        O = O * alpha + p * vd;
        L = L * alpha + p;
        M = Mn;
    }
    out[e * D_EDGE + h * HD + lane] = O / L;
}

// ---------------------------------------------------------------------------
extern "C" void kernel_launch(void* const* d_in, const int* in_sizes, int n_in,
                              void* d_out, int out_size, void* d_ws, size_t ws_size,
                              hipStream_t stream)
{
    const float* nf = (const float*)d_in[0];
    const float* ef = (const float*)d_in[1];
    const int* ei = (const int*)d_in[2];
    const int* src = ei;
    const int* dst = ei + E_EDGES;

    const float* a_Wn[2] = {(const float*)d_in[3],  (const float*)d_in[13]};
    const float* a_bn[2] = {(const float*)d_in[4],  (const float*)d_in[14]};
    const float* a_Wq[2] = {(const float*)d_in[5],  (const float*)d_in[15]};
    const float* a_bq[2] = {(const float*)d_in[6],  (const float*)d_in[16]};
    const float* a_Wk[2] = {(const float*)d_in[7],  (const float*)d_in[17]};
    const float* a_bk[2] = {(const float*)d_in[8],  (const float*)d_in[18]};
    const float* a_Wv[2] = {(const float*)d_in[9],  (const float*)d_in[19]};
    const float* a_bv[2] = {(const float*)d_in[10], (const float*)d_in[20]};
    const float* a_Wo[2] = {(const float*)d_in[11], (const float*)d_in[21]};
    const float* a_bo[2] = {(const float*)d_in[12], (const float*)d_in[22]};
    const float* cls_W1 = (const float*)d_in[23];
    const float* cls_b1 = (const float*)d_in[24];
    const float* cls_W2 = (const float*)d_in[25];
    const float* cls_b2 = (const float*)d_in[26];

    const size_t buf = (size_t)E_EDGES * D_EDGE;  // 1M floats = 4MB
    float* ws = (float*)d_ws;
    float* x  = ws + 0 * buf;
    float* qb = ws + 1 * buf;
    float* kb = ws + 2 * buf;
    float* vb = ws + 3 * buf;
    float* ao = ws + 4 * buf;
    float* y  = ws + 5 * buf;
    float* hb = ws + 6 * buf;           // classifier scratch (post-attn)
    int* cand   = (int*)(ws + 6 * buf); // alias hb: cand dead before hb write
    int* ccount = (int*)(ws + 7 * buf); // 16KB
    short* whiT = (short*)(ws + 7 * buf + 4096);      // 11 x 128KB bf16
    short* wloT = whiT + (size_t)11 * 65536;          // 11 x 128KB bf16

    const dim3 gGemm(D_EDGE / 64, E_EDGES / 64);   // (4, 64) = 256 blocks
    const dim3 gQkv(12, E_EDGES / 64);             // (12, 64) = 768 blocks
    const dim3 gCls(1, E_EDGES / 64);
    const dim3 gSplit(11, 16);

    split_w<<<gSplit, 256, 0, stream>>>(
        a_Wn[0], a_Wq[0], a_Wk[0], a_Wv[0], a_Wo[0],
        a_Wn[1], a_Wq[1], a_Wk[1], a_Wv[1], a_Wo[1],
        cls_W1, whiT, wloT);
    build_adj<<<E_EDGES / 4, 256, 0, stream>>>(src, dst, cand, ccount);

    const float* ef_in = ef;
    for (int L = 0; L < 2; ++L) {
        const int wbase = L * 5;
        // x = ef_in + concat(nf[src],nf[dst]) @ Wn + bn
        gemm_mfma<<<gGemm, 256, 0, stream>>>(
            nullptr, whiT + (size_t)wbase * 65536, wloT + (size_t)wbase * 65536,
            a_bn[L], ef_in, x, nf, src, dst, 0);
        gemm_mfma_qkv<<<gQkv, 256, 0, stream>>>(
            x, whiT, wloT, a_bq[L], a_bk[L], a_bv[L], qb, kb, vb, wbase);
        attn_sparse2<<<E_EDGES, 256, 0, stream>>>(qb, kb, vb, cand, ccount, ao);
        // y = x + ao @ Wo + bo
        gemm_mfma<<<gGemm, 256, 0, stream>>>(
            ao, whiT + (size_t)(wbase + 4) * 65536, wloT + (size_t)(wbase + 4) * 65536,
            a_bo[L], x, y, nullptr, nullptr, nullptr, 0);
        ef_in = y;
    }

    // h = gelu(y @ W1 + b1); out = h @ W2 + b2
    gemm_mfma<<<gGemm, 256, 0, stream>>>(
        y, whiT + (size_t)10 * 65536, wloT + (size_t)10 * 65536,
        cls_b1, nullptr, hb, nullptr, nullptr, nullptr, 1);
    gemm_small<<<gCls, 256, 0, stream>>>(hb, cls_W2, cls_b2, (float*)d_out,
                                         N_CLASSES, D_EDGE);
}

// Round 9
// 151.513 us; speedup vs baseline: 3.0486x; 1.1707x over previous
//
#include <hip/hip_runtime.h>
#include <math.h>

#define E_EDGES 4096
#define N_NODES 1024
#define D_NODE 128
#define D_EDGE 256
#define HEADS 4
#define HD 64
#define N_CLASSES 16
#define CAP 128   // max adjacent edges per edge (avg ~16, worst ~50)

typedef __attribute__((ext_vector_type(8))) short short8v;  // 8 bf16 = 4 VGPR
typedef __attribute__((ext_vector_type(4))) float f32x4;    // MFMA C/D frag

__device__ __forceinline__ unsigned short f2bf(float f) {
    unsigned u = __float_as_uint(f);
    return (unsigned short)((u + 0x7FFFu + ((u >> 16) & 1u)) >> 16);
}
__device__ __forceinline__ float bf2f(unsigned short b) {
    return __uint_as_float(((unsigned)b) << 16);
}

// direct-to-LDS 16B DMA (gfx950): per-wave dest = uniform base + lane*16,
// matched by our per-thread dest (base + t*16).
__device__ __forceinline__ void gload_lds16(const void* g, void* l) {
    __builtin_amdgcn_global_load_lds((const __attribute__((address_space(1))) void*)g,
                                     (__attribute__((address_space(3))) void*)l, 16, 0, 0);
}

// XCD-aware remap (R5: qkv FETCH 17.2 -> 5.2MB). Requires gridDim.y % 8 == 0.
__device__ __forceinline__ void xcd_remap(int& bx, int& by)
{
    const int nx = gridDim.x;
    const int lid = blockIdx.x + nx * blockIdx.y;
    const int g = lid & 7, s = lid >> 3;
    const int ppx = gridDim.y >> 3;
    by = g * ppx + s / nx;
    bx = s % nx;
}

// ---------------------------------------------------------------------------
// Prep (one dispatch): blocks 0..175 split 11 f32 W[k][n] (256x256) into
// TRANSPOSED bf16 hi/lo WT[n][k]; blocks 176..1199 build adjacency CSR
// (wave per edge, ballot-compaction ascending).
// Weight order: a1{Wn,Wq,Wk,Wv,Wo}, a2{...}, cls_W1.
// ---------------------------------------------------------------------------
__global__ __launch_bounds__(256) void prep(
    const float* W0, const float* W1, const float* W2, const float* W3,
    const float* W4, const float* W5, const float* W6, const float* W7,
    const float* W8, const float* W9, const float* W10,
    short* hiT, short* loT,
    const int* __restrict__ src, const int* __restrict__ dst,
    int* __restrict__ cand, int* __restrict__ ccount)
{
    const int t = threadIdx.x;
    if (blockIdx.x < 176) {
        const float* Ws[11] = {W0, W1, W2, W3, W4, W5, W6, W7, W8, W9, W10};
        const int mat = blockIdx.x % 11, byy = blockIdx.x / 11;
        const float* W = Ws[mat];
        short* ho = hiT + (size_t)mat * 65536;
        short* lo = loT + (size_t)mat * 65536;
        const int n = byy * 16 + (t >> 4);
        const int k0 = (t & 15) * 16;
        short8v h0, h1, l0, l1;
#pragma unroll
        for (int j = 0; j < 8; ++j) {
            const float x = W[(size_t)(k0 + j) * 256 + n];
            const unsigned short hb = f2bf(x);
            h0[j] = (short)hb; l0[j] = (short)f2bf(x - bf2f(hb));
        }
#pragma unroll
        for (int j = 0; j < 8; ++j) {
            const float x = W[(size_t)(k0 + 8 + j) * 256 + n];
            const unsigned short hb = f2bf(x);
            h1[j] = (short)hb; l1[j] = (short)f2bf(x - bf2f(hb));
        }
        *(short8v*)&ho[(size_t)n * 256 + k0] = h0;
        *(short8v*)&ho[(size_t)n * 256 + k0 + 8] = h1;
        *(short8v*)&lo[(size_t)n * 256 + k0] = l0;
        *(short8v*)&lo[(size_t)n * 256 + k0 + 8] = l1;
    } else {
        const int w = t >> 6, lane = t & 63;
        const int e = (blockIdx.x - 176) * 4 + w;
        const int a = src[e], b = dst[e];
        int* my = cand + (size_t)e * CAP;
        int base = 0;
        for (int c0 = 0; c0 < E_EDGES; c0 += 64) {
            const int f = c0 + lane;
            const int sf = src[f], df = dst[f];
            const bool adj = (sf == a) | (sf == b) | (df == a) | (df == b);
            const unsigned long long mk = __ballot(adj);
            if (adj) {
                const int pos = base + __popcll(mk & ((1ull << lane) - 1ull));
                if (pos < CAP) my[pos] = f;
            }
            base += __popcll(mk);
        }
        if (lane == 0) ccount[e] = (base < CAP) ? base : CAP;
    }
}

// ---------------------------------------------------------------------------
// Split-bf16 MFMA GEMM core: C[64x64] = act((A[+A2])@B + bias + res + res2),
// K = 256. A@B = AhBh + AhBl + AlBh (lo*lo ~2^-18 dropped). 4 waves x 2x2
// mfma_f32_16x16x32_bf16 frags. Dbuf LDS, ONE barrier/K-tile; A loads issued
// before MFMA, split+ds_write after (T14); B via global_load_lds DMA.
// If nf != null: A row m = concat(nf[src[m]], nf[dst[m]]).
// ---------------------------------------------------------------------------
__device__ __forceinline__ void gemm_mfma_core(
    const float* __restrict__ A, const float* __restrict__ A2,
    const short* __restrict__ BhiT, const short* __restrict__ BloT,
    const float* __restrict__ bias, const float* __restrict__ residual,
    const float* __restrict__ residual2, float* __restrict__ C,
    int m0, int n0,
    const float* __restrict__ nf, const int* __restrict__ src,
    const int* __restrict__ dst, int act)
{
    __shared__ short AsH[2][64 * 40];   // [buf][m][kpad40] bf16 hi
    __shared__ short AsL[2][64 * 40];
    __shared__ short BsH[2][64 * 32];   // [buf][n][k32] (DMA linear)
    __shared__ short BsL[2][64 * 32];
    const int t = threadIdx.x;
    const int w = t >> 6, lane = t & 63, lr = lane & 15, lg = lane >> 4;
    const int WR = (w >> 1) * 32, WC = (w & 1) * 32;
    const int am = t >> 2, akc = (t & 3) * 8;
    const int bn = t >> 2, bkc = (t & 3) * 8;

    int nS = 0, nD = 0;
    if (nf) { nS = src[m0 + am]; nD = dst[m0 + am]; }

    f32x4 acc00 = {0.f, 0.f, 0.f, 0.f};
    f32x4 acc01 = acc00, acc10 = acc00, acc11 = acc00;
    float4 av0, av1;

#define LOADA_REG(k0)                                                          \
    do {                                                                       \
        const int kq0 = (k0) + akc, kq1 = kq0 + 4;                             \
        if (nf) {                                                              \
            const float* p0 = (kq0 < D_NODE)                                   \
                ? &nf[(size_t)nS * D_NODE + kq0]                               \
                : &nf[(size_t)nD * D_NODE + kq0 - D_NODE];                     \
            const float* p1 = (kq1 < D_NODE)                                   \
                ? &nf[(size_t)nS * D_NODE + kq1]                               \
                : &nf[(size_t)nD * D_NODE + kq1 - D_NODE];                     \
            av0 = *(const float4*)p0; av1 = *(const float4*)p1;                \
        } else {                                                               \
            av0 = *(const float4*)&A[(size_t)(m0 + am) * 256 + kq0];           \
            av1 = *(const float4*)&A[(size_t)(m0 + am) * 256 + kq1];           \
            if (A2) {                                                          \
                const float4 c0_ = *(const float4*)&A2[(size_t)(m0 + am) * 256 + kq0]; \
                const float4 c1_ = *(const float4*)&A2[(size_t)(m0 + am) * 256 + kq1]; \
                av0.x += c0_.x; av0.y += c0_.y; av0.z += c0_.z; av0.w += c0_.w; \
                av1.x += c1_.x; av1.y += c1_.y; av1.z += c1_.z; av1.w += c1_.w; \
            }                                                                  \
        }                                                                      \
    } while (0)
#define SPLIT1(f, j)                                                           \
    { const unsigned short hb = f2bf(f); ah[j] = (short)hb;                    \
      al[j] = (short)f2bf((f) - bf2f(hb)); }
#define STOREA_SPLIT(buf)                                                      \
    do {                                                                       \
        short8v ah, al;                                                        \
        SPLIT1(av0.x, 0) SPLIT1(av0.y, 1) SPLIT1(av0.z, 2) SPLIT1(av0.w, 3)    \
        SPLIT1(av1.x, 4) SPLIT1(av1.y, 5) SPLIT1(av1.z, 6) SPLIT1(av1.w, 7)    \
        *(short8v*)&AsH[buf][am * 40 + akc] = ah;                              \
        *(short8v*)&AsL[buf][am * 40 + akc] = al;                              \
    } while (0)
#define STAGE_B(buf, k0)                                                       \
    do {                                                                       \
        gload_lds16(&BhiT[(size_t)(n0 + bn) * 256 + (k0) + bkc],               \
                    (short*)&BsH[buf][0] + t * 8);                             \
        gload_lds16(&BloT[(size_t)(n0 + bn) * 256 + (k0) + bkc],               \
                    (short*)&BsL[buf][0] + t * 8);                             \
    } while (0)
#define MFMA_STEP(buf)                                                         \
    do {                                                                       \
        const int c0 = WC + lr, c1 = WC + 16 + lr;                             \
        const short8v bH0 = *(const short8v*)&BsH[buf][c0 * 32 + lg * 8];      \
        const short8v bL0 = *(const short8v*)&BsL[buf][c0 * 32 + lg * 8];      \
        const short8v bH1 = *(const short8v*)&BsH[buf][c1 * 32 + lg * 8];      \
        const short8v bL1 = *(const short8v*)&BsL[buf][c1 * 32 + lg * 8];      \
        const short8v aH0 = *(const short8v*)&AsH[buf][(WR + lr) * 40 + lg * 8];      \
        const short8v aL0 = *(const short8v*)&AsL[buf][(WR + lr) * 40 + lg * 8];      \
        const short8v aH1 = *(const short8v*)&AsH[buf][(WR + 16 + lr) * 40 + lg * 8]; \
        const short8v aL1 = *(const short8v*)&AsL[buf][(WR + 16 + lr) * 40 + lg * 8]; \
        acc00 = __builtin_amdgcn_mfma_f32_16x16x32_bf16(aH0, bH0, acc00, 0, 0, 0);    \
        acc01 = __builtin_amdgcn_mfma_f32_16x16x32_bf16(aH0, bH1, acc01, 0, 0, 0);    \
        acc10 = __builtin_amdgcn_mfma_f32_16x16x32_bf16(aH1, bH0, acc10, 0, 0, 0);    \
        acc11 = __builtin_amdgcn_mfma_f32_16x16x32_bf16(aH1, bH1, acc11, 0, 0, 0);    \
        acc00 = __builtin_amdgcn_mfma_f32_16x16x32_bf16(aH0, bL0, acc00, 0, 0, 0);    \
        acc01 = __builtin_amdgcn_mfma_f32_16x16x32_bf16(aH0, bL1, acc01, 0, 0, 0);    \
        acc10 = __builtin_amdgcn_mfma_f32_16x16x32_bf16(aH1, bL0, acc10, 0, 0, 0);    \
        acc11 = __builtin_amdgcn_mfma_f32_16x16x32_bf16(aH1, bL1, acc11, 0, 0, 0);    \
        acc00 = __builtin_amdgcn_mfma_f32_16x16x32_bf16(aL0, bH0, acc00, 0, 0, 0);    \
        acc01 = __builtin_amdgcn_mfma_f32_16x16x32_bf16(aL0, bH1, acc01, 0, 0, 0);    \
        acc10 = __builtin_amdgcn_mfma_f32_16x16x32_bf16(aL1, bH0, acc10, 0, 0, 0);    \
        acc11 = __builtin_amdgcn_mfma_f32_16x16x32_bf16(aL1, bH1, acc11, 0, 0, 0);    \
    } while (0)

    LOADA_REG(0);
    STAGE_B(0, 0);
    STOREA_SPLIT(0);
    __syncthreads();

    for (int kt = 0; kt < 8; ++kt) {       // K = 256 = 8 x 32
        const int cur = kt & 1;
        if (kt < 7) {
            STAGE_B(cur ^ 1, (kt + 1) * 32);
            LOADA_REG((kt + 1) * 32);
        }
        MFMA_STEP(cur);
        if (kt < 7) STOREA_SPLIT(cur ^ 1);
        __syncthreads();
    }

#define EPI(accv, rt, ct)                                                      \
    do {                                                                       \
        const int col = n0 + WC + (ct) * 16 + lr;                              \
        const float bb = bias ? bias[col] : 0.f;                               \
        _Pragma("unroll") for (int i = 0; i < 4; ++i) {                        \
            const int row = m0 + WR + (rt) * 16 + lg * 4 + i;                  \
            float v = accv[i] + bb;                                            \
            if (residual) v += residual[(size_t)row * D_EDGE + col];           \
            if (residual2) v += residual2[(size_t)row * D_EDGE + col];         \
            if (act == 1) v = 0.5f * v * (1.f + erff(v * 0.70710678118654752f)); \
            C[(size_t)row * D_EDGE + col] = v;                                 \
        }                                                                      \
    } while (0)
    EPI(acc00, 0, 0); EPI(acc01, 0, 1); EPI(acc10, 1, 0); EPI(acc11, 1, 1);
#undef LOADA_REG
#undef SPLIT1
#undef STOREA_SPLIT
#undef STAGE_B
#undef MFMA_STEP
#undef EPI
}

// ctx precompute, BOTH layers in one dispatch: grid (4, 128); by<64 layer1.
// ctx_L = concat(nf[src],nf[dst]) @ Wn_L + bn_L.
__global__ __launch_bounds__(256) void gemm_ctx(
    const float* __restrict__ nf, const int* __restrict__ src,
    const int* __restrict__ dst, const short* __restrict__ whiT,
    const short* __restrict__ wloT, const float* __restrict__ bn1,
    const float* __restrict__ bn2, float* __restrict__ ctx)
{
    int bx = blockIdx.x, by = blockIdx.y;
    xcd_remap(bx, by);
    const int Lyr = by >> 6, rb = by & 63;
    const short* BH = whiT + (size_t)(Lyr * 5) * 65536;
    const short* BL = wloT + (size_t)(Lyr * 5) * 65536;
    gemm_mfma_core(nullptr, nullptr, BH, BL, Lyr ? bn2 : bn1,
                   nullptr, nullptr, ctx + (size_t)Lyr * E_EDGES * D_EDGE,
                   rb * 64, bx * 64, nf, src, dst, 0);
}

// generic (Wo / cls1): A [+A2] @ W + bias + residual [+residual2]
__global__ __launch_bounds__(256) void gemm_mfma(
    const float* __restrict__ A, const float* __restrict__ A2,
    const short* __restrict__ BhiT, const short* __restrict__ BloT,
    const float* __restrict__ bias, const float* __restrict__ residual,
    const float* __restrict__ residual2, float* __restrict__ C, int act)
{
    int bx = blockIdx.x, by = blockIdx.y;
    xcd_remap(bx, by);
    gemm_mfma_core(A, A2, BhiT, BloT, bias, residual, residual2, C,
                   by * 64, bx * 64, nullptr, nullptr, nullptr, act);
}

// q/k/v fused, x = ef_in + ctx formed on the fly in A-staging.
__global__ __launch_bounds__(256) void gemm_mfma_qkv(
    const float* __restrict__ ef_in, const float* __restrict__ ctx,
    const short* __restrict__ whiT, const short* __restrict__ wloT,
    const float* __restrict__ bq, const float* __restrict__ bk,
    const float* __restrict__ bv,
    float* __restrict__ qb, float* __restrict__ kb, float* __restrict__ vb,
    int wbase)
{
    int bx = blockIdx.x, by = blockIdx.y;
    xcd_remap(bx, by);
    const int wsel = bx >> 2, nt = bx & 3;
    const short* BH = whiT + (size_t)(wbase + 1 + wsel) * 65536;
    const short* BL = wloT + (size_t)(wbase + 1 + wsel) * 65536;
    const float* bias = (wsel == 0) ? bq : (wsel == 1) ? bk : bv;
    float* C = (wsel == 0) ? qb : (wsel == 1) ? kb : vb;
    gemm_mfma_core(ef_in, ctx, BH, BL, bias, nullptr, nullptr, C,
                   by * 64, nt * 64, nullptr, nullptr, nullptr, 0);
}

// ---------------------------------------------------------------------------
// Sparse attention v3. Block = edge, wave = head. Wave splits into 4 groups
// of 16 lanes; each group processes one candidate per iteration with float4
// k/v gathers (lane = 4 dims): dot = 4 FMA + 4 shfl (16-lane), 4 candidates
// per iteration, online softmax state wave-uniform via 4 lane-broadcasts.
// Final O = sum of 4 group partials (2 shfl_xor steps). expf(-1e9-max)==0
// keeps sparse == dense-masked semantics.
// ---------------------------------------------------------------------------
__global__ __launch_bounds__(256) void attn_sparse3(
    const float* __restrict__ q, const float* __restrict__ k,
    const float* __restrict__ v, const int* __restrict__ cand,
    const int* __restrict__ ccount, float* __restrict__ out)
{
    __shared__ int lc[CAP];
    const int e = blockIdx.x;
    const int t = threadIdx.x, h = t >> 6, lane = t & 63;
    const int g = lane >> 4, il = lane & 15;
    const int m = ccount[e];
    if (t < m) lc[t] = cand[(size_t)e * CAP + t];
    __syncthreads();

    const float4 q4 = *(const float4*)&q[(size_t)e * D_EDGE + h * HD + il * 4];
    float M = -1e30f, L = 0.f;
    float4 O = make_float4(0.f, 0.f, 0.f, 0.f);

    for (int i0 = 0; i0 < m; i0 += 4) {
        const int ci = i0 + g;
        const bool valid = ci < m;
        float4 k4 = make_float4(0.f, 0.f, 0.f, 0.f), v4 = k4;
        if (valid) {
            const int f = lc[ci];
            k4 = *(const float4*)&k[(size_t)f * D_EDGE + h * HD + il * 4];
            v4 = *(const float4*)&v[(size_t)f * D_EDGE + h * HD + il * 4];
        }
        float sc = q4.x * k4.x + q4.y * k4.y + q4.z * k4.z + q4.w * k4.w;
        sc += __shfl_xor(sc, 1);
        sc += __shfl_xor(sc, 2);
        sc += __shfl_xor(sc, 4);
        sc += __shfl_xor(sc, 8);
        const float s_own = valid ? sc * 0.125f : -1e30f;
        const float s0 = __shfl(s_own, 0);
        const float s1 = __shfl(s_own, 16);
        const float s2 = __shfl(s_own, 32);
        const float s3 = __shfl(s_own, 48);
        const float Mn = fmaxf(M, fmaxf(fmaxf(s0, s1), fmaxf(s2, s3)));
        const float alpha = __expf(M - Mn);
        const float p0 = __expf(s0 - Mn), p1 = __expf(s1 - Mn);
        const float p2 = __expf(s2 - Mn), p3 = __expf(s3 - Mn);
        const float p_own = (g == 0) ? p0 : (g == 1) ? p1 : (g == 2) ? p2 : p3;
        O.x = O.x * alpha + p_own * v4.x;
        O.y = O.y * alpha + p_own * v4.y;
        O.z = O.z * alpha + p_own * v4.z;
        O.w = O.w * alpha + p_own * v4.w;
        L = L * alpha + (p0 + p1 + p2 + p3);
        M = Mn;
    }
    // sum group partials
    O.x += __shfl_xor(O.x, 16); O.y += __shfl_xor(O.y, 16);
    O.z += __shfl_xor(O.z, 16); O.w += __shfl_xor(O.w, 16);
    O.x += __shfl_xor(O.x, 32); O.y += __shfl_xor(O.y, 32);
    O.z += __shfl_xor(O.z, 32); O.w += __shfl_xor(O.w, 32);
    if (lane < 16) {
        const float invL = 1.f / L;
        float4 r = make_float4(O.x * invL, O.y * invL, O.z * invL, O.w * invL);
        *(float4*)&out[(size_t)e * D_EDGE + h * HD + il * 4] = r;
    }
}

// ---------------------------------------------------------------------------
// Small guarded f32 GEMM (classifier head, N=16).
// ---------------------------------------------------------------------------
__global__ __launch_bounds__(256) void gemm_small(
    const float* __restrict__ A, const float* __restrict__ B,
    const float* __restrict__ bias, float* __restrict__ C, int N, int K)
{
    __shared__ float As[32][68];
    __shared__ float Bs[32][68];
    const int t = threadIdx.x;
    const int tx = t & 15, ty = t >> 4;
    const int m0 = blockIdx.y * 64, n0 = 0;
    const int ar0 = t >> 3, ak0 = (t & 7) * 4;
    const int br0 = t >> 4, nc = (t & 15) * 4;
    float acc[4][4] = {};

    for (int k0 = 0; k0 < K; k0 += 32) {
        float4 a0 = *(const float4*)&A[(size_t)(m0 + ar0) * K + k0 + ak0];
        float4 a1 = *(const float4*)&A[(size_t)(m0 + ar0 + 32) * K + k0 + ak0];
        float4 b0 = make_float4(0.f, 0.f, 0.f, 0.f), b1 = b0;
        if (n0 + nc < N) {
            b0 = *(const float4*)&B[(size_t)(k0 + br0) * N + n0 + nc];
            b1 = *(const float4*)&B[(size_t)(k0 + br0 + 16) * N + n0 + nc];
        }
        As[ak0 + 0][ar0] = a0.x; As[ak0 + 1][ar0] = a0.y;
        As[ak0 + 2][ar0] = a0.z; As[ak0 + 3][ar0] = a0.w;
        As[ak0 + 0][ar0 + 32] = a1.x; As[ak0 + 1][ar0 + 32] = a1.y;
        As[ak0 + 2][ar0 + 32] = a1.z; As[ak0 + 3][ar0 + 32] = a1.w;
        *(float4*)&Bs[br0][nc] = b0; *(float4*)&Bs[br0 + 16][nc] = b1;
        __syncthreads();
#pragma unroll
        for (int kk = 0; kk < 32; ++kk) {
            const float4 av = *(const float4*)&As[kk][ty * 4];
            const float4 bv = *(const float4*)&Bs[kk][tx * 4];
            const float a_[4] = {av.x, av.y, av.z, av.w};
            const float b_[4] = {bv.x, bv.y, bv.z, bv.w};
#pragma unroll
            for (int i = 0; i < 4; ++i)
#pragma unroll
                for (int j = 0; j < 4; ++j) acc[i][j] += a_[i] * b_[j];
        }
        __syncthreads();
    }

#pragma unroll
    for (int i = 0; i < 4; ++i) {
        const int row = m0 + ty * 4 + i;
        const int col = n0 + tx * 4;
        if (col < N) {
            float4 r = make_float4(acc[i][0], acc[i][1], acc[i][2], acc[i][3]);
            const float4 bb = *(const float4*)&bias[col];
            r.x += bb.x; r.y += bb.y; r.z += bb.z; r.w += bb.w;
            *(float4*)&C[(size_t)row * N + col] = r;
        }
    }
}

// ---------------------------------------------------------------------------
extern "C" void kernel_launch(void* const* d_in, const int* in_sizes, int n_in,
                              void* d_out, int out_size, void* d_ws, size_t ws_size,
                              hipStream_t stream)
{
    const float* nf = (const float*)d_in[0];
    const float* ef = (const float*)d_in[1];
    const int* ei = (const int*)d_in[2];
    const int* src = ei;
    const int* dst = ei + E_EDGES;

    const float* a_Wn[2] = {(const float*)d_in[3],  (const float*)d_in[13]};
    const float* a_bn[2] = {(const float*)d_in[4],  (const float*)d_in[14]};
    const float* a_Wq[2] = {(const float*)d_in[5],  (const float*)d_in[15]};
    const float* a_bq[2] = {(const float*)d_in[6],  (const float*)d_in[16]};
    const float* a_Wk[2] = {(const float*)d_in[7],  (const float*)d_in[17]};
    const float* a_bk[2] = {(const float*)d_in[8],  (const float*)d_in[18]};
    const float* a_Wv[2] = {(const float*)d_in[9],  (const float*)d_in[19]};
    const float* a_bv[2] = {(const float*)d_in[10], (const float*)d_in[20]};
    const float* a_Wo[2] = {(const float*)d_in[11], (const float*)d_in[21]};
    const float* a_bo[2] = {(const float*)d_in[12], (const float*)d_in[22]};
    const float* cls_W1 = (const float*)d_in[23];
    const float* cls_b1 = (const float*)d_in[24];
    const float* cls_W2 = (const float*)d_in[25];
    const float* cls_b2 = (const float*)d_in[26];

    const size_t buf = (size_t)E_EDGES * D_EDGE;  // 1M floats = 4MB
    float* ws = (float*)d_ws;
    float* ctx1 = ws + 0 * buf;         // layer-1 context; later aliased by y2
    float* ctx2 = ws + 1 * buf;
    float* qb   = ws + 2 * buf;         // later aliased by hb (after attn L2)
    float* kb   = ws + 3 * buf;
    float* vb   = ws + 4 * buf;
    float* ao   = ws + 5 * buf;
    float* y1   = ws + 6 * buf;
    float* y2   = ctx1;                 // ctx1 dead after layer-1 Wo
    float* hb   = qb;                   // qb dead after layer-2 attn
    int* cand   = (int*)(ws + 7 * buf);            // 4096*128*4 = 2MB
    int* ccount = cand + (size_t)E_EDGES * CAP;    // 16KB
    short* whiT = (short*)(ccount + E_EDGES);      // 11 x 128KB
    short* wloT = whiT + (size_t)11 * 65536;       // 11 x 128KB

    const dim3 gGemm(D_EDGE / 64, E_EDGES / 64);   // (4, 64) = 256 blocks
    const dim3 gCtx(D_EDGE / 64, 2 * E_EDGES / 64);// (4, 128) = 512 blocks
    const dim3 gQkv(12, E_EDGES / 64);             // (12, 64) = 768 blocks
    const dim3 gCls(1, E_EDGES / 64);

    prep<<<176 + E_EDGES / 4, 256, 0, stream>>>(
        a_Wn[0], a_Wq[0], a_Wk[0], a_Wv[0], a_Wo[0],
        a_Wn[1], a_Wq[1], a_Wk[1], a_Wv[1], a_Wo[1],
        cls_W1, whiT, wloT, src, dst, cand, ccount);

    gemm_ctx<<<gCtx, 256, 0, stream>>>(nf, src, dst, whiT, wloT,
                                       a_bn[0], a_bn[1], ctx1);

    const float* ef_in = ef;
    const float* ctxL[2] = {ctx1, ctx2};
    float* yout[2] = {y1, y2};
    for (int L = 0; L < 2; ++L) {
        const int wbase = L * 5;
        gemm_mfma_qkv<<<gQkv, 256, 0, stream>>>(
            ef_in, ctxL[L], whiT, wloT, a_bq[L], a_bk[L], a_bv[L],
            qb, kb, vb, wbase);
        attn_sparse3<<<E_EDGES, 256, 0, stream>>>(qb, kb, vb, cand, ccount, ao);
        // y = (ef_in + ctx) + ao @ Wo + bo
        gemm_mfma<<<gGemm, 256, 0, stream>>>(
            ao, nullptr, whiT + (size_t)(wbase + 4) * 65536,
            wloT + (size_t)(wbase + 4) * 65536,
            a_bo[L], ef_in, ctxL[L], yout[L], 0);
        ef_in = yout[L];
    }

    gemm_mfma<<<gGemm, 256, 0, stream>>>(
        y2, nullptr, whiT + (size_t)10 * 65536, wloT + (size_t)10 * 65536,
        cls_b1, nullptr, nullptr, hb, 1);
    gemm_small<<<gCls, 256, 0, stream>>>(hb, cls_W2, cls_b2, (float*)d_out,
                                         N_CLASSES, D_EDGE);
}

// Round 10
// 148.755 us; speedup vs baseline: 3.1051x; 1.0185x over previous
//
#include <hip/hip_runtime.h>
#include <math.h>

#define E_EDGES 4096
#define N_NODES 1024
#define D_NODE 128
#define D_EDGE 256
#define HEADS 4
#define HD 64
#define N_CLASSES 16
#define CAP 128   // max adjacent edges per edge (avg ~16, worst ~50)

typedef __attribute__((ext_vector_type(8))) short short8v;  // 8 bf16 = 4 VGPR
typedef __attribute__((ext_vector_type(4))) float f32x4;    // MFMA C/D frag

__device__ __forceinline__ unsigned short f2bf(float f) {
    unsigned u = __float_as_uint(f);
    return (unsigned short)((u + 0x7FFFu + ((u >> 16) & 1u)) >> 16);
}
__device__ __forceinline__ float bf2f(unsigned short b) {
    return __uint_as_float(((unsigned)b) << 16);
}

// direct-to-LDS 16B DMA (gfx950): per-wave dest = uniform base + lane*16,
// matched by our per-thread dest (base + t*16).
__device__ __forceinline__ void gload_lds16(const void* g, void* l) {
    __builtin_amdgcn_global_load_lds((const __attribute__((address_space(1))) void*)g,
                                     (__attribute__((address_space(3))) void*)l, 16, 0, 0);
}

// XCD-aware remap (R5: qkv FETCH 17.2 -> 5.2MB). Requires gridDim.y % 8 == 0.
__device__ __forceinline__ void xcd_remap(int& bx, int& by)
{
    const int nx = gridDim.x;
    const int lid = blockIdx.x + nx * blockIdx.y;
    const int g = lid & 7, s = lid >> 3;
    const int ppx = gridDim.y >> 3;
    by = g * ppx + s / nx;
    bx = s % nx;
}

// ---------------------------------------------------------------------------
// Prep (one dispatch):
//  blocks 0..175: coalesced split of 11 f32 W[k][n] (256x256) into TRANSPOSED
//    bf16 hi/lo WT[n][k], via a 64x64 LDS transpose tile (float4 reads along
//    n, short8v writes along k). mat = bx/16, tile = bx%16.
//  blocks 176..1199: adjacency CSR build (wave per edge, ballot-compaction).
// Weight order: a1{Wn,Wq,Wk,Wv,Wo}, a2{...}, cls_W1.
// ---------------------------------------------------------------------------
__global__ __launch_bounds__(256) void prep(
    const float* W0, const float* W1, const float* W2, const float* W3,
    const float* W4, const float* W5, const float* W6, const float* W7,
    const float* W8, const float* W9, const float* W10,
    short* hiT, short* loT,
    const int* __restrict__ src, const int* __restrict__ dst,
    int* __restrict__ cand, int* __restrict__ ccount)
{
    __shared__ float tl[64][65];
    const int t = threadIdx.x;
    if (blockIdx.x < 176) {
        const float* Ws[11] = {W0, W1, W2, W3, W4, W5, W6, W7, W8, W9, W10};
        const int mat = blockIdx.x >> 4, tile = blockIdx.x & 15;
        const int k0 = (tile >> 2) * 64, n0 = (tile & 3) * 64;
        const float* W = Ws[mat];
#pragma unroll
        for (int p = 0; p < 4; ++p) {
            const int kr = (t >> 4) + p * 16;
            const int nc = (t & 15) * 4;
            *(float4*)&tl[kr][nc] = *(const float4*)&W[(size_t)(k0 + kr) * 256 + n0 + nc];
        }
        __syncthreads();
        const int n = t >> 2, ks = (t & 3) * 16;
        short8v h0, h1, l0, l1;
#pragma unroll
        for (int j = 0; j < 8; ++j) {
            const float x = tl[ks + j][n];
            const unsigned short hb = f2bf(x);
            h0[j] = (short)hb; l0[j] = (short)f2bf(x - bf2f(hb));
        }
#pragma unroll
        for (int j = 0; j < 8; ++j) {
            const float x = tl[ks + 8 + j][n];
            const unsigned short hb = f2bf(x);
            h1[j] = (short)hb; l1[j] = (short)f2bf(x - bf2f(hb));
        }
        short* ho = hiT + (size_t)mat * 65536;
        short* lo = loT + (size_t)mat * 65536;
        *(short8v*)&ho[(size_t)(n0 + n) * 256 + k0 + ks] = h0;
        *(short8v*)&ho[(size_t)(n0 + n) * 256 + k0 + ks + 8] = h1;
        *(short8v*)&lo[(size_t)(n0 + n) * 256 + k0 + ks] = l0;
        *(short8v*)&lo[(size_t)(n0 + n) * 256 + k0 + ks + 8] = l1;
    } else {
        const int w = t >> 6, lane = t & 63;
        const int e = (blockIdx.x - 176) * 4 + w;
        const int a = src[e], b = dst[e];
        int* my = cand + (size_t)e * CAP;
        int base = 0;
        for (int c0 = 0; c0 < E_EDGES; c0 += 64) {
            const int f = c0 + lane;
            const int sf = src[f], df = dst[f];
            const bool adj = (sf == a) | (sf == b) | (df == a) | (df == b);
            const unsigned long long mk = __ballot(adj);
            if (adj) {
                const int pos = base + __popcll(mk & ((1ull << lane) - 1ull));
                if (pos < CAP) my[pos] = f;
            }
            base += __popcll(mk);
        }
        if (lane == 0) ccount[e] = (base < CAP) ? base : CAP;
    }
}

// ---------------------------------------------------------------------------
// Split-bf16 MFMA GEMM core: C[64x64] = act((A[+A2])@B + bias + res + res2),
// K = 256. A@B = AhBh + AhBl + AlBh (lo*lo ~2^-18 dropped). 4 waves x 2x2
// mfma_f32_16x16x32_bf16 frags. Dbuf LDS, ONE barrier/K-tile; A loads issued
// before MFMA, split+ds_write after (T14); B via global_load_lds DMA.
// If nf != null: A row m = concat(nf[src[m]], nf[dst[m]]).
// ---------------------------------------------------------------------------
__device__ __forceinline__ void gemm_mfma_core(
    const float* __restrict__ A, const float* __restrict__ A2,
    const short* __restrict__ BhiT, const short* __restrict__ BloT,
    const float* __restrict__ bias, const float* __restrict__ residual,
    const float* __restrict__ residual2, float* __restrict__ C,
    int m0, int n0,
    const float* __restrict__ nf, const int* __restrict__ src,
    const int* __restrict__ dst, int act)
{
    __shared__ short AsH[2][64 * 40];   // [buf][m][kpad40] bf16 hi
    __shared__ short AsL[2][64 * 40];
    __shared__ short BsH[2][64 * 32];   // [buf][n][k32] (DMA linear)
    __shared__ short BsL[2][64 * 32];
    const int t = threadIdx.x;
    const int w = t >> 6, lane = t & 63, lr = lane & 15, lg = lane >> 4;
    const int WR = (w >> 1) * 32, WC = (w & 1) * 32;
    const int am = t >> 2, akc = (t & 3) * 8;
    const int bn = t >> 2, bkc = (t & 3) * 8;

    int nS = 0, nD = 0;
    if (nf) { nS = src[m0 + am]; nD = dst[m0 + am]; }

    f32x4 acc00 = {0.f, 0.f, 0.f, 0.f};
    f32x4 acc01 = acc00, acc10 = acc00, acc11 = acc00;
    float4 av0, av1;

#define LOADA_REG(k0)                                                          \
    do {                                                                       \
        const int kq0 = (k0) + akc, kq1 = kq0 + 4;                             \
        if (nf) {                                                              \
            const float* p0 = (kq0 < D_NODE)                                   \
                ? &nf[(size_t)nS * D_NODE + kq0]                               \
                : &nf[(size_t)nD * D_NODE + kq0 - D_NODE];                     \
            const float* p1 = (kq1 < D_NODE)                                   \
                ? &nf[(size_t)nS * D_NODE + kq1]                               \
                : &nf[(size_t)nD * D_NODE + kq1 - D_NODE];                     \
            av0 = *(const float4*)p0; av1 = *(const float4*)p1;                \
        } else {                                                               \
            av0 = *(const float4*)&A[(size_t)(m0 + am) * 256 + kq0];           \
            av1 = *(const float4*)&A[(size_t)(m0 + am) * 256 + kq1];           \
            if (A2) {                                                          \
                const float4 c0_ = *(const float4*)&A2[(size_t)(m0 + am) * 256 + kq0]; \
                const float4 c1_ = *(const float4*)&A2[(size_t)(m0 + am) * 256 + kq1]; \
                av0.x += c0_.x; av0.y += c0_.y; av0.z += c0_.z; av0.w += c0_.w; \
                av1.x += c1_.x; av1.y += c1_.y; av1.z += c1_.z; av1.w += c1_.w; \
            }                                                                  \
        }                                                                      \
    } while (0)
#define SPLIT1(f, j)                                                           \
    { const unsigned short hb = f2bf(f); ah[j] = (short)hb;                    \
      al[j] = (short)f2bf((f) - bf2f(hb)); }
#define STOREA_SPLIT(buf)                                                      \
    do {                                                                       \
        short8v ah, al;                                                        \
        SPLIT1(av0.x, 0) SPLIT1(av0.y, 1) SPLIT1(av0.z, 2) SPLIT1(av0.w, 3)    \
        SPLIT1(av1.x, 4) SPLIT1(av1.y, 5) SPLIT1(av1.z, 6) SPLIT1(av1.w, 7)    \
        *(short8v*)&AsH[buf][am * 40 + akc] = ah;                              \
        *(short8v*)&AsL[buf][am * 40 + akc] = al;                              \
    } while (0)
#define STAGE_B(buf, k0)                                                       \
    do {                                                                       \
        gload_lds16(&BhiT[(size_t)(n0 + bn) * 256 + (k0) + bkc],               \
                    (short*)&BsH[buf][0] + t * 8);                             \
        gload_lds16(&BloT[(size_t)(n0 + bn) * 256 + (k0) + bkc],               \
                    (short*)&BsL[buf][0] + t * 8);                             \
    } while (0)
#define MFMA_STEP(buf)                                                         \
    do {                                                                       \
        const int c0 = WC + lr, c1 = WC + 16 + lr;                             \
        const short8v bH0 = *(const short8v*)&BsH[buf][c0 * 32 + lg * 8];      \
        const short8v bL0 = *(const short8v*)&BsL[buf][c0 * 32 + lg * 8];      \
        const short8v bH1 = *(const short8v*)&BsH[buf][c1 * 32 + lg * 8];      \
        const short8v bL1 = *(const short8v*)&BsL[buf][c1 * 32 + lg * 8];      \
        const short8v aH0 = *(const short8v*)&AsH[buf][(WR + lr) * 40 + lg * 8];      \
        const short8v aL0 = *(const short8v*)&AsL[buf][(WR + lr) * 40 + lg * 8];      \
        const short8v aH1 = *(const short8v*)&AsH[buf][(WR + 16 + lr) * 40 + lg * 8]; \
        const short8v aL1 = *(const short8v*)&AsL[buf][(WR + 16 + lr) * 40 + lg * 8]; \
        acc00 = __builtin_amdgcn_mfma_f32_16x16x32_bf16(aH0, bH0, acc00, 0, 0, 0);    \
        acc01 = __builtin_amdgcn_mfma_f32_16x16x32_bf16(aH0, bH1, acc01, 0, 0, 0);    \
        acc10 = __builtin_amdgcn_mfma_f32_16x16x32_bf16(aH1, bH0, acc10, 0, 0, 0);    \
        acc11 = __builtin_amdgcn_mfma_f32_16x16x32_bf16(aH1, bH1, acc11, 0, 0, 0);    \
        acc00 = __builtin_amdgcn_mfma_f32_16x16x32_bf16(aH0, bL0, acc00, 0, 0, 0);    \
        acc01 = __builtin_amdgcn_mfma_f32_16x16x32_bf16(aH0, bL1, acc01, 0, 0, 0);    \
        acc10 = __builtin_amdgcn_mfma_f32_16x16x32_bf16(aH1, bL0, acc10, 0, 0, 0);    \
        acc11 = __builtin_amdgcn_mfma_f32_16x16x32_bf16(aH1, bL1, acc11, 0, 0, 0);    \
        acc00 = __builtin_amdgcn_mfma_f32_16x16x32_bf16(aL0, bH0, acc00, 0, 0, 0);    \
        acc01 = __builtin_amdgcn_mfma_f32_16x16x32_bf16(aL0, bH1, acc01, 0, 0, 0);    \
        acc10 = __builtin_amdgcn_mfma_f32_16x16x32_bf16(aL1, bH0, acc10, 0, 0, 0);    \
        acc11 = __builtin_amdgcn_mfma_f32_16x16x32_bf16(aL1, bH1, acc11, 0, 0, 0);    \
    } while (0)

    LOADA_REG(0);
    STAGE_B(0, 0);
    STOREA_SPLIT(0);
    __syncthreads();

    for (int kt = 0; kt < 8; ++kt) {       // K = 256 = 8 x 32
        const int cur = kt & 1;
        if (kt < 7) {
            STAGE_B(cur ^ 1, (kt + 1) * 32);
            LOADA_REG((kt + 1) * 32);
        }
        MFMA_STEP(cur);
        if (kt < 7) STOREA_SPLIT(cur ^ 1);
        __syncthreads();
    }

#define EPI(accv, rt, ct)                                                      \
    do {                                                                       \
        const int col = n0 + WC + (ct) * 16 + lr;                              \
        const float bb = bias ? bias[col] : 0.f;                               \
        _Pragma("unroll") for (int i = 0; i < 4; ++i) {                        \
            const int row = m0 + WR + (rt) * 16 + lg * 4 + i;                  \
            float v = accv[i] + bb;                                            \
            if (residual) v += residual[(size_t)row * D_EDGE + col];           \
            if (residual2) v += residual2[(size_t)row * D_EDGE + col];         \
            if (act == 1) v = 0.5f * v * (1.f + erff(v * 0.70710678118654752f)); \
            C[(size_t)row * D_EDGE + col] = v;                                 \
        }                                                                      \
    } while (0)
    EPI(acc00, 0, 0); EPI(acc01, 0, 1); EPI(acc10, 1, 0); EPI(acc11, 1, 1);
#undef LOADA_REG
#undef SPLIT1
#undef STOREA_SPLIT
#undef STAGE_B
#undef MFMA_STEP
#undef EPI
}

// ctx precompute, BOTH layers in one dispatch: grid (4, 128); by<64 layer1.
__global__ __launch_bounds__(256) void gemm_ctx(
    const float* __restrict__ nf, const int* __restrict__ src,
    const int* __restrict__ dst, const short* __restrict__ whiT,
    const short* __restrict__ wloT, const float* __restrict__ bn1,
    const float* __restrict__ bn2, float* __restrict__ ctx)
{
    int bx = blockIdx.x, by = blockIdx.y;
    xcd_remap(bx, by);
    const int Lyr = by >> 6, rb = by & 63;
    const short* BH = whiT + (size_t)(Lyr * 5) * 65536;
    const short* BL = wloT + (size_t)(Lyr * 5) * 65536;
    gemm_mfma_core(nullptr, nullptr, BH, BL, Lyr ? bn2 : bn1,
                   nullptr, nullptr, ctx + (size_t)Lyr * E_EDGES * D_EDGE,
                   rb * 64, bx * 64, nf, src, dst, 0);
}

// generic (Wo): A [+A2] @ W + bias + residual [+residual2]
__global__ __launch_bounds__(256) void gemm_mfma(
    const float* __restrict__ A, const float* __restrict__ A2,
    const short* __restrict__ BhiT, const short* __restrict__ BloT,
    const float* __restrict__ bias, const float* __restrict__ residual,
    const float* __restrict__ residual2, float* __restrict__ C, int act)
{
    int bx = blockIdx.x, by = blockIdx.y;
    xcd_remap(bx, by);
    gemm_mfma_core(A, A2, BhiT, BloT, bias, residual, residual2, C,
                   by * 64, bx * 64, nullptr, nullptr, nullptr, act);
}

// q/k/v fused, x = ef_in + ctx formed on the fly in A-staging.
__global__ __launch_bounds__(256) void gemm_mfma_qkv(
    const float* __restrict__ ef_in, const float* __restrict__ ctx,
    const short* __restrict__ whiT, const short* __restrict__ wloT,
    const float* __restrict__ bq, const float* __restrict__ bk,
    const float* __restrict__ bv,
    float* __restrict__ qb, float* __restrict__ kb, float* __restrict__ vb,
    int wbase)
{
    int bx = blockIdx.x, by = blockIdx.y;
    xcd_remap(bx, by);
    const int wsel = bx >> 2, nt = bx & 3;
    const short* BH = whiT + (size_t)(wbase + 1 + wsel) * 65536;
    const short* BL = wloT + (size_t)(wbase + 1 + wsel) * 65536;
    const float* bias = (wsel == 0) ? bq : (wsel == 1) ? bk : bv;
    float* C = (wsel == 0) ? qb : (wsel == 1) ? kb : vb;
    gemm_mfma_core(ef_in, ctx, BH, BL, bias, nullptr, nullptr, C,
                   by * 64, nt * 64, nullptr, nullptr, nullptr, 0);
}

// ---------------------------------------------------------------------------
// Sparse attention v4. Block = edge, wave = head, 4 groups of 16 lanes.
// KEY CHANGE vs v3: each group runs an INDEPENDENT online softmax over its
// own candidate subset (i ≡ g mod 4) — no per-iteration cross-group
// broadcast/sync — merged once at the end via the standard softmax-merge
// butterfly. 2-way unrolled (two independent shfl-reduce chains).
// expf(-1e30-max)==0 keeps empty groups and tail candidates exact.
// ---------------------------------------------------------------------------
__global__ __launch_bounds__(256) void attn_sparse4(
    const float* __restrict__ q, const float* __restrict__ k,
    const float* __restrict__ v, const int* __restrict__ cand,
    const int* __restrict__ ccount, float* __restrict__ out)
{
    __shared__ int lc[CAP];
    const int e = blockIdx.x;
    const int t = threadIdx.x, h = t >> 6, lane = t & 63;
    const int g = lane >> 4, il = lane & 15;
    const int m = ccount[e];
    if (t < m) lc[t] = cand[(size_t)e * CAP + t];
    __syncthreads();

    const float4 q4 = *(const float4*)&q[(size_t)e * D_EDGE + h * HD + il * 4];
    float M = -1e30f, L = 0.f;
    float4 O = make_float4(0.f, 0.f, 0.f, 0.f);

    for (int i0 = g; i0 < m; i0 += 8) {
        const int f0 = lc[i0];
        const bool ok1 = (i0 + 4) < m;
        const int f1 = ok1 ? lc[i0 + 4] : f0;
        const float4 k0 = *(const float4*)&k[(size_t)f0 * D_EDGE + h * HD + il * 4];
        const float4 v0 = *(const float4*)&v[(size_t)f0 * D_EDGE + h * HD + il * 4];
        const float4 k1 = *(const float4*)&k[(size_t)f1 * D_EDGE + h * HD + il * 4];
        const float4 v1 = *(const float4*)&v[(size_t)f1 * D_EDGE + h * HD + il * 4];
        float s0 = q4.x * k0.x + q4.y * k0.y + q4.z * k0.z + q4.w * k0.w;
        float s1 = q4.x * k1.x + q4.y * k1.y + q4.z * k1.z + q4.w * k1.w;
        s0 += __shfl_xor(s0, 1); s1 += __shfl_xor(s1, 1);
        s0 += __shfl_xor(s0, 2); s1 += __shfl_xor(s1, 2);
        s0 += __shfl_xor(s0, 4); s1 += __shfl_xor(s1, 4);
        s0 += __shfl_xor(s0, 8); s1 += __shfl_xor(s1, 8);
        s0 *= 0.125f;                          // 1/sqrt(64)
        s1 = ok1 ? s1 * 0.125f : -1e30f;       // tail: p1 -> 0 exactly
        const float Mn = fmaxf(M, fmaxf(s0, s1));
        const float al = __expf(M - Mn);
        const float p0 = __expf(s0 - Mn), p1 = __expf(s1 - Mn);
        O.x = O.x * al + p0 * v0.x + p1 * v1.x;
        O.y = O.y * al + p0 * v0.y + p1 * v1.y;
        O.z = O.z * al + p0 * v0.z + p1 * v1.z;
        O.w = O.w * al + p0 * v0.w + p1 * v1.w;
        L = L * al + p0 + p1;
        M = Mn;
    }
    // merge the 4 groups: M_g -> Mo, scale each group's (O,L) by exp(M_g-Mo)
    float Mo = fmaxf(M, __shfl_xor(M, 16));
    Mo = fmaxf(Mo, __shfl_xor(Mo, 32));
    const float sc = __expf(M - Mo);           // empty group: exp(-1e30-Mo)=0
    O.x *= sc; O.y *= sc; O.z *= sc; O.w *= sc; L *= sc;
    O.x += __shfl_xor(O.x, 16); O.y += __shfl_xor(O.y, 16);
    O.z += __shfl_xor(O.z, 16); O.w += __shfl_xor(O.w, 16);
    L += __shfl_xor(L, 16);
    O.x += __shfl_xor(O.x, 32); O.y += __shfl_xor(O.y, 32);
    O.z += __shfl_xor(O.z, 32); O.w += __shfl_xor(O.w, 32);
    L += __shfl_xor(L, 32);
    if (lane < 16) {
        const float invL = 1.f / L;
        float4 r = make_float4(O.x * invL, O.y * invL, O.z * invL, O.w * invL);
        *(float4*)&out[(size_t)e * D_EDGE + h * HD + il * 4] = r;
    }
}

// ---------------------------------------------------------------------------
// Fused classifier: out = gelu(y@W1+b1)@W2 + b2, one dispatch, 64 blocks.
// Phase 1: block computes full h-tile [64][256] (split-bf16 MFMA, single-buf
//   B DMA, 16 acc frags/wave), GELU, split -> LDS hH/hL.
// Phase 2: wave w computes out rows w*16..+15 x 16 cols via MFMA; W2 staged
//   f32 in LDS, split to hi/lo in-flight. 3-term split product throughout.
// Static smem union: phase1 {AsH,AsL,BsH,BsL} 43KB / phase2 {hH,hL,W2s} 84KB.
// ---------------------------------------------------------------------------
__global__ __launch_bounds__(256) void gemm_cls(
    const float* __restrict__ y, const short* __restrict__ BhiT,
    const short* __restrict__ BloT, const float* __restrict__ b1,
    const float* __restrict__ W2, const float* __restrict__ b2,
    float* __restrict__ outp)
{
    __shared__ __attribute__((aligned(16))) char smem[86016];
    short* AsH = (short*)smem;                  // 64*40 sh = 5120 B
    short* AsL = (short*)(smem + 5120);         // 5120 B
    short* BsH = (short*)(smem + 10240);        // 256*32 sh = 16384 B
    short* BsL = (short*)(smem + 26624);        // 16384 B -> 43008
    short* hH  = (short*)smem;                  // 64*264 sh = 33792 B
    short* hL  = (short*)(smem + 33792);        // 33792 -> 67584
    float* W2s = (float*)(smem + 67584);        // 16384 -> 83968

    const int t = threadIdx.x;
    const int w = t >> 6, lane = t & 63, lr = lane & 15, lg = lane >> 4;
    const int WR = (w >> 1) * 32, WC = (w & 1) * 32;
    const int am = t >> 2, akc = (t & 3) * 8;
    const int m0 = blockIdx.x * 64;

    f32x4 acc[4][2][2];
#pragma unroll
    for (int nt = 0; nt < 4; ++nt)
#pragma unroll
        for (int rt = 0; rt < 2; ++rt)
#pragma unroll
            for (int ct = 0; ct < 2; ++ct) acc[nt][rt][ct] = (f32x4){0.f, 0.f, 0.f, 0.f};

    for (int kt = 0; kt < 8; ++kt) {
        const int k0 = kt * 32;
        // stage A (f32 y -> split bf16 hi/lo)
        {
            const float4 av0 = *(const float4*)&y[(size_t)(m0 + am) * 256 + k0 + akc];
            const float4 av1 = *(const float4*)&y[(size_t)(m0 + am) * 256 + k0 + akc + 4];
            short8v ah, al;
            const float fv[8] = {av0.x, av0.y, av0.z, av0.w, av1.x, av1.y, av1.z, av1.w};
#pragma unroll
            for (int j = 0; j < 8; ++j) {
                const unsigned short hb = f2bf(fv[j]);
                ah[j] = (short)hb; al[j] = (short)f2bf(fv[j] - bf2f(hb));
            }
            *(short8v*)&AsH[am * 40 + akc] = ah;
            *(short8v*)&AsL[am * 40 + akc] = al;
        }
        // stage B full-width 256n x 32k via DMA
#pragma unroll
        for (int p = 0; p < 4; ++p) {
            const int idx = t + 256 * p;
            const int n = idx >> 2, k8 = (idx & 3) * 8;
            gload_lds16(&BhiT[(size_t)n * 256 + k0 + k8], BsH + (size_t)idx * 8);
            gload_lds16(&BloT[(size_t)n * 256 + k0 + k8], BsL + (size_t)idx * 8);
        }
        __syncthreads();
        const short8v aH0 = *(const short8v*)&AsH[(WR + lr) * 40 + lg * 8];
        const short8v aL0 = *(const short8v*)&AsL[(WR + lr) * 40 + lg * 8];
        const short8v aH1 = *(const short8v*)&AsH[(WR + 16 + lr) * 40 + lg * 8];
        const short8v aL1 = *(const short8v*)&AsL[(WR + 16 + lr) * 40 + lg * 8];
#pragma unroll
        for (int nt = 0; nt < 4; ++nt) {
            const int c0 = nt * 64 + WC + lr, c1 = c0 + 16;
            const short8v bH0 = *(const short8v*)&BsH[c0 * 32 + lg * 8];
            const short8v bL0 = *(const short8v*)&BsL[c0 * 32 + lg * 8];
            const short8v bH1 = *(const short8v*)&BsH[c1 * 32 + lg * 8];
            const short8v bL1 = *(const short8v*)&BsL[c1 * 32 + lg * 8];
            acc[nt][0][0] = __builtin_amdgcn_mfma_f32_16x16x32_bf16(aH0, bH0, acc[nt][0][0], 0, 0, 0);
            acc[nt][0][1] = __builtin_amdgcn_mfma_f32_16x16x32_bf16(aH0, bH1, acc[nt][0][1], 0, 0, 0);
            acc[nt][1][0] = __builtin_amdgcn_mfma_f32_16x16x32_bf16(aH1, bH0, acc[nt][1][0], 0, 0, 0);
            acc[nt][1][1] = __builtin_amdgcn_mfma_f32_16x16x32_bf16(aH1, bH1, acc[nt][1][1], 0, 0, 0);
            acc[nt][0][0] = __builtin_amdgcn_mfma_f32_16x16x32_bf16(aH0, bL0, acc[nt][0][0], 0, 0, 0);
            acc[nt][0][1] = __builtin_amdgcn_mfma_f32_16x16x32_bf16(aH0, bL1, acc[nt][0][1], 0, 0, 0);
            acc[nt][1][0] = __builtin_amdgcn_mfma_f32_16x16x32_bf16(aH1, bL0, acc[nt][1][0], 0, 0, 0);
            acc[nt][1][1] = __builtin_amdgcn_mfma_f32_16x16x32_bf16(aH1, bL1, acc[nt][1][1], 0, 0, 0);
            acc[nt][0][0] = __builtin_amdgcn_mfma_f32_16x16x32_bf16(aL0, bH0, acc[nt][0][0], 0, 0, 0);
            acc[nt][0][1] = __builtin_amdgcn_mfma_f32_16x16x32_bf16(aL0, bH1, acc[nt][0][1], 0, 0, 0);
            acc[nt][1][0] = __builtin_amdgcn_mfma_f32_16x16x32_bf16(aL1, bH0, acc[nt][1][0], 0, 0, 0);
            acc[nt][1][1] = __builtin_amdgcn_mfma_f32_16x16x32_bf16(aL1, bH1, acc[nt][1][1], 0, 0, 0);
        }
        __syncthreads();    // all LDS reads done before restage / overwrite
    }

    // phase-1 epilogue: bias + gelu + split -> hH/hL (safe: reads drained)
#pragma unroll
    for (int nt = 0; nt < 4; ++nt)
#pragma unroll
        for (int rt = 0; rt < 2; ++rt)
#pragma unroll
            for (int ct = 0; ct < 2; ++ct) {
                const int col = nt * 64 + WC + ct * 16 + lr;
                const float bb = b1[col];
#pragma unroll
                for (int i = 0; i < 4; ++i) {
                    const int row = WR + rt * 16 + lg * 4 + i;
                    float vv = acc[nt][rt][ct][i] + bb;
                    vv = 0.5f * vv * (1.f + erff(vv * 0.70710678118654752f));
                    const unsigned short hb = f2bf(vv);
                    hH[row * 264 + col] = (short)hb;
                    hL[row * 264 + col] = (short)f2bf(vv - bf2f(hb));
                }
            }
    // stage W2 f32 into LDS (region disjoint from phase-1 arrays)
#pragma unroll
    for (int p = 0; p < 4; ++p) {
        const int idx = t + 256 * p;       // 1024 x 16B = 16384 B
        gload_lds16(&W2[(size_t)idx * 4], W2s + (size_t)idx * 4);
    }
    __syncthreads();

    // phase 2: wave w -> out rows m0 + w*16 .. +15, cols 0..15
    f32x4 o = {0.f, 0.f, 0.f, 0.f};
#pragma unroll
    for (int kk = 0; kk < 8; ++kk) {
        const short8v aH = *(const short8v*)&hH[(w * 16 + lr) * 264 + kk * 32 + lg * 8];
        const short8v aL = *(const short8v*)&hL[(w * 16 + lr) * 264 + kk * 32 + lg * 8];
        short8v bH, bL;
#pragma unroll
        for (int j = 0; j < 8; ++j) {
            const float x = W2s[(size_t)(kk * 32 + lg * 8 + j) * 16 + lr];
            const unsigned short hb = f2bf(x);
            bH[j] = (short)hb; bL[j] = (short)f2bf(x - bf2f(hb));
        }
        o = __builtin_amdgcn_mfma_f32_16x16x32_bf16(aH, bH, o, 0, 0, 0);
        o = __builtin_amdgcn_mfma_f32_16x16x32_bf16(aH, bL, o, 0, 0, 0);
        o = __builtin_amdgcn_mfma_f32_16x16x32_bf16(aL, bH, o, 0, 0, 0);
    }
#pragma unroll
    for (int i = 0; i < 4; ++i) {
        const int row = m0 + w * 16 + lg * 4 + i;
        outp[(size_t)row * 16 + lr] = o[i] + b2[lr];
    }
}

// ---------------------------------------------------------------------------
extern "C" void kernel_launch(void* const* d_in, const int* in_sizes, int n_in,
                              void* d_out, int out_size, void* d_ws, size_t ws_size,
                              hipStream_t stream)
{
    const float* nf = (const float*)d_in[0];
    const float* ef = (const float*)d_in[1];
    const int* ei = (const int*)d_in[2];
    const int* src = ei;
    const int* dst = ei + E_EDGES;

    const float* a_Wn[2] = {(const float*)d_in[3],  (const float*)d_in[13]};
    const float* a_bn[2] = {(const float*)d_in[4],  (const float*)d_in[14]};
    const float* a_Wq[2] = {(const float*)d_in[5],  (const float*)d_in[15]};
    const float* a_bq[2] = {(const float*)d_in[6],  (const float*)d_in[16]};
    const float* a_Wk[2] = {(const float*)d_in[7],  (const float*)d_in[17]};
    const float* a_bk[2] = {(const float*)d_in[8],  (const float*)d_in[18]};
    const float* a_Wv[2] = {(const float*)d_in[9],  (const float*)d_in[19]};
    const float* a_bv[2] = {(const float*)d_in[10], (const float*)d_in[20]};
    const float* a_Wo[2] = {(const float*)d_in[11], (const float*)d_in[21]};
    const float* a_bo[2] = {(const float*)d_in[12], (const float*)d_in[22]};
    const float* cls_W1 = (const float*)d_in[23];
    const float* cls_b1 = (const float*)d_in[24];
    const float* cls_W2 = (const float*)d_in[25];
    const float* cls_b2 = (const float*)d_in[26];

    const size_t buf = (size_t)E_EDGES * D_EDGE;  // 1M floats = 4MB
    float* ws = (float*)d_ws;
    float* ctx1 = ws + 0 * buf;         // layer-1 context; later aliased by y2
    float* ctx2 = ws + 1 * buf;
    float* qb   = ws + 2 * buf;
    float* kb   = ws + 3 * buf;
    float* vb   = ws + 4 * buf;
    float* ao   = ws + 5 * buf;
    float* y1   = ws + 6 * buf;
    float* y2   = ctx1;                 // ctx1 dead after layer-1 Wo
    int* cand   = (int*)(ws + 7 * buf);            // 4096*128*4 = 2MB
    int* ccount = cand + (size_t)E_EDGES * CAP;    // 16KB
    short* whiT = (short*)(ccount + E_EDGES);      // 11 x 128KB
    short* wloT = whiT + (size_t)11 * 65536;       // 11 x 128KB

    const dim3 gGemm(D_EDGE / 64, E_EDGES / 64);   // (4, 64) = 256 blocks
    const dim3 gCtx(D_EDGE / 64, 2 * E_EDGES / 64);// (4, 128) = 512 blocks
    const dim3 gQkv(12, E_EDGES / 64);             // (12, 64) = 768 blocks

    prep<<<176 + E_EDGES / 4, 256, 0, stream>>>(
        a_Wn[0], a_Wq[0], a_Wk[0], a_Wv[0], a_Wo[0],
        a_Wn[1], a_Wq[1], a_Wk[1], a_Wv[1], a_Wo[1],
        cls_W1, whiT, wloT, src, dst, cand, ccount);

    gemm_ctx<<<gCtx, 256, 0, stream>>>(nf, src, dst, whiT, wloT,
                                       a_bn[0], a_bn[1], ctx1);

    const float* ef_in = ef;
    const float* ctxL[2] = {ctx1, ctx2};
    float* yout[2] = {y1, y2};
    for (int L = 0; L < 2; ++L) {
        const int wbase = L * 5;
        gemm_mfma_qkv<<<gQkv, 256, 0, stream>>>(
            ef_in, ctxL[L], whiT, wloT, a_bq[L], a_bk[L], a_bv[L],
            qb, kb, vb, wbase);
        attn_sparse4<<<E_EDGES, 256, 0, stream>>>(qb, kb, vb, cand, ccount, ao);
        // y = (ef_in + ctx) + ao @ Wo + bo
        gemm_mfma<<<gGemm, 256, 0, stream>>>(
            ao, nullptr, whiT + (size_t)(wbase + 4) * 65536,
            wloT + (size_t)(wbase + 4) * 65536,
            a_bo[L], ef_in, ctxL[L], yout[L], 0);
        ef_in = yout[L];
    }

    gemm_cls<<<64, 256, 0, stream>>>(y2, whiT + (size_t)10 * 65536,
                                     wloT + (size_t)10 * 65536,
                                     cls_b1, cls_W2, cls_b2, (float*)d_out);
}

// Round 11
// 135.856 us; speedup vs baseline: 3.3999x; 1.0950x over previous
//
#include <hip/hip_runtime.h>
#include <math.h>

#define E_EDGES 4096
#define N_NODES 1024
#define D_NODE 128
#define D_EDGE 256
#define HEADS 4
#define HD 64
#define N_CLASSES 16
#define CAP 128   // max adjacent edges per edge (avg ~16, worst ~50)

typedef __attribute__((ext_vector_type(8))) short short8v;  // 8 bf16 = 4 VGPR
typedef __attribute__((ext_vector_type(4))) float f32x4;    // MFMA C/D frag

__device__ __forceinline__ unsigned short f2bf(float f) {
    unsigned u = __float_as_uint(f);
    return (unsigned short)((u + 0x7FFFu + ((u >> 16) & 1u)) >> 16);
}
__device__ __forceinline__ float bf2f(unsigned short b) {
    return __uint_as_float(((unsigned)b) << 16);
}

// direct-to-LDS 16B DMA (gfx950): per-wave dest = uniform base + lane*16,
// matched by our per-thread dest (base + t*16).
__device__ __forceinline__ void gload_lds16(const void* g, void* l) {
    __builtin_amdgcn_global_load_lds((const __attribute__((address_space(1))) void*)g,
                                     (__attribute__((address_space(3))) void*)l, 16, 0, 0);
}

// XCD-aware remap (R5: qkv FETCH 17.2 -> 5.2MB). Requires gridDim.y % 8 == 0.
__device__ __forceinline__ void xcd_remap(int& bx, int& by)
{
    const int nx = gridDim.x;
    const int lid = blockIdx.x + nx * blockIdx.y;
    const int g = lid & 7, s = lid >> 3;
    const int ppx = gridDim.y >> 3;
    by = g * ppx + s / nx;
    bx = s % nx;
}

// ---------------------------------------------------------------------------
// Prep (one dispatch):
//  blocks 0..175: coalesced split of 11 f32 W[k][n] (256x256) into TRANSPOSED
//    bf16 hi/lo WT[n][k], via a 64x64 LDS transpose tile.
//  blocks 176..1199: adjacency CSR build (wave per edge, ballot-compaction).
// Weight order: a1{Wn,Wq,Wk,Wv,Wo}, a2{...}, cls_W1.
// ---------------------------------------------------------------------------
__global__ __launch_bounds__(256) void prep(
    const float* W0, const float* W1, const float* W2, const float* W3,
    const float* W4, const float* W5, const float* W6, const float* W7,
    const float* W8, const float* W9, const float* W10,
    short* hiT, short* loT,
    const int* __restrict__ src, const int* __restrict__ dst,
    int* __restrict__ cand, int* __restrict__ ccount)
{
    __shared__ float tl[64][65];
    const int t = threadIdx.x;
    if (blockIdx.x < 176) {
        const float* Ws[11] = {W0, W1, W2, W3, W4, W5, W6, W7, W8, W9, W10};
        const int mat = blockIdx.x >> 4, tile = blockIdx.x & 15;
        const int k0 = (tile >> 2) * 64, n0 = (tile & 3) * 64;
        const float* W = Ws[mat];
#pragma unroll
        for (int p = 0; p < 4; ++p) {
            const int kr = (t >> 4) + p * 16;
            const int nc = (t & 15) * 4;
            *(float4*)&tl[kr][nc] = *(const float4*)&W[(size_t)(k0 + kr) * 256 + n0 + nc];
        }
        __syncthreads();
        const int n = t >> 2, ks = (t & 3) * 16;
        short8v h0, h1, l0, l1;
#pragma unroll
        for (int j = 0; j < 8; ++j) {
            const float x = tl[ks + j][n];
            const unsigned short hb = f2bf(x);
            h0[j] = (short)hb; l0[j] = (short)f2bf(x - bf2f(hb));
        }
#pragma unroll
        for (int j = 0; j < 8; ++j) {
            const float x = tl[ks + 8 + j][n];
            const unsigned short hb = f2bf(x);
            h1[j] = (short)hb; l1[j] = (short)f2bf(x - bf2f(hb));
        }
        short* ho = hiT + (size_t)mat * 65536;
        short* lo = loT + (size_t)mat * 65536;
        *(short8v*)&ho[(size_t)(n0 + n) * 256 + k0 + ks] = h0;
        *(short8v*)&ho[(size_t)(n0 + n) * 256 + k0 + ks + 8] = h1;
        *(short8v*)&lo[(size_t)(n0 + n) * 256 + k0 + ks] = l0;
        *(short8v*)&lo[(size_t)(n0 + n) * 256 + k0 + ks + 8] = l1;
    } else {
        const int w = t >> 6, lane = t & 63;
        const int e = (blockIdx.x - 176) * 4 + w;
        const int a = src[e], b = dst[e];
        int* my = cand + (size_t)e * CAP;
        int base = 0;
        for (int c0 = 0; c0 < E_EDGES; c0 += 64) {
            const int f = c0 + lane;
            const int sf = src[f], df = dst[f];
            const bool adj = (sf == a) | (sf == b) | (df == a) | (df == b);
            const unsigned long long mk = __ballot(adj);
            if (adj) {
                const int pos = base + __popcll(mk & ((1ull << lane) - 1ull));
                if (pos < CAP) my[pos] = f;
            }
            base += __popcll(mk);
        }
        if (lane == 0) ccount[e] = (base < CAP) ? base : CAP;
    }
}

// ---------------------------------------------------------------------------
// Split-bf16 MFMA GEMM core: C[64x64] = act((A[+A2])@B + bias + res + res2),
// K = 256. A@B = AhBh + AhBl + AlBh (lo*lo ~2^-18 dropped). 4 waves x 2x2
// mfma_f32_16x16x32_bf16 frags. Dbuf LDS, ONE barrier/K-tile; A loads issued
// before MFMA, split+ds_write after (T14); B via global_load_lds DMA.
// If nf != null: A row m = concat(nf[src[m]], nf[dst[m]]).
// ---------------------------------------------------------------------------
__device__ __forceinline__ void gemm_mfma_core(
    const float* __restrict__ A, const float* __restrict__ A2,
    const short* __restrict__ BhiT, const short* __restrict__ BloT,
    const float* __restrict__ bias, const float* __restrict__ residual,
    const float* __restrict__ residual2, float* __restrict__ C,
    int m0, int n0,
    const float* __restrict__ nf, const int* __restrict__ src,
    const int* __restrict__ dst, int act)
{
    __shared__ short AsH[2][64 * 40];   // [buf][m][kpad40] bf16 hi
    __shared__ short AsL[2][64 * 40];
    __shared__ short BsH[2][64 * 32];   // [buf][n][k32] (DMA linear)
    __shared__ short BsL[2][64 * 32];
    const int t = threadIdx.x;
    const int w = t >> 6, lane = t & 63, lr = lane & 15, lg = lane >> 4;
    const int WR = (w >> 1) * 32, WC = (w & 1) * 32;
    const int am = t >> 2, akc = (t & 3) * 8;
    const int bn = t >> 2, bkc = (t & 3) * 8;

    int nS = 0, nD = 0;
    if (nf) { nS = src[m0 + am]; nD = dst[m0 + am]; }

    f32x4 acc00 = {0.f, 0.f, 0.f, 0.f};
    f32x4 acc01 = acc00, acc10 = acc00, acc11 = acc00;
    float4 av0, av1;

#define LOADA_REG(k0)                                                          \
    do {                                                                       \
        const int kq0 = (k0) + akc, kq1 = kq0 + 4;                             \
        if (nf) {                                                              \
            const float* p0 = (kq0 < D_NODE)                                   \
                ? &nf[(size_t)nS * D_NODE + kq0]                               \
                : &nf[(size_t)nD * D_NODE + kq0 - D_NODE];                     \
            const float* p1 = (kq1 < D_NODE)                                   \
                ? &nf[(size_t)nS * D_NODE + kq1]                               \
                : &nf[(size_t)nD * D_NODE + kq1 - D_NODE];                     \
            av0 = *(const float4*)p0; av1 = *(const float4*)p1;                \
        } else {                                                               \
            av0 = *(const float4*)&A[(size_t)(m0 + am) * 256 + kq0];           \
            av1 = *(const float4*)&A[(size_t)(m0 + am) * 256 + kq1];           \
            if (A2) {                                                          \
                const float4 c0_ = *(const float4*)&A2[(size_t)(m0 + am) * 256 + kq0]; \
                const float4 c1_ = *(const float4*)&A2[(size_t)(m0 + am) * 256 + kq1]; \
                av0.x += c0_.x; av0.y += c0_.y; av0.z += c0_.z; av0.w += c0_.w; \
                av1.x += c1_.x; av1.y += c1_.y; av1.z += c1_.z; av1.w += c1_.w; \
            }                                                                  \
        }                                                                      \
    } while (0)
#define SPLIT1(f, j)                                                           \
    { const unsigned short hb = f2bf(f); ah[j] = (short)hb;                    \
      al[j] = (short)f2bf((f) - bf2f(hb)); }
#define STOREA_SPLIT(buf)                                                      \
    do {                                                                       \
        short8v ah, al;                                                        \
        SPLIT1(av0.x, 0) SPLIT1(av0.y, 1) SPLIT1(av0.z, 2) SPLIT1(av0.w, 3)    \
        SPLIT1(av1.x, 4) SPLIT1(av1.y, 5) SPLIT1(av1.z, 6) SPLIT1(av1.w, 7)    \
        *(short8v*)&AsH[buf][am * 40 + akc] = ah;                              \
        *(short8v*)&AsL[buf][am * 40 + akc] = al;                              \
    } while (0)
#define STAGE_B(buf, k0)                                                       \
    do {                                                                       \
        gload_lds16(&BhiT[(size_t)(n0 + bn) * 256 + (k0) + bkc],               \
                    (short*)&BsH[buf][0] + t * 8);                             \
        gload_lds16(&BloT[(size_t)(n0 + bn) * 256 + (k0) + bkc],               \
                    (short*)&BsL[buf][0] + t * 8);                             \
    } while (0)
#define MFMA_STEP(buf)                                                         \
    do {                                                                       \
        const int c0 = WC + lr, c1 = WC + 16 + lr;                             \
        const short8v bH0 = *(const short8v*)&BsH[buf][c0 * 32 + lg * 8];      \
        const short8v bL0 = *(const short8v*)&BsL[buf][c0 * 32 + lg * 8];      \
        const short8v bH1 = *(const short8v*)&BsH[buf][c1 * 32 + lg * 8];      \
        const short8v bL1 = *(const short8v*)&BsL[buf][c1 * 32 + lg * 8];      \
        const short8v aH0 = *(const short8v*)&AsH[buf][(WR + lr) * 40 + lg * 8];      \
        const short8v aL0 = *(const short8v*)&AsL[buf][(WR + lr) * 40 + lg * 8];      \
        const short8v aH1 = *(const short8v*)&AsH[buf][(WR + 16 + lr) * 40 + lg * 8]; \
        const short8v aL1 = *(const short8v*)&AsL[buf][(WR + 16 + lr) * 40 + lg * 8]; \
        acc00 = __builtin_amdgcn_mfma_f32_16x16x32_bf16(aH0, bH0, acc00, 0, 0, 0);    \
        acc01 = __builtin_amdgcn_mfma_f32_16x16x32_bf16(aH0, bH1, acc01, 0, 0, 0);    \
        acc10 = __builtin_amdgcn_mfma_f32_16x16x32_bf16(aH1, bH0, acc10, 0, 0, 0);    \
        acc11 = __builtin_amdgcn_mfma_f32_16x16x32_bf16(aH1, bH1, acc11, 0, 0, 0);    \
        acc00 = __builtin_amdgcn_mfma_f32_16x16x32_bf16(aH0, bL0, acc00, 0, 0, 0);    \
        acc01 = __builtin_amdgcn_mfma_f32_16x16x32_bf16(aH0, bL1, acc01, 0, 0, 0);    \
        acc10 = __builtin_amdgcn_mfma_f32_16x16x32_bf16(aH1, bL0, acc10, 0, 0, 0);    \
        acc11 = __builtin_amdgcn_mfma_f32_16x16x32_bf16(aH1, bL1, acc11, 0, 0, 0);    \
        acc00 = __builtin_amdgcn_mfma_f32_16x16x32_bf16(aL0, bH0, acc00, 0, 0, 0);    \
        acc01 = __builtin_amdgcn_mfma_f32_16x16x32_bf16(aL0, bH1, acc01, 0, 0, 0);    \
        acc10 = __builtin_amdgcn_mfma_f32_16x16x32_bf16(aL1, bH0, acc10, 0, 0, 0);    \
        acc11 = __builtin_amdgcn_mfma_f32_16x16x32_bf16(aL1, bH1, acc11, 0, 0, 0);    \
    } while (0)

    LOADA_REG(0);
    STAGE_B(0, 0);
    STOREA_SPLIT(0);
    __syncthreads();

    for (int kt = 0; kt < 8; ++kt) {       // K = 256 = 8 x 32
        const int cur = kt & 1;
        if (kt < 7) {
            STAGE_B(cur ^ 1, (kt + 1) * 32);
            LOADA_REG((kt + 1) * 32);
        }
        MFMA_STEP(cur);
        if (kt < 7) STOREA_SPLIT(cur ^ 1);
        __syncthreads();
    }

#define EPI(accv, rt, ct)                                                      \
    do {                                                                       \
        const int col = n0 + WC + (ct) * 16 + lr;                              \
        const float bb = bias ? bias[col] : 0.f;                               \
        _Pragma("unroll") for (int i = 0; i < 4; ++i) {                        \
            const int row = m0 + WR + (rt) * 16 + lg * 4 + i;                  \
            float v = accv[i] + bb;                                            \
            if (residual) v += residual[(size_t)row * D_EDGE + col];           \
            if (residual2) v += residual2[(size_t)row * D_EDGE + col];         \
            if (act == 1) v = 0.5f * v * (1.f + erff(v * 0.70710678118654752f)); \
            C[(size_t)row * D_EDGE + col] = v;                                 \
        }                                                                      \
    } while (0)
    EPI(acc00, 0, 0); EPI(acc01, 0, 1); EPI(acc10, 1, 0); EPI(acc11, 1, 1);
#undef LOADA_REG
#undef SPLIT1
#undef STOREA_SPLIT
#undef STAGE_B
#undef MFMA_STEP
#undef EPI
}

// ctx precompute, BOTH layers in one dispatch: grid (4, 128); by<64 layer1.
__global__ __launch_bounds__(256) void gemm_ctx(
    const float* __restrict__ nf, const int* __restrict__ src,
    const int* __restrict__ dst, const short* __restrict__ whiT,
    const short* __restrict__ wloT, const float* __restrict__ bn1,
    const float* __restrict__ bn2, float* __restrict__ ctx)
{
    int bx = blockIdx.x, by = blockIdx.y;
    xcd_remap(bx, by);
    const int Lyr = by >> 6, rb = by & 63;
    const short* BH = whiT + (size_t)(Lyr * 5) * 65536;
    const short* BL = wloT + (size_t)(Lyr * 5) * 65536;
    gemm_mfma_core(nullptr, nullptr, BH, BL, Lyr ? bn2 : bn1,
                   nullptr, nullptr, ctx + (size_t)Lyr * E_EDGES * D_EDGE,
                   rb * 64, bx * 64, nf, src, dst, 0);
}

// generic (Wo): A [+A2] @ W + bias + residual [+residual2]
__global__ __launch_bounds__(256) void gemm_mfma(
    const float* __restrict__ A, const float* __restrict__ A2,
    const short* __restrict__ BhiT, const short* __restrict__ BloT,
    const float* __restrict__ bias, const float* __restrict__ residual,
    const float* __restrict__ residual2, float* __restrict__ C, int act)
{
    int bx = blockIdx.x, by = blockIdx.y;
    xcd_remap(bx, by);
    gemm_mfma_core(A, A2, BhiT, BloT, bias, residual, residual2, C,
                   by * 64, bx * 64, nullptr, nullptr, nullptr, act);
}

// q/k/v fused, x = ef_in + ctx formed on the fly in A-staging.
__global__ __launch_bounds__(256) void gemm_mfma_qkv(
    const float* __restrict__ ef_in, const float* __restrict__ ctx,
    const short* __restrict__ whiT, const short* __restrict__ wloT,
    const float* __restrict__ bq, const float* __restrict__ bk,
    const float* __restrict__ bv,
    float* __restrict__ qb, float* __restrict__ kb, float* __restrict__ vb,
    int wbase)
{
    int bx = blockIdx.x, by = blockIdx.y;
    xcd_remap(bx, by);
    const int wsel = bx >> 2, nt = bx & 3;
    const short* BH = whiT + (size_t)(wbase + 1 + wsel) * 65536;
    const short* BL = wloT + (size_t)(wbase + 1 + wsel) * 65536;
    const float* bias = (wsel == 0) ? bq : (wsel == 1) ? bk : bv;
    float* C = (wsel == 0) ? qb : (wsel == 1) ? kb : vb;
    gemm_mfma_core(ef_in, ctx, BH, BL, bias, nullptr, nullptr, C,
                   by * 64, nt * 64, nullptr, nullptr, nullptr, 0);
}

// ---------------------------------------------------------------------------
// Sparse attention v4. Block = edge, wave = head, 4 groups of 16 lanes.
// Each group runs an INDEPENDENT online softmax over its candidate subset
// (i ≡ g mod 4), merged once at the end via the softmax-merge butterfly.
// ---------------------------------------------------------------------------
__global__ __launch_bounds__(256) void attn_sparse4(
    const float* __restrict__ q, const float* __restrict__ k,
    const float* __restrict__ v, const int* __restrict__ cand,
    const int* __restrict__ ccount, float* __restrict__ out)
{
    __shared__ int lc[CAP];
    const int e = blockIdx.x;
    const int t = threadIdx.x, h = t >> 6, lane = t & 63;
    const int g = lane >> 4, il = lane & 15;
    const int m = ccount[e];
    if (t < m) lc[t] = cand[(size_t)e * CAP + t];
    __syncthreads();

    const float4 q4 = *(const float4*)&q[(size_t)e * D_EDGE + h * HD + il * 4];
    float M = -1e30f, L = 0.f;
    float4 O = make_float4(0.f, 0.f, 0.f, 0.f);

    for (int i0 = g; i0 < m; i0 += 8) {
        const int f0 = lc[i0];
        const bool ok1 = (i0 + 4) < m;
        const int f1 = ok1 ? lc[i0 + 4] : f0;
        const float4 k0 = *(const float4*)&k[(size_t)f0 * D_EDGE + h * HD + il * 4];
        const float4 v0 = *(const float4*)&v[(size_t)f0 * D_EDGE + h * HD + il * 4];
        const float4 k1 = *(const float4*)&k[(size_t)f1 * D_EDGE + h * HD + il * 4];
        const float4 v1 = *(const float4*)&v[(size_t)f1 * D_EDGE + h * HD + il * 4];
        float s0 = q4.x * k0.x + q4.y * k0.y + q4.z * k0.z + q4.w * k0.w;
        float s1 = q4.x * k1.x + q4.y * k1.y + q4.z * k1.z + q4.w * k1.w;
        s0 += __shfl_xor(s0, 1); s1 += __shfl_xor(s1, 1);
        s0 += __shfl_xor(s0, 2); s1 += __shfl_xor(s1, 2);
        s0 += __shfl_xor(s0, 4); s1 += __shfl_xor(s1, 4);
        s0 += __shfl_xor(s0, 8); s1 += __shfl_xor(s1, 8);
        s0 *= 0.125f;                          // 1/sqrt(64)
        s1 = ok1 ? s1 * 0.125f : -1e30f;       // tail: p1 -> 0 exactly
        const float Mn = fmaxf(M, fmaxf(s0, s1));
        const float al = __expf(M - Mn);
        const float p0 = __expf(s0 - Mn), p1 = __expf(s1 - Mn);
        O.x = O.x * al + p0 * v0.x + p1 * v1.x;
        O.y = O.y * al + p0 * v0.y + p1 * v1.y;
        O.z = O.z * al + p0 * v0.z + p1 * v1.z;
        O.w = O.w * al + p0 * v0.w + p1 * v1.w;
        L = L * al + p0 + p1;
        M = Mn;
    }
    // merge the 4 groups: M_g -> Mo, scale each group's (O,L) by exp(M_g-Mo)
    float Mo = fmaxf(M, __shfl_xor(M, 16));
    Mo = fmaxf(Mo, __shfl_xor(Mo, 32));
    const float sc = __expf(M - Mo);           // empty group: exp(-1e30-Mo)=0
    O.x *= sc; O.y *= sc; O.z *= sc; O.w *= sc; L *= sc;
    O.x += __shfl_xor(O.x, 16); O.y += __shfl_xor(O.y, 16);
    O.z += __shfl_xor(O.z, 16); O.w += __shfl_xor(O.w, 16);
    L += __shfl_xor(L, 16);
    O.x += __shfl_xor(O.x, 32); O.y += __shfl_xor(O.y, 32);
    O.z += __shfl_xor(O.z, 32); O.w += __shfl_xor(O.w, 32);
    L += __shfl_xor(L, 32);
    if (lane < 16) {
        const float invL = 1.f / L;
        float4 r = make_float4(O.x * invL, O.y * invL, O.z * invL, O.w * invL);
        *(float4*)&out[(size_t)e * D_EDGE + h * HD + il * 4] = r;
    }
}

// ---------------------------------------------------------------------------
// Fused classifier v2: out = gelu(y@W1+b1)@W2 + b2.
// R10 POST-MORTEM FIX: 64 blocks x 64-row tiles was serial-latency-bound
// (60us, 1 block/CU, 64 CUs used). Now 256 blocks x 16-row tiles, LDS 35KB
// -> 4 blocks/CU, full GPU. Phase 1: wave w computes h[16][w*64..w*64+63]
// (4 col-frags x 3 split-MFMAs per K-tile). Phase 2: 16x16 out via 24 MFMAs,
// redundantly computed per wave (cheap), wave 0 stores.
// ---------------------------------------------------------------------------
__global__ __launch_bounds__(256) void gemm_cls(
    const float* __restrict__ y, const short* __restrict__ BhiT,
    const short* __restrict__ BloT, const float* __restrict__ b1,
    const float* __restrict__ W2, const float* __restrict__ b2,
    float* __restrict__ outp)
{
    __shared__ __attribute__((aligned(16))) char smem[35840];
    short* AsH = (short*)smem;                  // 16*40 sh = 1280 B
    short* AsL = (short*)(smem + 1280);         // 1280 B
    short* BsH = (short*)(smem + 2560);         // 256*32 sh = 16384 B
    short* BsL = (short*)(smem + 18944);        // 16384 -> 35328
    short* hH  = (short*)smem;                  // 16*264 sh = 8448 B (phase 2)
    short* hL  = (short*)(smem + 8448);         // 8448 -> 16896
    float* W2s = (float*)(smem + 16896);        // 16384 -> 33280

    const int t = threadIdx.x;
    const int w = t >> 6, lane = t & 63, lr = lane & 15, lg = lane >> 4;
    const int m0 = blockIdx.x * 16;

    f32x4 acc[4];
#pragma unroll
    for (int ct = 0; ct < 4; ++ct) acc[ct] = (f32x4){0.f, 0.f, 0.f, 0.f};

    for (int kt = 0; kt < 8; ++kt) {
        const int k0 = kt * 32;
        // stage A: 16 rows x 32 k f32 -> split bf16 (threads 0..127)
        if (t < 128) {
            const int row = t >> 3, kc = (t & 7) * 4;
            const float4 a4 = *(const float4*)&y[(size_t)(m0 + row) * 256 + k0 + kc];
            const float fv[4] = {a4.x, a4.y, a4.z, a4.w};
#pragma unroll
            for (int j = 0; j < 4; ++j) {
                const unsigned short hb = f2bf(fv[j]);
                AsH[row * 40 + kc + j] = (short)hb;
                AsL[row * 40 + kc + j] = (short)f2bf(fv[j] - bf2f(hb));
            }
        }
        // stage B: full 256n x 32k hi/lo via DMA (4+4 per thread)
#pragma unroll
        for (int p = 0; p < 4; ++p) {
            const int idx = t + 256 * p;
            const int n = idx >> 2, k8 = (idx & 3) * 8;
            gload_lds16(&BhiT[(size_t)n * 256 + k0 + k8], BsH + (size_t)idx * 8);
            gload_lds16(&BloT[(size_t)n * 256 + k0 + k8], BsL + (size_t)idx * 8);
        }
        __syncthreads();
        const short8v aH = *(const short8v*)&AsH[lr * 40 + lg * 8];
        const short8v aL = *(const short8v*)&AsL[lr * 40 + lg * 8];
#pragma unroll
        for (int ct = 0; ct < 4; ++ct) {
            const int c = w * 64 + ct * 16 + lr;
            const short8v bH = *(const short8v*)&BsH[c * 32 + lg * 8];
            const short8v bL = *(const short8v*)&BsL[c * 32 + lg * 8];
            acc[ct] = __builtin_amdgcn_mfma_f32_16x16x32_bf16(aH, bH, acc[ct], 0, 0, 0);
            acc[ct] = __builtin_amdgcn_mfma_f32_16x16x32_bf16(aH, bL, acc[ct], 0, 0, 0);
            acc[ct] = __builtin_amdgcn_mfma_f32_16x16x32_bf16(aL, bH, acc[ct], 0, 0, 0);
        }
        __syncthreads();    // LDS reads drained before restage / overwrite
    }

    // phase-1 epilogue: bias + gelu + split -> hH/hL (overlaps AsH..BsH tail,
    // safe: all phase-1 reads drained by the loop's final barrier)
#pragma unroll
    for (int ct = 0; ct < 4; ++ct) {
        const int col = w * 64 + ct * 16 + lr;
        const float bb = b1[col];
#pragma unroll
        for (int i = 0; i < 4; ++i) {
            const int row = lg * 4 + i;
            float vv = acc[ct][i] + bb;
            vv = 0.5f * vv * (1.f + erff(vv * 0.70710678118654752f));
            const unsigned short hb = f2bf(vv);
            hH[row * 264 + col] = (short)hb;
            hL[row * 264 + col] = (short)f2bf(vv - bf2f(hb));
        }
    }
    // stage W2 f32 (256x16 = 16KB) into LDS
#pragma unroll
    for (int p = 0; p < 4; ++p) {
        const int idx = t + 256 * p;       // 1024 x 16B
        gload_lds16(&W2[(size_t)idx * 4], W2s + (size_t)idx * 4);
    }
    __syncthreads();

    // phase 2: 16x16 out, redundantly per wave; wave 0 stores
    f32x4 o = {0.f, 0.f, 0.f, 0.f};
#pragma unroll
    for (int kk = 0; kk < 8; ++kk) {
        const short8v aH = *(const short8v*)&hH[lr * 264 + kk * 32 + lg * 8];
        const short8v aL = *(const short8v*)&hL[lr * 264 + kk * 32 + lg * 8];
        short8v bH, bL;
#pragma unroll
        for (int j = 0; j < 8; ++j) {
            const float x = W2s[(size_t)(kk * 32 + lg * 8 + j) * 16 + lr];
            const unsigned short hb = f2bf(x);
            bH[j] = (short)hb; bL[j] = (short)f2bf(x - bf2f(hb));
        }
        o = __builtin_amdgcn_mfma_f32_16x16x32_bf16(aH, bH, o, 0, 0, 0);
        o = __builtin_amdgcn_mfma_f32_16x16x32_bf16(aH, bL, o, 0, 0, 0);
        o = __builtin_amdgcn_mfma_f32_16x16x32_bf16(aL, bH, o, 0, 0, 0);
    }
    if (w == 0) {
#pragma unroll
        for (int i = 0; i < 4; ++i) {
            const int row = m0 + lg * 4 + i;
            outp[(size_t)row * 16 + lr] = o[i] + b2[lr];
        }
    }
}

// ---------------------------------------------------------------------------
extern "C" void kernel_launch(void* const* d_in, const int* in_sizes, int n_in,
                              void* d_out, int out_size, void* d_ws, size_t ws_size,
                              hipStream_t stream)
{
    const float* nf = (const float*)d_in[0];
    const float* ef = (const float*)d_in[1];
    const int* ei = (const int*)d_in[2];
    const int* src = ei;
    const int* dst = ei + E_EDGES;

    const float* a_Wn[2] = {(const float*)d_in[3],  (const float*)d_in[13]};
    const float* a_bn[2] = {(const float*)d_in[4],  (const float*)d_in[14]};
    const float* a_Wq[2] = {(const float*)d_in[5],  (const float*)d_in[15]};
    const float* a_bq[2] = {(const float*)d_in[6],  (const float*)d_in[16]};
    const float* a_Wk[2] = {(const float*)d_in[7],  (const float*)d_in[17]};
    const float* a_bk[2] = {(const float*)d_in[8],  (const float*)d_in[18]};
    const float* a_Wv[2] = {(const float*)d_in[9],  (const float*)d_in[19]};
    const float* a_bv[2] = {(const float*)d_in[10], (const float*)d_in[20]};
    const float* a_Wo[2] = {(const float*)d_in[11], (const float*)d_in[21]};
    const float* a_bo[2] = {(const float*)d_in[12], (const float*)d_in[22]};
    const float* cls_W1 = (const float*)d_in[23];
    const float* cls_b1 = (const float*)d_in[24];
    const float* cls_W2 = (const float*)d_in[25];
    const float* cls_b2 = (const float*)d_in[26];

    const size_t buf = (size_t)E_EDGES * D_EDGE;  // 1M floats = 4MB
    float* ws = (float*)d_ws;
    float* ctx1 = ws + 0 * buf;         // layer-1 context; later aliased by y2
    float* ctx2 = ws + 1 * buf;
    float* qb   = ws + 2 * buf;
    float* kb   = ws + 3 * buf;
    float* vb   = ws + 4 * buf;
    float* ao   = ws + 5 * buf;
    float* y1   = ws + 6 * buf;
    float* y2   = ctx1;                 // ctx1 dead after layer-1 Wo
    int* cand   = (int*)(ws + 7 * buf);            // 4096*128*4 = 2MB
    int* ccount = cand + (size_t)E_EDGES * CAP;    // 16KB
    short* whiT = (short*)(ccount + E_EDGES);      // 11 x 128KB
    short* wloT = whiT + (size_t)11 * 65536;       // 11 x 128KB

    const dim3 gGemm(D_EDGE / 64, E_EDGES / 64);   // (4, 64) = 256 blocks
    const dim3 gCtx(D_EDGE / 64, 2 * E_EDGES / 64);// (4, 128) = 512 blocks
    const dim3 gQkv(12, E_EDGES / 64);             // (12, 64) = 768 blocks

    prep<<<176 + E_EDGES / 4, 256, 0, stream>>>(
        a_Wn[0], a_Wq[0], a_Wk[0], a_Wv[0], a_Wo[0],
        a_Wn[1], a_Wq[1], a_Wk[1], a_Wv[1], a_Wo[1],
        cls_W1, whiT, wloT, src, dst, cand, ccount);

    gemm_ctx<<<gCtx, 256, 0, stream>>>(nf, src, dst, whiT, wloT,
                                       a_bn[0], a_bn[1], ctx1);

    const float* ef_in = ef;
    const float* ctxL[2] = {ctx1, ctx2};
    float* yout[2] = {y1, y2};
    for (int L = 0; L < 2; ++L) {
        const int wbase = L * 5;
        gemm_mfma_qkv<<<gQkv, 256, 0, stream>>>(
            ef_in, ctxL[L], whiT, wloT, a_bq[L], a_bk[L], a_bv[L],
            qb, kb, vb, wbase);
        attn_sparse4<<<E_EDGES, 256, 0, stream>>>(qb, kb, vb, cand, ccount, ao);
        // y = (ef_in + ctx) + ao @ Wo + bo
        gemm_mfma<<<gGemm, 256, 0, stream>>>(
            ao, nullptr, whiT + (size_t)(wbase + 4) * 65536,
            wloT + (size_t)(wbase + 4) * 65536,
            a_bo[L], ef_in, ctxL[L], yout[L], 0);
        ef_in = yout[L];
    }

    gemm_cls<<<E_EDGES / 16, 256, 0, stream>>>(
        y2, whiT + (size_t)10 * 65536, wloT + (size_t)10 * 65536,
        cls_b1, cls_W2, cls_b2, (float*)d_out);
}

// Round 12
// 132.392 us; speedup vs baseline: 3.4889x; 1.0262x over previous
//
#include <hip/hip_runtime.h>
#include <math.h>

#define E_EDGES 4096
#define N_NODES 1024
#define D_NODE 128
#define D_EDGE 256
#define HEADS 4
#define HD 64
#define N_CLASSES 16
#define CAP 128   // max adjacent edges per edge (avg ~16, worst ~50)

typedef __attribute__((ext_vector_type(8))) short short8v;  // 8 bf16 = 4 VGPR
typedef __attribute__((ext_vector_type(4))) short short4v;  // 4 bf16 = 2 VGPR
typedef __attribute__((ext_vector_type(4))) float f32x4;    // MFMA C/D frag

__device__ __forceinline__ unsigned short f2bf(float f) {
    unsigned u = __float_as_uint(f);
    return (unsigned short)((u + 0x7FFFu + ((u >> 16) & 1u)) >> 16);
}
__device__ __forceinline__ float bf2f(unsigned short b) {
    return __uint_as_float(((unsigned)b) << 16);
}

// direct-to-LDS 16B DMA (gfx950): per-wave dest = uniform base + lane*16,
// matched by our per-thread dest (base + t*16).
__device__ __forceinline__ void gload_lds16(const void* g, void* l) {
    __builtin_amdgcn_global_load_lds((const __attribute__((address_space(1))) void*)g,
                                     (__attribute__((address_space(3))) void*)l, 16, 0, 0);
}

// ---------------------------------------------------------------------------
// prep: coalesced split of 11 f32 W[k][n] (256x256) into TRANSPOSED bf16
// hi/lo WT[n][k] via 64x64 LDS transpose tile. 176 blocks (11 mats x 16).
// Weight order: a1{Wn,Wq,Wk,Wv,Wo}, a2{...}, cls_W1.
// ---------------------------------------------------------------------------
__global__ __launch_bounds__(256) void prep(
    const float* W0, const float* W1, const float* W2, const float* W3,
    const float* W4, const float* W5, const float* W6, const float* W7,
    const float* W8, const float* W9, const float* W10,
    short* hiT, short* loT)
{
    __shared__ float tl[64][65];
    const int t = threadIdx.x;
    const float* Ws[11] = {W0, W1, W2, W3, W4, W5, W6, W7, W8, W9, W10};
    const int mat = blockIdx.x >> 4, tile = blockIdx.x & 15;
    const int k0 = (tile >> 2) * 64, n0 = (tile & 3) * 64;
    const float* W = Ws[mat];
#pragma unroll
    for (int p = 0; p < 4; ++p) {
        const int kr = (t >> 4) + p * 16;
        const int nc = (t & 15) * 4;
        *(float4*)&tl[kr][nc] = *(const float4*)&W[(size_t)(k0 + kr) * 256 + n0 + nc];
    }
    __syncthreads();
    const int n = t >> 2, ks = (t & 3) * 16;
    short8v h0, h1, l0, l1;
#pragma unroll
    for (int j = 0; j < 8; ++j) {
        const float x = tl[ks + j][n];
        const unsigned short hb = f2bf(x);
        h0[j] = (short)hb; l0[j] = (short)f2bf(x - bf2f(hb));
    }
#pragma unroll
    for (int j = 0; j < 8; ++j) {
        const float x = tl[ks + 8 + j][n];
        const unsigned short hb = f2bf(x);
        h1[j] = (short)hb; l1[j] = (short)f2bf(x - bf2f(hb));
    }
    short* ho = hiT + (size_t)mat * 65536;
    short* lo = loT + (size_t)mat * 65536;
    *(short8v*)&ho[(size_t)(n0 + n) * 256 + k0 + ks] = h0;
    *(short8v*)&ho[(size_t)(n0 + n) * 256 + k0 + ks + 8] = h1;
    *(short8v*)&lo[(size_t)(n0 + n) * 256 + k0 + ks] = l0;
    *(short8v*)&lo[(size_t)(n0 + n) * 256 + k0 + ks + 8] = l1;
}

// ---------------------------------------------------------------------------
// Split-bf16 MFMA GEMM core, BM=32: C[32x64] = act((A[+A2])@B + bias + r1+r2),
// K=256. A@B = AhBh + AhBl + AlBh. 4 waves (2x2), wave = 16x32 out = 2 frags,
// 6 mfma_f32_16x16x32_bf16 per K-tile. LDS 26.6KB -> up to 6 blocks/CU
// (R11 cores were 37KB/64-row, 1 block/CU at 256-grid: every barrier-drain
// stalled the SIMD with no other wave to run — THE limiter per R7 evidence).
// Dbuf, ONE barrier/K-tile; A loads issued before MFMA, split after (T14);
// B via global_load_lds DMA. If nf: A row m = concat(nf[src[m]],nf[dst[m]]).
// ---------------------------------------------------------------------------
__device__ __forceinline__ void mcore32(
    const float* __restrict__ A, const float* __restrict__ A2,
    const short* __restrict__ BhiT, const short* __restrict__ BloT,
    const float* __restrict__ bias, const float* __restrict__ res,
    const float* __restrict__ res2, float* __restrict__ C,
    int m0, int n0,
    const float* __restrict__ nf, const int* __restrict__ src,
    const int* __restrict__ dst, int act)
{
    __shared__ short AsH[2][32 * 40];   // [buf][m][kpad40]
    __shared__ short AsL[2][32 * 40];
    __shared__ short BsH[2][64 * 32];   // [buf][n][k32] (DMA linear)
    __shared__ short BsL[2][64 * 32];
    const int t = threadIdx.x;
    const int w = t >> 6, lane = t & 63, lr = lane & 15, lg = lane >> 4;
    const int WR = (w >> 1) * 16, WC = (w & 1) * 32;
    const int ar = t >> 3, akc = (t & 7) * 4;   // A stage: row, k-col (float4)
    const int bn = t >> 2, bkc = (t & 3) * 8;   // B DMA: n-row, k-col (16B)

    int nS = 0, nD = 0;
    if (nf) { nS = src[m0 + ar]; nD = dst[m0 + ar]; }

    f32x4 acc0 = {0.f, 0.f, 0.f, 0.f}, acc1 = {0.f, 0.f, 0.f, 0.f};
    float4 av;

#define LOADA_R(k0)                                                            \
    do {                                                                       \
        const int kq = (k0) + akc;                                             \
        if (nf) {                                                              \
            const float* pp = (kq < D_NODE)                                    \
                ? &nf[(size_t)nS * D_NODE + kq]                                \
                : &nf[(size_t)nD * D_NODE + kq - D_NODE];                      \
            av = *(const float4*)pp;                                           \
        } else {                                                               \
            av = *(const float4*)&A[(size_t)(m0 + ar) * 256 + kq];             \
            if (A2) {                                                          \
                const float4 c_ = *(const float4*)&A2[(size_t)(m0 + ar) * 256 + kq]; \
                av.x += c_.x; av.y += c_.y; av.z += c_.z; av.w += c_.w;        \
            }                                                                  \
        }                                                                      \
    } while (0)
#define STOREA_S(buf)                                                          \
    do {                                                                       \
        short4v ah, al;                                                        \
        const float fv[4] = {av.x, av.y, av.z, av.w};                          \
        _Pragma("unroll") for (int j = 0; j < 4; ++j) {                        \
            const unsigned short hb = f2bf(fv[j]);                             \
            ah[j] = (short)hb; al[j] = (short)f2bf(fv[j] - bf2f(hb));          \
        }                                                                      \
        *(short4v*)&AsH[buf][ar * 40 + akc] = ah;                              \
        *(short4v*)&AsL[buf][ar * 40 + akc] = al;                              \
    } while (0)
#define STAGE_B(buf, k0)                                                       \
    do {                                                                       \
        gload_lds16(&BhiT[(size_t)(n0 + bn) * 256 + (k0) + bkc],               \
                    (short*)&BsH[buf][0] + t * 8);                             \
        gload_lds16(&BloT[(size_t)(n0 + bn) * 256 + (k0) + bkc],               \
                    (short*)&BsL[buf][0] + t * 8);                             \
    } while (0)
#define MFMA_STEP(buf)                                                         \
    do {                                                                       \
        const int c0 = WC + lr, c1 = WC + 16 + lr;                             \
        const short8v bH0 = *(const short8v*)&BsH[buf][c0 * 32 + lg * 8];      \
        const short8v bL0 = *(const short8v*)&BsL[buf][c0 * 32 + lg * 8];      \
        const short8v bH1 = *(const short8v*)&BsH[buf][c1 * 32 + lg * 8];      \
        const short8v bL1 = *(const short8v*)&BsL[buf][c1 * 32 + lg * 8];      \
        const short8v aH = *(const short8v*)&AsH[buf][(WR + lr) * 40 + lg * 8];\
        const short8v aL = *(const short8v*)&AsL[buf][(WR + lr) * 40 + lg * 8];\
        acc0 = __builtin_amdgcn_mfma_f32_16x16x32_bf16(aH, bH0, acc0, 0, 0, 0);\
        acc1 = __builtin_amdgcn_mfma_f32_16x16x32_bf16(aH, bH1, acc1, 0, 0, 0);\
        acc0 = __builtin_amdgcn_mfma_f32_16x16x32_bf16(aH, bL0, acc0, 0, 0, 0);\
        acc1 = __builtin_amdgcn_mfma_f32_16x16x32_bf16(aH, bL1, acc1, 0, 0, 0);\
        acc0 = __builtin_amdgcn_mfma_f32_16x16x32_bf16(aL, bH0, acc0, 0, 0, 0);\
        acc1 = __builtin_amdgcn_mfma_f32_16x16x32_bf16(aL, bH1, acc1, 0, 0, 0);\
    } while (0)

    LOADA_R(0);
    STAGE_B(0, 0);
    STOREA_S(0);
    __syncthreads();

    for (int kt = 0; kt < 8; ++kt) {       // K = 256 = 8 x 32
        const int cur = kt & 1;
        if (kt < 7) {
            STAGE_B(cur ^ 1, (kt + 1) * 32);
            LOADA_R((kt + 1) * 32);
        }
        MFMA_STEP(cur);
        if (kt < 7) STOREA_S(cur ^ 1);
        __syncthreads();
    }

#define EPI(accv, ct)                                                          \
    do {                                                                       \
        const int col = n0 + WC + (ct) * 16 + lr;                              \
        const float bb = bias ? bias[col] : 0.f;                               \
        _Pragma("unroll") for (int i = 0; i < 4; ++i) {                        \
            const int row = m0 + WR + lg * 4 + i;                              \
            float v = accv[i] + bb;                                            \
            if (res)  v += res[(size_t)row * D_EDGE + col];                    \
            if (res2) v += res2[(size_t)row * D_EDGE + col];                   \
            if (act == 1) v = 0.5f * v * (1.f + erff(v * 0.70710678118654752f)); \
            C[(size_t)row * D_EDGE + col] = v;                                 \
        }                                                                      \
    } while (0)
    EPI(acc0, 0); EPI(acc1, 1);
#undef LOADA_R
#undef STOREA_S
#undef STAGE_B
#undef MFMA_STEP
#undef EPI
}

// ---------------------------------------------------------------------------
// ctx + adjacency, one dispatch (2048 blocks, independent work):
//  blocks 0..1023: ctx_L = concat(nf[src],nf[dst]) @ Wn_L + bn_L, BOTH layers
//    (8192 rows / 32 = 256 row-tiles x 4 col-tiles), XCD row-panel pinning.
//  blocks 1024..2047: adjacency CSR build (wave per edge, ballot-compaction).
// ---------------------------------------------------------------------------
__global__ __launch_bounds__(256) void ctx_adj(
    const float* __restrict__ nf, const int* __restrict__ src,
    const int* __restrict__ dst, const short* __restrict__ whiT,
    const short* __restrict__ wloT, const float* __restrict__ bn1,
    const float* __restrict__ bn2, float* __restrict__ ctx,
    int* __restrict__ cand, int* __restrict__ ccount)
{
    if (blockIdx.x < 1024) {
        const int lid = blockIdx.x;
        const int g = lid & 7, s = lid >> 3;       // XCD, slot
        const int rowt = g * 32 + (s >> 2);        // [0,256)
        const int ct = s & 3;
        const int R = rowt * 32;
        const int Lyr = R >> 12;                   // R >= 4096 -> layer 2
        const int r = R & (E_EDGES - 1);
        mcore32(nullptr, nullptr,
                whiT + (size_t)(Lyr * 5) * 65536, wloT + (size_t)(Lyr * 5) * 65536,
                Lyr ? bn2 : bn1, nullptr, nullptr,
                ctx + (size_t)Lyr * E_EDGES * D_EDGE,
                r, ct * 64, nf, src, dst, 0);
    } else {
        const int t = threadIdx.x;
        const int w = t >> 6, lane = t & 63;
        const int e = (blockIdx.x - 1024) * 4 + w;
        const int a = src[e], b = dst[e];
        int* my = cand + (size_t)e * CAP;
        int base = 0;
        for (int c0 = 0; c0 < E_EDGES; c0 += 64) {
            const int f = c0 + lane;
            const int sf = src[f], df = dst[f];
            const bool adj = (sf == a) | (sf == b) | (df == a) | (df == b);
            const unsigned long long mk = __ballot(adj);
            if (adj) {
                const int pos = base + __popcll(mk & ((1ull << lane) - 1ull));
                if (pos < CAP) my[pos] = f;
            }
            base += __popcll(mk);
        }
        if (lane == 0) ccount[e] = (base < CAP) ? base : CAP;
    }
}

// q/k/v fused: 1536 blocks = 6 blocks/CU, one pass. Row-panel (12 blocks:
// 3 mats x 4 col-tiles) pinned to one XCD -> x rows L2-resident.
__global__ __launch_bounds__(256) void gemm_qkv32(
    const float* __restrict__ ef_in, const float* __restrict__ ctx,
    const short* __restrict__ whiT, const short* __restrict__ wloT,
    const float* __restrict__ bq, const float* __restrict__ bk,
    const float* __restrict__ bv,
    float* __restrict__ qb, float* __restrict__ kb, float* __restrict__ vb,
    int wbase)
{
    const int lid = blockIdx.x;
    const int g = lid & 7, s = lid >> 3;           // s in [0,192)
    const int rowt = g * 16 + s / 12;              // [0,128)
    const int rem = s % 12, wsel = rem >> 2, ct = rem & 3;
    const short* BH = whiT + (size_t)(wbase + 1 + wsel) * 65536;
    const short* BL = wloT + (size_t)(wbase + 1 + wsel) * 65536;
    const float* bias = (wsel == 0) ? bq : (wsel == 1) ? bk : bv;
    float* C = (wsel == 0) ? qb : (wsel == 1) ? kb : vb;
    mcore32(ef_in, ctx, BH, BL, bias, nullptr, nullptr, C,
            rowt * 32, ct * 64, nullptr, nullptr, nullptr, 0);
}

// Wo: 512 blocks = 2 blocks/CU. y = ao@Wo + bo + ef_in + ctx.
__global__ __launch_bounds__(256) void gemm_wo32(
    const float* __restrict__ ao, const short* __restrict__ BhiT,
    const short* __restrict__ BloT, const float* __restrict__ bo,
    const float* __restrict__ ef_in, const float* __restrict__ ctx,
    float* __restrict__ y)
{
    const int lid = blockIdx.x;
    const int g = lid & 7, s = lid >> 3;           // s in [0,64)
    const int rowt = g * 16 + (s >> 2);            // [0,128)
    const int ct = s & 3;
    mcore32(ao, nullptr, BhiT, BloT, bo, ef_in, ctx, y,
            rowt * 32, ct * 64, nullptr, nullptr, nullptr, 0);
}

// ---------------------------------------------------------------------------
// Sparse attention v4. Block = edge, wave = head, 4 groups of 16 lanes.
// Each group runs an INDEPENDENT online softmax over its candidate subset
// (i ≡ g mod 4), merged once at the end via the softmax-merge butterfly.
// ---------------------------------------------------------------------------
__global__ __launch_bounds__(256) void attn_sparse4(
    const float* __restrict__ q, const float* __restrict__ k,
    const float* __restrict__ v, const int* __restrict__ cand,
    const int* __restrict__ ccount, float* __restrict__ out)
{
    __shared__ int lc[CAP];
    const int e = blockIdx.x;
    const int t = threadIdx.x, h = t >> 6, lane = t & 63;
    const int g = lane >> 4, il = lane & 15;
    const int m = ccount[e];
    if (t < m) lc[t] = cand[(size_t)e * CAP + t];
    __syncthreads();

    const float4 q4 = *(const float4*)&q[(size_t)e * D_EDGE + h * HD + il * 4];
    float M = -1e30f, L = 0.f;
    float4 O = make_float4(0.f, 0.f, 0.f, 0.f);

    for (int i0 = g; i0 < m; i0 += 8) {
        const int f0 = lc[i0];
        const bool ok1 = (i0 + 4) < m;
        const int f1 = ok1 ? lc[i0 + 4] : f0;
        const float4 k0 = *(const float4*)&k[(size_t)f0 * D_EDGE + h * HD + il * 4];
        const float4 v0 = *(const float4*)&v[(size_t)f0 * D_EDGE + h * HD + il * 4];
        const float4 k1 = *(const float4*)&k[(size_t)f1 * D_EDGE + h * HD + il * 4];
        const float4 v1 = *(const float4*)&v[(size_t)f1 * D_EDGE + h * HD + il * 4];
        float s0 = q4.x * k0.x + q4.y * k0.y + q4.z * k0.z + q4.w * k0.w;
        float s1 = q4.x * k1.x + q4.y * k1.y + q4.z * k1.z + q4.w * k1.w;
        s0 += __shfl_xor(s0, 1); s1 += __shfl_xor(s1, 1);
        s0 += __shfl_xor(s0, 2); s1 += __shfl_xor(s1, 2);
        s0 += __shfl_xor(s0, 4); s1 += __shfl_xor(s1, 4);
        s0 += __shfl_xor(s0, 8); s1 += __shfl_xor(s1, 8);
        s0 *= 0.125f;                          // 1/sqrt(64)
        s1 = ok1 ? s1 * 0.125f : -1e30f;       // tail: p1 -> 0 exactly
        const float Mn = fmaxf(M, fmaxf(s0, s1));
        const float al = __expf(M - Mn);
        const float p0 = __expf(s0 - Mn), p1 = __expf(s1 - Mn);
        O.x = O.x * al + p0 * v0.x + p1 * v1.x;
        O.y = O.y * al + p0 * v0.y + p1 * v1.y;
        O.z = O.z * al + p0 * v0.z + p1 * v1.z;
        O.w = O.w * al + p0 * v0.w + p1 * v1.w;
        L = L * al + p0 + p1;
        M = Mn;
    }
    // merge the 4 groups: M_g -> Mo, scale each group's (O,L) by exp(M_g-Mo)
    float Mo = fmaxf(M, __shfl_xor(M, 16));
    Mo = fmaxf(Mo, __shfl_xor(Mo, 32));
    const float sc = __expf(M - Mo);           // empty group: exp(-1e30-Mo)=0
    O.x *= sc; O.y *= sc; O.z *= sc; O.w *= sc; L *= sc;
    O.x += __shfl_xor(O.x, 16); O.y += __shfl_xor(O.y, 16);
    O.z += __shfl_xor(O.z, 16); O.w += __shfl_xor(O.w, 16);
    L += __shfl_xor(L, 16);
    O.x += __shfl_xor(O.x, 32); O.y += __shfl_xor(O.y, 32);
    O.z += __shfl_xor(O.z, 32); O.w += __shfl_xor(O.w, 32);
    L += __shfl_xor(L, 32);
    if (lane < 16) {
        const float invL = 1.f / L;
        float4 r = make_float4(O.x * invL, O.y * invL, O.z * invL, O.w * invL);
        *(float4*)&out[(size_t)e * D_EDGE + h * HD + il * 4] = r;
    }
}

// ---------------------------------------------------------------------------
// Fused classifier v2 (R11-proven): out = gelu(y@W1+b1)@W2 + b2.
// 256 blocks x 16-row tiles, LDS 35KB -> 4 blocks/CU.
// ---------------------------------------------------------------------------
__global__ __launch_bounds__(256) void gemm_cls(
    const float* __restrict__ y, const short* __restrict__ BhiT,
    const short* __restrict__ BloT, const float* __restrict__ b1,
    const float* __restrict__ W2, const float* __restrict__ b2,
    float* __restrict__ outp)
{
    __shared__ __attribute__((aligned(16))) char smem[35840];
    short* AsH = (short*)smem;                  // 16*40 sh = 1280 B
    short* AsL = (short*)(smem + 1280);
    short* BsH = (short*)(smem + 2560);         // 256*32 sh = 16384 B
    short* BsL = (short*)(smem + 18944);        // -> 35328
    short* hH  = (short*)smem;                  // 16*264 sh = 8448 B (ph 2)
    short* hL  = (short*)(smem + 8448);
    float* W2s = (float*)(smem + 16896);        // 16384 -> 33280

    const int t = threadIdx.x;
    const int w = t >> 6, lane = t & 63, lr = lane & 15, lg = lane >> 4;
    const int m0 = blockIdx.x * 16;

    f32x4 acc[4];
#pragma unroll
    for (int ct = 0; ct < 4; ++ct) acc[ct] = (f32x4){0.f, 0.f, 0.f, 0.f};

    for (int kt = 0; kt < 8; ++kt) {
        const int k0 = kt * 32;
        if (t < 128) {
            const int row = t >> 3, kc = (t & 7) * 4;
            const float4 a4 = *(const float4*)&y[(size_t)(m0 + row) * 256 + k0 + kc];
            const float fv[4] = {a4.x, a4.y, a4.z, a4.w};
#pragma unroll
            for (int j = 0; j < 4; ++j) {
                const unsigned short hb = f2bf(fv[j]);
                AsH[row * 40 + kc + j] = (short)hb;
                AsL[row * 40 + kc + j] = (short)f2bf(fv[j] - bf2f(hb));
            }
        }
#pragma unroll
        for (int p = 0; p < 4; ++p) {
            const int idx = t + 256 * p;
            const int n = idx >> 2, k8 = (idx & 3) * 8;
            gload_lds16(&BhiT[(size_t)n * 256 + k0 + k8], BsH + (size_t)idx * 8);
            gload_lds16(&BloT[(size_t)n * 256 + k0 + k8], BsL + (size_t)idx * 8);
        }
        __syncthreads();
        const short8v aH = *(const short8v*)&AsH[lr * 40 + lg * 8];
        const short8v aL = *(const short8v*)&AsL[lr * 40 + lg * 8];
#pragma unroll
        for (int ct = 0; ct < 4; ++ct) {
            const int c = w * 64 + ct * 16 + lr;
            const short8v bH = *(const short8v*)&BsH[c * 32 + lg * 8];
            const short8v bL = *(const short8v*)&BsL[c * 32 + lg * 8];
            acc[ct] = __builtin_amdgcn_mfma_f32_16x16x32_bf16(aH, bH, acc[ct], 0, 0, 0);
            acc[ct] = __builtin_amdgcn_mfma_f32_16x16x32_bf16(aH, bL, acc[ct], 0, 0, 0);
            acc[ct] = __builtin_amdgcn_mfma_f32_16x16x32_bf16(aL, bH, acc[ct], 0, 0, 0);
        }
        __syncthreads();
    }

#pragma unroll
    for (int ct = 0; ct < 4; ++ct) {
        const int col = w * 64 + ct * 16 + lr;
        const float bb = b1[col];
#pragma unroll
        for (int i = 0; i < 4; ++i) {
            const int row = lg * 4 + i;
            float vv = acc[ct][i] + bb;
            vv = 0.5f * vv * (1.f + erff(vv * 0.70710678118654752f));
            const unsigned short hb = f2bf(vv);
            hH[row * 264 + col] = (short)hb;
            hL[row * 264 + col] = (short)f2bf(vv - bf2f(hb));
        }
    }
#pragma unroll
    for (int p = 0; p < 4; ++p) {
        const int idx = t + 256 * p;
        gload_lds16(&W2[(size_t)idx * 4], W2s + (size_t)idx * 4);
    }
    __syncthreads();

    f32x4 o = {0.f, 0.f, 0.f, 0.f};
#pragma unroll
    for (int kk = 0; kk < 8; ++kk) {
        const short8v aH = *(const short8v*)&hH[lr * 264 + kk * 32 + lg * 8];
        const short8v aL = *(const short8v*)&hL[lr * 264 + kk * 32 + lg * 8];
        short8v bH, bL;
#pragma unroll
        for (int j = 0; j < 8; ++j) {
            const float x = W2s[(size_t)(kk * 32 + lg * 8 + j) * 16 + lr];
            const unsigned short hb = f2bf(x);
            bH[j] = (short)hb; bL[j] = (short)f2bf(x - bf2f(hb));
        }
        o = __builtin_amdgcn_mfma_f32_16x16x32_bf16(aH, bH, o, 0, 0, 0);
        o = __builtin_amdgcn_mfma_f32_16x16x32_bf16(aH, bL, o, 0, 0, 0);
        o = __builtin_amdgcn_mfma_f32_16x16x32_bf16(aL, bH, o, 0, 0, 0);
    }
    if (w == 0) {
#pragma unroll
        for (int i = 0; i < 4; ++i) {
            const int row = m0 + lg * 4 + i;
            outp[(size_t)row * 16 + lr] = o[i] + b2[lr];
        }
    }
}

// ---------------------------------------------------------------------------
extern "C" void kernel_launch(void* const* d_in, const int* in_sizes, int n_in,
                              void* d_out, int out_size, void* d_ws, size_t ws_size,
                              hipStream_t stream)
{
    const float* nf = (const float*)d_in[0];
    const float* ef = (const float*)d_in[1];
    const int* ei = (const int*)d_in[2];
    const int* src = ei;
    const int* dst = ei + E_EDGES;

    const float* a_Wn[2] = {(const float*)d_in[3],  (const float*)d_in[13]};
    const float* a_bn[2] = {(const float*)d_in[4],  (const float*)d_in[14]};
    const float* a_Wq[2] = {(const float*)d_in[5],  (const float*)d_in[15]};
    const float* a_bq[2] = {(const float*)d_in[6],  (const float*)d_in[16]};
    const float* a_Wk[2] = {(const float*)d_in[7],  (const float*)d_in[17]};
    const float* a_bk[2] = {(const float*)d_in[8],  (const float*)d_in[18]};
    const float* a_Wv[2] = {(const float*)d_in[9],  (const float*)d_in[19]};
    const float* a_bv[2] = {(const float*)d_in[10], (const float*)d_in[20]};
    const float* a_Wo[2] = {(const float*)d_in[11], (const float*)d_in[21]};
    const float* a_bo[2] = {(const float*)d_in[12], (const float*)d_in[22]};
    const float* cls_W1 = (const float*)d_in[23];
    const float* cls_b1 = (const float*)d_in[24];
    const float* cls_W2 = (const float*)d_in[25];
    const float* cls_b2 = (const float*)d_in[26];

    const size_t buf = (size_t)E_EDGES * D_EDGE;  // 1M floats = 4MB
    float* ws = (float*)d_ws;
    float* ctx1 = ws + 0 * buf;         // layer-1 context; later aliased by y2
    float* ctx2 = ws + 1 * buf;
    float* qb   = ws + 2 * buf;
    float* kb   = ws + 3 * buf;
    float* vb   = ws + 4 * buf;
    float* ao   = ws + 5 * buf;
    float* y1   = ws + 6 * buf;
    float* y2   = ctx1;                 // ctx1 dead after layer-1 Wo
    int* cand   = (int*)(ws + 7 * buf);            // 4096*128*4 = 2MB
    int* ccount = cand + (size_t)E_EDGES * CAP;    // 16KB
    short* whiT = (short*)(ccount + E_EDGES);      // 11 x 128KB
    short* wloT = whiT + (size_t)11 * 65536;       // 11 x 128KB

    prep<<<176, 256, 0, stream>>>(
        a_Wn[0], a_Wq[0], a_Wk[0], a_Wv[0], a_Wo[0],
        a_Wn[1], a_Wq[1], a_Wk[1], a_Wv[1], a_Wo[1],
        cls_W1, whiT, wloT);

    // ctx (1024 GEMM blocks) + adjacency (1024 blocks) in one dispatch
    ctx_adj<<<2048, 256, 0, stream>>>(nf, src, dst, whiT, wloT,
                                      a_bn[0], a_bn[1], ctx1, cand, ccount);

    const float* ef_in = ef;
    const float* ctxL[2] = {ctx1, ctx2};
    float* yout[2] = {y1, y2};
    for (int L = 0; L < 2; ++L) {
        const int wbase = L * 5;
        gemm_qkv32<<<1536, 256, 0, stream>>>(
            ef_in, ctxL[L], whiT, wloT, a_bq[L], a_bk[L], a_bv[L],
            qb, kb, vb, wbase);
        attn_sparse4<<<E_EDGES, 256, 0, stream>>>(qb, kb, vb, cand, ccount, ao);
        gemm_wo32<<<512, 256, 0, stream>>>(
            ao, whiT + (size_t)(wbase + 4) * 65536,
            wloT + (size_t)(wbase + 4) * 65536,
            a_bo[L], ef_in, ctxL[L], yout[L]);
        ef_in = yout[L];
    }

    gemm_cls<<<E_EDGES / 16, 256, 0, stream>>>(
        y2, whiT + (size_t)10 * 65536, wloT + (size_t)10 * 65536,
        cls_b1, cls_W2, cls_b2, (float*)d_out);
}

// Round 13
// 129.048 us; speedup vs baseline: 3.5793x; 1.0259x over previous
//
#include <hip/hip_runtime.h>
#include <math.h>

#define E_EDGES 4096
#define N_NODES 1024
#define D_NODE 128
#define D_EDGE 256
#define HEADS 4
#define HD 64
#define N_CLASSES 16
#define CAP 128   // max adjacent edges per edge (avg ~16, worst ~50)

typedef __attribute__((ext_vector_type(8))) short short8v;  // 8 bf16 = 4 VGPR
typedef __attribute__((ext_vector_type(4))) short short4v;  // 4 bf16 = 2 VGPR
typedef __attribute__((ext_vector_type(4))) float f32x4;    // MFMA C/D frag

__device__ __forceinline__ unsigned short f2bf(float f) {
    unsigned u = __float_as_uint(f);
    return (unsigned short)((u + 0x7FFFu + ((u >> 16) & 1u)) >> 16);
}
__device__ __forceinline__ float bf2f(unsigned short b) {
    return __uint_as_float(((unsigned)b) << 16);
}

// direct-to-LDS 16B DMA (gfx950): per-wave dest = uniform base + lane*16,
// matched by our per-thread dest (base + t*16).
__device__ __forceinline__ void gload_lds16(const void* g, void* l) {
    __builtin_amdgcn_global_load_lds((const __attribute__((address_space(1))) void*)g,
                                     (__attribute__((address_space(3))) void*)l, 16, 0, 0);
}

// ---------------------------------------------------------------------------
// Weight-split unit: one 64x64 tile of one f32 W[k][n] -> TRANSPOSED bf16
// hi/lo WT[n][k], coalesced via LDS transpose. Uses smem[0..16639].
// ---------------------------------------------------------------------------
__device__ __forceinline__ void split_unit(
    char* smem, const float* __restrict__ W, short* __restrict__ ho,
    short* __restrict__ lo, int tile)
{
    float* tl = (float*)smem;   // [64][65]
    const int t = threadIdx.x;
    const int k0 = (tile >> 2) * 64, n0 = (tile & 3) * 64;
#pragma unroll
    for (int p = 0; p < 4; ++p) {
        const int kr = (t >> 4) + p * 16;
        const int nc = (t & 15) * 4;
        *(float4*)&tl[kr * 65 + nc] = *(const float4*)&W[(size_t)(k0 + kr) * 256 + n0 + nc];
    }
    __syncthreads();
    const int n = t >> 2, ks = (t & 3) * 16;
    short8v h0, h1, l0, l1;
#pragma unroll
    for (int j = 0; j < 8; ++j) {
        const float x = tl[(ks + j) * 65 + n];
        const unsigned short hb = f2bf(x);
        h0[j] = (short)hb; l0[j] = (short)f2bf(x - bf2f(hb));
    }
#pragma unroll
    for (int j = 0; j < 8; ++j) {
        const float x = tl[(ks + 8 + j) * 65 + n];
        const unsigned short hb = f2bf(x);
        h1[j] = (short)hb; l1[j] = (short)f2bf(x - bf2f(hb));
    }
    *(short8v*)&ho[(size_t)(n0 + n) * 256 + k0 + ks] = h0;
    *(short8v*)&ho[(size_t)(n0 + n) * 256 + k0 + ks + 8] = h1;
    *(short8v*)&lo[(size_t)(n0 + n) * 256 + k0 + ks] = l0;
    *(short8v*)&lo[(size_t)(n0 + n) * 256 + k0 + ks + 8] = l1;
}

// ---------------------------------------------------------------------------
// Adjacency unit: one wave builds edge e's CSR list (ballot-compaction asc).
// ---------------------------------------------------------------------------
__device__ __forceinline__ void adj_unit(
    const int* __restrict__ src, const int* __restrict__ dst,
    int* __restrict__ cand, int* __restrict__ ccount, int e, int lane)
{
    const int a = src[e], b = dst[e];
    int* my = cand + (size_t)e * CAP;
    int base = 0;
    for (int c0 = 0; c0 < E_EDGES; c0 += 64) {
        const int f = c0 + lane;
        const int sf = src[f], df = dst[f];
        const bool adj = (sf == a) | (sf == b) | (df == a) | (df == b);
        const unsigned long long mk = __ballot(adj);
        if (adj) {
            const int pos = base + __popcll(mk & ((1ull << lane) - 1ull));
            if (pos < CAP) my[pos] = f;
        }
        base += __popcll(mk);
    }
    if (lane == 0) ccount[e] = (base < CAP) ? base : CAP;
}

// ---------------------------------------------------------------------------
// Split-bf16 MFMA GEMM core, BM=32 (R12-proven): C[32x64] =
// act((A[+A2])@B + bias + r1 + r2), K=256. A@B = AhBh + AhBl + AlBh.
// 4 waves (2x2), wave = 16x32 out, 6 MFMAs/K-tile. LDS 26.6KB via smem ptr.
// Dbuf, ONE barrier/K-tile; A loads before MFMA, split after (T14); B via
// global_load_lds DMA. If nf: A row m = concat(nf[src[m]], nf[dst[m]]).
// ---------------------------------------------------------------------------
__device__ __forceinline__ void mcore32(
    char* smem,
    const float* __restrict__ A, const float* __restrict__ A2,
    const short* __restrict__ BhiT, const short* __restrict__ BloT,
    const float* __restrict__ bias, const float* __restrict__ res,
    const float* __restrict__ res2, float* __restrict__ C,
    int m0, int n0,
    const float* __restrict__ nf, const int* __restrict__ src,
    const int* __restrict__ dst, int act)
{
    short* AsH = (short*)smem;              // [2][32*40]  5120 B
    short* AsL = (short*)(smem + 5120);     //             5120 B
    short* BsH = (short*)(smem + 10240);    // [2][64*32]  8192 B
    short* BsL = (short*)(smem + 18432);    //             8192 B -> 26624
    const int t = threadIdx.x;
    const int w = t >> 6, lane = t & 63, lr = lane & 15, lg = lane >> 4;
    const int WR = (w >> 1) * 16, WC = (w & 1) * 32;
    const int ar = t >> 3, akc = (t & 7) * 4;   // A stage: row, k-col
    const int bn = t >> 2, bkc = (t & 3) * 8;   // B DMA: n-row, k-col

    int nS = 0, nD = 0;
    if (nf) { nS = src[m0 + ar]; nD = dst[m0 + ar]; }

    f32x4 acc0 = {0.f, 0.f, 0.f, 0.f}, acc1 = {0.f, 0.f, 0.f, 0.f};
    float4 av;

#define LOADA_R(k0)                                                            \
    do {                                                                       \
        const int kq = (k0) + akc;                                             \
        if (nf) {                                                              \
            const float* pp = (kq < D_NODE)                                    \
                ? &nf[(size_t)nS * D_NODE + kq]                                \
                : &nf[(size_t)nD * D_NODE + kq - D_NODE];                      \
            av = *(const float4*)pp;                                           \
        } else {                                                               \
            av = *(const float4*)&A[(size_t)(m0 + ar) * 256 + kq];             \
            if (A2) {                                                          \
                const float4 c_ = *(const float4*)&A2[(size_t)(m0 + ar) * 256 + kq]; \
                av.x += c_.x; av.y += c_.y; av.z += c_.z; av.w += c_.w;        \
            }                                                                  \
        }                                                                      \
    } while (0)
#define STOREA_S(buf)                                                          \
    do {                                                                       \
        short4v ah, al;                                                        \
        const float fv[4] = {av.x, av.y, av.z, av.w};                          \
        _Pragma("unroll") for (int j = 0; j < 4; ++j) {                        \
            const unsigned short hb = f2bf(fv[j]);                             \
            ah[j] = (short)hb; al[j] = (short)f2bf(fv[j] - bf2f(hb));          \
        }                                                                      \
        *(short4v*)&AsH[(buf) * 1280 + ar * 40 + akc] = ah;                    \
        *(short4v*)&AsL[(buf) * 1280 + ar * 40 + akc] = al;                    \
    } while (0)
#define STAGE_B(buf, k0)                                                       \
    do {                                                                       \
        gload_lds16(&BhiT[(size_t)(n0 + bn) * 256 + (k0) + bkc],               \
                    BsH + (buf) * 2048 + t * 8);                               \
        gload_lds16(&BloT[(size_t)(n0 + bn) * 256 + (k0) + bkc],               \
                    BsL + (buf) * 2048 + t * 8);                               \
    } while (0)
#define MFMA_STEP(buf)                                                         \
    do {                                                                       \
        const int c0 = WC + lr, c1 = WC + 16 + lr;                             \
        const short8v bH0 = *(const short8v*)&BsH[(buf) * 2048 + c0 * 32 + lg * 8]; \
        const short8v bL0 = *(const short8v*)&BsL[(buf) * 2048 + c0 * 32 + lg * 8]; \
        const short8v bH1 = *(const short8v*)&BsH[(buf) * 2048 + c1 * 32 + lg * 8]; \
        const short8v bL1 = *(const short8v*)&BsL[(buf) * 2048 + c1 * 32 + lg * 8]; \
        const short8v aH = *(const short8v*)&AsH[(buf) * 1280 + (WR + lr) * 40 + lg * 8]; \
        const short8v aL = *(const short8v*)&AsL[(buf) * 1280 + (WR + lr) * 40 + lg * 8]; \
        acc0 = __builtin_amdgcn_mfma_f32_16x16x32_bf16(aH, bH0, acc0, 0, 0, 0);\
        acc1 = __builtin_amdgcn_mfma_f32_16x16x32_bf16(aH, bH1, acc1, 0, 0, 0);\
        acc0 = __builtin_amdgcn_mfma_f32_16x16x32_bf16(aH, bL0, acc0, 0, 0, 0);\
        acc1 = __builtin_amdgcn_mfma_f32_16x16x32_bf16(aH, bL1, acc1, 0, 0, 0);\
        acc0 = __builtin_amdgcn_mfma_f32_16x16x32_bf16(aL, bH0, acc0, 0, 0, 0);\
        acc1 = __builtin_amdgcn_mfma_f32_16x16x32_bf16(aL, bH1, acc1, 0, 0, 0);\
    } while (0)

    LOADA_R(0);
    STAGE_B(0, 0);
    STOREA_S(0);
    __syncthreads();

    for (int kt = 0; kt < 8; ++kt) {       // K = 256 = 8 x 32
        const int cur = kt & 1;
        if (kt < 7) {
            STAGE_B(cur ^ 1, (kt + 1) * 32);
            LOADA_R((kt + 1) * 32);
        }
        MFMA_STEP(cur);
        if (kt < 7) STOREA_S(cur ^ 1);
        __syncthreads();
    }

#define EPI(accv, ct)                                                          \
    do {                                                                       \
        const int col = n0 + WC + (ct) * 16 + lr;                              \
        const float bb = bias ? bias[col] : 0.f;                               \
        _Pragma("unroll") for (int i = 0; i < 4; ++i) {                        \
            const int row = m0 + WR + lg * 4 + i;                              \
            float v = accv[i] + bb;                                            \
            if (res)  v += res[(size_t)row * D_EDGE + col];                    \
            if (res2) v += res2[(size_t)row * D_EDGE + col];                   \
            if (act == 1) v = 0.5f * v * (1.f + erff(v * 0.70710678118654752f)); \
            C[(size_t)row * D_EDGE + col] = v;                                 \
        }                                                                      \
    } while (0)
    EPI(acc0, 0); EPI(acc1, 1);
#undef LOADA_R
#undef STOREA_S
#undef STAGE_B
#undef MFMA_STEP
#undef EPI
}

// ---------------------------------------------------------------------------
// Dispatch A: adjacency (blocks 0..1023, wave per edge) + Wn1/Wn2 splits
// (blocks 1024..1055) — only the splits ctx needs. Independent work.
// ---------------------------------------------------------------------------
__global__ __launch_bounds__(256) void adj_prep(
    const int* __restrict__ src, const int* __restrict__ dst,
    int* __restrict__ cand, int* __restrict__ ccount,
    const float* Wn1, const float* Wn2, short* hiT, short* loT)
{
    __shared__ __attribute__((aligned(16))) char smem[16640];
    if (blockIdx.x < 1024) {
        const int t = threadIdx.x;
        adj_unit(src, dst, cand, ccount, blockIdx.x * 4 + (t >> 6), t & 63);
    } else {
        const int u = blockIdx.x - 1024;
        const int mat = (u >> 4) ? 5 : 0;
        split_unit(smem, (u >> 4) ? Wn2 : Wn1,
                   hiT + (size_t)mat * 65536, loT + (size_t)mat * 65536, u & 15);
    }
}

// ---------------------------------------------------------------------------
// Dispatch B: ctx both layers (blocks 0..1023, XCD row-panel pinned) + the
// 9 remaining weight splits (blocks 1024..1167) — qkv needs them, ctx not.
// ---------------------------------------------------------------------------
__global__ __launch_bounds__(256) void ctx_prep(
    const float* __restrict__ nf, const int* __restrict__ src,
    const int* __restrict__ dst, short* hiT, short* loT,
    const float* __restrict__ bn1, const float* __restrict__ bn2,
    float* __restrict__ ctx,
    const float* Wq1, const float* Wk1, const float* Wv1, const float* Wo1,
    const float* Wq2, const float* Wk2, const float* Wv2, const float* Wo2,
    const float* Wc1)
{
    __shared__ __attribute__((aligned(16))) char smem[26624];
    if (blockIdx.x < 1024) {
        const int lid = blockIdx.x;
        const int g = lid & 7, s = lid >> 3;       // XCD, slot
        const int rowt = g * 32 + (s >> 2);        // [0,256)
        const int ct = s & 3;
        const int R = rowt * 32;
        const int Lyr = R >> 12;
        const int r = R & (E_EDGES - 1);
        mcore32(smem, nullptr, nullptr,
                hiT + (size_t)(Lyr * 5) * 65536, loT + (size_t)(Lyr * 5) * 65536,
                Lyr ? bn2 : bn1, nullptr, nullptr,
                ctx + (size_t)Lyr * E_EDGES * D_EDGE,
                r, ct * 64, nf, src, dst, 0);
    } else {
        const int u = blockIdx.x - 1024;
        const int mi = u >> 4;
        const int matIdx[9] = {1, 2, 3, 4, 6, 7, 8, 9, 10};
        const float* Ws[9] = {Wq1, Wk1, Wv1, Wo1, Wq2, Wk2, Wv2, Wo2, Wc1};
        const int mat = matIdx[mi];
        split_unit(smem, Ws[mi], hiT + (size_t)mat * 65536,
                   loT + (size_t)mat * 65536, u & 15);
    }
}

// q/k/v fused: 1536 blocks = one 6/CU pass; row-panel pinned to one XCD.
__global__ __launch_bounds__(256) void gemm_qkv32(
    const float* __restrict__ ef_in, const float* __restrict__ ctx,
    const short* __restrict__ whiT, const short* __restrict__ wloT,
    const float* __restrict__ bq, const float* __restrict__ bk,
    const float* __restrict__ bv,
    float* __restrict__ qb, float* __restrict__ kb, float* __restrict__ vb,
    int wbase)
{
    __shared__ __attribute__((aligned(16))) char smem[26624];
    const int lid = blockIdx.x;
    const int g = lid & 7, s = lid >> 3;           // s in [0,192)
    const int rowt = g * 16 + s / 12;              // [0,128)
    const int rem = s % 12, wsel = rem >> 2, ct = rem & 3;
    const short* BH = whiT + (size_t)(wbase + 1 + wsel) * 65536;
    const short* BL = wloT + (size_t)(wbase + 1 + wsel) * 65536;
    const float* bias = (wsel == 0) ? bq : (wsel == 1) ? bk : bv;
    float* C = (wsel == 0) ? qb : (wsel == 1) ? kb : vb;
    mcore32(smem, ef_in, ctx, BH, BL, bias, nullptr, nullptr, C,
            rowt * 32, ct * 64, nullptr, nullptr, nullptr, 0);
}

// Generic 512-block GEMM: C = act(A@B + bias + res + res2).
// Used for Wo (res=ef_in, res2=ctx) and cls_h (act=1, h = gelu(y@W1+b1)).
__global__ __launch_bounds__(256) void gemm_g32(
    const float* __restrict__ A, const short* __restrict__ BhiT,
    const short* __restrict__ BloT, const float* __restrict__ bias,
    const float* __restrict__ res, const float* __restrict__ res2,
    float* __restrict__ C, int act)
{
    __shared__ __attribute__((aligned(16))) char smem[26624];
    const int lid = blockIdx.x;
    const int g = lid & 7, s = lid >> 3;           // s in [0,64)
    const int rowt = g * 16 + (s >> 2);            // [0,128)
    const int ct = s & 3;
    mcore32(smem, A, nullptr, BhiT, BloT, bias, res, res2, C,
            rowt * 32, ct * 64, nullptr, nullptr, nullptr, act);
}

// ---------------------------------------------------------------------------
// Sparse attention v4 (R11-proven). Block = edge, wave = head, 4 groups of
// 16 lanes, independent online softmax per group, merged once at the end.
// ---------------------------------------------------------------------------
__global__ __launch_bounds__(256) void attn_sparse4(
    const float* __restrict__ q, const float* __restrict__ k,
    const float* __restrict__ v, const int* __restrict__ cand,
    const int* __restrict__ ccount, float* __restrict__ out)
{
    __shared__ int lc[CAP];
    const int e = blockIdx.x;
    const int t = threadIdx.x, h = t >> 6, lane = t & 63;
    const int g = lane >> 4, il = lane & 15;
    const int m = ccount[e];
    if (t < m) lc[t] = cand[(size_t)e * CAP + t];
    __syncthreads();

    const float4 q4 = *(const float4*)&q[(size_t)e * D_EDGE + h * HD + il * 4];
    float M = -1e30f, L = 0.f;
    float4 O = make_float4(0.f, 0.f, 0.f, 0.f);

    for (int i0 = g; i0 < m; i0 += 8) {
        const int f0 = lc[i0];
        const bool ok1 = (i0 + 4) < m;
        const int f1 = ok1 ? lc[i0 + 4] : f0;
        const float4 k0 = *(const float4*)&k[(size_t)f0 * D_EDGE + h * HD + il * 4];
        const float4 v0 = *(const float4*)&v[(size_t)f0 * D_EDGE + h * HD + il * 4];
        const float4 k1 = *(const float4*)&k[(size_t)f1 * D_EDGE + h * HD + il * 4];
        const float4 v1 = *(const float4*)&v[(size_t)f1 * D_EDGE + h * HD + il * 4];
        float s0 = q4.x * k0.x + q4.y * k0.y + q4.z * k0.z + q4.w * k0.w;
        float s1 = q4.x * k1.x + q4.y * k1.y + q4.z * k1.z + q4.w * k1.w;
        s0 += __shfl_xor(s0, 1); s1 += __shfl_xor(s1, 1);
        s0 += __shfl_xor(s0, 2); s1 += __shfl_xor(s1, 2);
        s0 += __shfl_xor(s0, 4); s1 += __shfl_xor(s1, 4);
        s0 += __shfl_xor(s0, 8); s1 += __shfl_xor(s1, 8);
        s0 *= 0.125f;                          // 1/sqrt(64)
        s1 = ok1 ? s1 * 0.125f : -1e30f;       // tail: p1 -> 0 exactly
        const float Mn = fmaxf(M, fmaxf(s0, s1));
        const float al = __expf(M - Mn);
        const float p0 = __expf(s0 - Mn), p1 = __expf(s1 - Mn);
        O.x = O.x * al + p0 * v0.x + p1 * v1.x;
        O.y = O.y * al + p0 * v0.y + p1 * v1.y;
        O.z = O.z * al + p0 * v0.z + p1 * v1.z;
        O.w = O.w * al + p0 * v0.w + p1 * v1.w;
        L = L * al + p0 + p1;
        M = Mn;
    }
    float Mo = fmaxf(M, __shfl_xor(M, 16));
    Mo = fmaxf(Mo, __shfl_xor(Mo, 32));
    const float sc = __expf(M - Mo);           // empty group: exp(-1e30-Mo)=0
    O.x *= sc; O.y *= sc; O.z *= sc; O.w *= sc; L *= sc;
    O.x += __shfl_xor(O.x, 16); O.y += __shfl_xor(O.y, 16);
    O.z += __shfl_xor(O.z, 16); O.w += __shfl_xor(O.w, 16);
    L += __shfl_xor(L, 16);
    O.x += __shfl_xor(O.x, 32); O.y += __shfl_xor(O.y, 32);
    O.z += __shfl_xor(O.z, 32); O.w += __shfl_xor(O.w, 32);
    L += __shfl_xor(L, 32);
    if (lane < 16) {
        const float invL = 1.f / L;
        float4 r = make_float4(O.x * invL, O.y * invL, O.z * invL, O.w * invL);
        *(float4*)&out[(size_t)e * D_EDGE + h * HD + il * 4] = r;
    }
}

// ---------------------------------------------------------------------------
// cls_out: out[4096][16] = h@W2 + b2. 256 blocks x 16 rows. W2 (16KB) in
// LDS; h read direct from global (L2-warm, just written), split in regs;
// 24 MFMAs on wave 0. Tiny by construction.
// ---------------------------------------------------------------------------
__global__ __launch_bounds__(256) void cls_out(
    const float* __restrict__ h, const float* __restrict__ W2,
    const float* __restrict__ b2, float* __restrict__ outp)
{
    __shared__ __attribute__((aligned(16))) float W2s[256 * 16];
    const int t = threadIdx.x;
    const int w = t >> 6, lane = t & 63, lr = lane & 15, lg = lane >> 4;
    const int m0 = blockIdx.x * 16;
#pragma unroll
    for (int p = 0; p < 4; ++p) {
        const int idx = t + 256 * p;       // 1024 x 16B = 16KB
        gload_lds16(&W2[(size_t)idx * 4], W2s + (size_t)idx * 4);
    }
    __syncthreads();
    if (w == 0) {
        f32x4 o = {0.f, 0.f, 0.f, 0.f};
#pragma unroll
        for (int kk = 0; kk < 8; ++kk) {
            const float4 h0 = *(const float4*)&h[(size_t)(m0 + lr) * 256 + kk * 32 + lg * 8];
            const float4 h1 = *(const float4*)&h[(size_t)(m0 + lr) * 256 + kk * 32 + lg * 8 + 4];
            short8v aH, aL;
            const float fv[8] = {h0.x, h0.y, h0.z, h0.w, h1.x, h1.y, h1.z, h1.w};
#pragma unroll
            for (int j = 0; j < 8; ++j) {
                const unsigned short hb = f2bf(fv[j]);
                aH[j] = (short)hb; aL[j] = (short)f2bf(fv[j] - bf2f(hb));
            }
            short8v bH, bL;
#pragma unroll
            for (int j = 0; j < 8; ++j) {
                const float x = W2s[(size_t)(kk * 32 + lg * 8 + j) * 16 + lr];
                const unsigned short hb = f2bf(x);
                bH[j] = (short)hb; bL[j] = (short)f2bf(x - bf2f(hb));
            }
            o = __builtin_amdgcn_mfma_f32_16x16x32_bf16(aH, bH, o, 0, 0, 0);
            o = __builtin_amdgcn_mfma_f32_16x16x32_bf16(aH, bL, o, 0, 0, 0);
            o = __builtin_amdgcn_mfma_f32_16x16x32_bf16(aL, bH, o, 0, 0, 0);
        }
#pragma unroll
        for (int i = 0; i < 4; ++i) {
            const int row = m0 + lg * 4 + i;
            outp[(size_t)row * 16 + lr] = o[i] + b2[lr];
        }
    }
}

// ---------------------------------------------------------------------------
extern "C" void kernel_launch(void* const* d_in, const int* in_sizes, int n_in,
                              void* d_out, int out_size, void* d_ws, size_t ws_size,
                              hipStream_t stream)
{
    const float* nf = (const float*)d_in[0];
    const float* ef = (const float*)d_in[1];
    const int* ei = (const int*)d_in[2];
    const int* src = ei;
    const int* dst = ei + E_EDGES;

    const float* a_Wn[2] = {(const float*)d_in[3],  (const float*)d_in[13]};
    const float* a_bn[2] = {(const float*)d_in[4],  (const float*)d_in[14]};
    const float* a_Wq[2] = {(const float*)d_in[5],  (const float*)d_in[15]};
    const float* a_bq[2] = {(const float*)d_in[6],  (const float*)d_in[16]};
    const float* a_Wk[2] = {(const float*)d_in[7],  (const float*)d_in[17]};
    const float* a_bk[2] = {(const float*)d_in[8],  (const float*)d_in[18]};
    const float* a_Wv[2] = {(const float*)d_in[9],  (const float*)d_in[19]};
    const float* a_bv[2] = {(const float*)d_in[10], (const float*)d_in[20]};
    const float* a_Wo[2] = {(const float*)d_in[11], (const float*)d_in[21]};
    const float* a_bo[2] = {(const float*)d_in[12], (const float*)d_in[22]};
    const float* cls_W1 = (const float*)d_in[23];
    const float* cls_b1 = (const float*)d_in[24];
    const float* cls_W2 = (const float*)d_in[25];
    const float* cls_b2 = (const float*)d_in[26];

    const size_t buf = (size_t)E_EDGES * D_EDGE;  // 1M floats = 4MB
    float* ws = (float*)d_ws;
    float* ctx1 = ws + 0 * buf;         // ctx base; ctx2 contiguous
    float* ctx2 = ws + 1 * buf;
    float* qb   = ws + 2 * buf;         // later aliased by h (post attn L2)
    float* kb   = ws + 3 * buf;
    float* vb   = ws + 4 * buf;
    float* ao   = ws + 5 * buf;
    float* y1   = ws + 6 * buf;
    float* y2   = ctx1;                 // ctx1 dead after layer-1 Wo
    float* hb   = qb;                   // qb dead after layer-2 attn
    int* cand   = (int*)(ws + 7 * buf);            // 4096*128*4 = 2MB
    int* ccount = cand + (size_t)E_EDGES * CAP;    // 16KB
    short* whiT = (short*)(ccount + E_EDGES);      // 11 x 128KB
    short* wloT = whiT + (size_t)11 * 65536;       // 11 x 128KB

    // A: adjacency + Wn splits (the only splits ctx needs)
    adj_prep<<<1056, 256, 0, stream>>>(src, dst, cand, ccount,
                                       a_Wn[0], a_Wn[1], whiT, wloT);
    // B: ctx both layers + the 9 remaining splits (first needed by qkv)
    ctx_prep<<<1168, 256, 0, stream>>>(nf, src, dst, whiT, wloT,
                                       a_bn[0], a_bn[1], ctx1,
                                       a_Wq[0], a_Wk[0], a_Wv[0], a_Wo[0],
                                       a_Wq[1], a_Wk[1], a_Wv[1], a_Wo[1],
                                       cls_W1);

    const float* ef_in = ef;
    const float* ctxL[2] = {ctx1, ctx2};
    float* yout[2] = {y1, y2};
    for (int L = 0; L < 2; ++L) {
        const int wbase = L * 5;
        gemm_qkv32<<<1536, 256, 0, stream>>>(
            ef_in, ctxL[L], whiT, wloT, a_bq[L], a_bk[L], a_bv[L],
            qb, kb, vb, wbase);
        attn_sparse4<<<E_EDGES, 256, 0, stream>>>(qb, kb, vb, cand, ccount, ao);
        gemm_g32<<<512, 256, 0, stream>>>(
            ao, whiT + (size_t)(wbase + 4) * 65536,
            wloT + (size_t)(wbase + 4) * 65536,
            a_bo[L], ef_in, ctxL[L], yout[L], 0);
        ef_in = yout[L];
    }

    // h = gelu(y2 @ W1 + b1)  (proven mcore32 path)
    gemm_g32<<<512, 256, 0, stream>>>(
        y2, whiT + (size_t)10 * 65536, wloT + (size_t)10 * 65536,
        cls_b1, nullptr, nullptr, hb, 1);
    // out = h @ W2 + b2  (tiny)
    cls_out<<<E_EDGES / 16, 256, 0, stream>>>(hb, cls_W2, cls_b2, (float*)d_out);
}